// Round 7
// baseline (561.391 us; speedup 1.0000x reference)
//
#include <hip/hip_runtime.h>
#include <hip/hip_bf16.h>
#include <hip/hip_cooperative_groups.h>
#include <math.h>

namespace cg = cooperative_groups;

#define L_SEQ 16384
#define DM 256
#define DI 512
#define DS 16
#define NCH 512   // number of scan chunks
#define CHL 32    // chunk length (NCH*CHL == L_SEQ)
#define CLB 16    // conv: timesteps per thread

typedef __attribute__((ext_vector_type(8))) short short8v;
typedef __attribute__((ext_vector_type(4))) float f32x4;

__device__ __forceinline__ float warpSum(float v){
#pragma unroll
  for(int o=32;o;o>>=1) v += __shfl_xor(v,o);
  return v;
}
__device__ __forceinline__ float gelu_f(float x){
  float x3 = x*x*x;
  return 0.5f*x*(1.0f + tanhf(0.7978845608028654f*(x + 0.044715f*x3)));
}
__device__ __forceinline__ float silu_f(float x){
  return x / (1.0f + __expf(-x));
}
__device__ __forceinline__ float softplus_f(float x){
  return fmaxf(x,0.0f) + log1pf(__expf(-fabsf(x)));
}
__device__ __forceinline__ float bf2f(unsigned short u){
  return __uint_as_float(((unsigned int)u)<<16);
}
__device__ __forceinline__ void gload16(const void* g, void* l){
  __builtin_amdgcn_global_load_lds((const __attribute__((address_space(1))) void*)g,
                                   (__attribute__((address_space(3))) void*)l, 16, 0, 0);
}
__device__ __forceinline__ void stv(float* p, float v){ *p = v; }
__device__ __forceinline__ void stv(__hip_bfloat16* p, float v){ *p = __float2bfloat16(v); }

// ---- weight convert + transpose to bf16: Wt[n][k] = bf16(W[k][n]) ----
__global__ void k_cvtw(const float* __restrict__ inW, const float* __restrict__ outW,
                       const float* __restrict__ W1, __hip_bfloat16* __restrict__ inWt,
                       __hip_bfloat16* __restrict__ outWt, __hip_bfloat16* __restrict__ W1t){
  int idx = blockIdx.x*256 + threadIdx.x;
  if(idx < 524288){                      // inW: 2 layers of [256][1024] -> [1024][256]
    int layer = idx >> 18;
    int r = idx & 262143;
    int n = r >> 8, k = r & 255;
    inWt[idx] = __float2bfloat16(inW[layer*262144 + k*1024 + n]);
  } else if(idx < 786432){               // outW: 2 layers of [512][256] -> [256][512]
    int j = idx - 524288;
    int layer = j >> 17;
    int r = j & 131071;
    int n = r >> 9, k = r & 511;
    outWt[j] = __float2bfloat16(outW[layer*131072 + k*256 + n]);
  } else if(idx < 819200){               // W1: [256][128] -> [128][256]
    int j = idx - 786432;
    int n = j >> 8, k = j & 255;
    W1t[j] = __float2bfloat16(W1[k*128 + n]);
  }
}

// ---- build merged delta|BC weight: Wdbc_t[layer][640][512]:
//      rows 0..511  = (xpW[:, :16] @ dtW)^T  (delta pre-act)
//      rows 512..543 = xpW[:, 16+..]^T (B|C), rows 544..639 = 0 ----
__global__ void k_wd(const float* __restrict__ xpW, const float* __restrict__ dtW,
                     __hip_bfloat16* __restrict__ Wdbc_t){
  int idx = blockIdx.x*256 + threadIdx.x;   // 2*640*512 = 655360
  if(idx >= 655360) return;
  int layer = idx / 327680;
  int r = idx % 327680;
  int n = r >> 9, k = r & 511;
  const float* xp = xpW + layer*512*48;
  float v;
  if(n < 512){
    const float* dt = dtW + layer*16*512;
    float s = 0.f;
#pragma unroll
    for(int j=0;j<16;j++) s = fmaf(xp[k*48+j], dt[j*512+n], s);
    v = s;
  } else if(n < 544){
    v = xp[k*48 + 16 + (n-512)];
  } else v = 0.f;
  Wdbc_t[idx] = __float2bfloat16(v);
}

// ---- input projection + LN + gelu: u = gelu(LN(x@Win + bin)) ----
__global__ void k_input(const float* __restrict__ x, const float* __restrict__ Win,
                        const float* __restrict__ bin, const float* __restrict__ g,
                        const float* __restrict__ b, float* __restrict__ u){
  int r = blockIdx.x, t = threadIdx.x;
  __shared__ float xr[32];
  __shared__ float sA[4], sB[4];
  if(t<32) xr[t] = x[r*32+t];
  __syncthreads();
  float v = bin[t];
#pragma unroll
  for(int k=0;k<32;k++) v = fmaf(xr[k], Win[k*DM+t], v);
  float s = warpSum(v), sq = warpSum(v*v);
  if((t&63)==0){ sA[t>>6]=s; sB[t>>6]=sq; }
  __syncthreads();
  float mean = (sA[0]+sA[1]+sA[2]+sA[3])*(1.0f/DM);
  float msq  = (sB[0]+sB[1]+sB[2]+sB[3])*(1.0f/DM);
  float var = msq - mean*mean;
  float nv = (v-mean)*rsqrtf(var+1e-5f)*g[t]+b[t];
  u[r*DM+t] = gelu_f(nv);
}

// ---- rmsnorm over 256 -> bf16 ----
__global__ void k_rms(const float* __restrict__ u, const float* __restrict__ w,
                      __hip_bfloat16* __restrict__ o){
  int r=blockIdx.x, t=threadIdx.x;
  __shared__ float sA[4];
  float v = u[r*DM+t];
  float sq = warpSum(v*v);
  if((t&63)==0) sA[t>>6]=sq;
  __syncthreads();
  float ms = (sA[0]+sA[1]+sA[2]+sA[3])*(1.0f/DM);
  o[r*DM+t] = __float2bfloat16(v*rsqrtf(ms+1e-5f)*w[t]);
}

// ---- layernorm over 256 -> bf16 ----
__global__ void k_ln(const float* __restrict__ u, const float* __restrict__ g,
                     const float* __restrict__ b, __hip_bfloat16* __restrict__ o){
  int r=blockIdx.x, t=threadIdx.x;
  __shared__ float sA[4], sB[4];
  float v = u[r*DM+t];
  float s = warpSum(v), sq = warpSum(v*v);
  if((t&63)==0){ sA[t>>6]=s; sB[t>>6]=sq; }
  __syncthreads();
  float mean = (sA[0]+sA[1]+sA[2]+sA[3])*(1.0f/DM);
  float msq  = (sB[0]+sB[1]+sB[2]+sB[3])*(1.0f/DM);
  float var = msq - mean*mean;
  o[r*DM+t] = __float2bfloat16((v-mean)*rsqrtf(var+1e-5f)*g[t]+b[t]);
}

// ---- bf16 MFMA GEMM: C[M,:](OT, stride ldc) = A[M,K](bf16) @ Wt[N,K](bf16)^T
//      EPI: 0=store, 1=+R, 2=gelu(+bias), 3=softplus(+bias),
//      4=split delta|BC: col<512 -> softplus(+bias)->C; 512<=col<544 -> C2. ----
template<int EPI, typename OT>
__global__ __launch_bounds__(256) void k_mgemm(const __hip_bfloat16* __restrict__ A,
    const __hip_bfloat16* __restrict__ Wt, const float* __restrict__ bias,
    const float* __restrict__ R, OT* __restrict__ C, float* __restrict__ C2,
    int M, int K, int ldc, int Nout){
  __shared__ short As[8192];   // [128 rows][64 k] bf16, slot-swizzled
  __shared__ short Bs[8192];
  int t = threadIdx.x, lane = t&63, wave = t>>6;
  int m0 = blockIdx.y*128, n0 = blockIdx.x*128;
  int wm = (wave>>1)*64, wn = (wave&1)*64;
  f32x4 acc[4][4] = {};
  // staging descriptors: LDS linear dest (base+lane*16), pre-swizzled global src
  int soff[4], srow[4], scol[4];
#pragma unroll
  for(int c=0;c<4;c++){
    int off = (wave*4+c)*1024 + lane*16;   // byte offset in 16KB tile
    int row = off>>7;                       // 128B per row
    int sl  = ((off>>4)&7) ^ (row&7);       // logical 16B slot for this phys slot
    soff[c]=off; srow[c]=row; scol[c]=sl*8;
  }
  for(int kt=0; kt<K; kt+=64){
#pragma unroll
    for(int c=0;c<4;c++){
      gload16(&A [(m0+srow[c])*K + kt + scol[c]], (char*)As + soff[c]);
      gload16(&Wt[(n0+srow[c])*K + kt + scol[c]], (char*)Bs + soff[c]);
    }
    asm volatile("s_waitcnt vmcnt(0)" ::: "memory");
    __syncthreads();
#pragma unroll
    for(int ks=0; ks<2; ks++){
      short8v a[4], b[4];
      int k8 = ks*4 + (lane>>4);
#pragma unroll
      for(int i=0;i<4;i++){
        int lr = wm + i*16 + (lane&15);
        a[i] = *(const short8v*)&As[lr*64 + (k8 ^ (lr&7))*8];
      }
#pragma unroll
      for(int j=0;j<4;j++){
        int lr = wn + j*16 + (lane&15);
        b[j] = *(const short8v*)&Bs[lr*64 + (k8 ^ (lr&7))*8];
      }
#pragma unroll
      for(int i=0;i<4;i++)
#pragma unroll
        for(int j=0;j<4;j++)
          acc[i][j] = __builtin_amdgcn_mfma_f32_16x16x32_bf16(a[i], b[j], acc[i][j], 0,0,0);
    }
    __syncthreads();
  }
#pragma unroll
  for(int i=0;i<4;i++){
    int grow0 = m0 + wm + i*16 + (lane>>4)*4;
#pragma unroll
    for(int j=0;j<4;j++){
      int gcol = n0 + wn + j*16 + (lane&15);
      if(gcol < Nout){
#pragma unroll
        for(int r=0;r<4;r++){
          float v = acc[i][j][r];
          int grow = grow0 + r;
          if(EPI==4){
            if(gcol < 512) stv(&C[grow*ldc+gcol], softplus_f(v + bias[gcol]));
            else           C2[grow*32 + (gcol-512)] = v;
          } else {
            if(EPI==1) v += R[grow*ldc+gcol];
            if(EPI==2) v = gelu_f(v + bias[gcol]);
            if(EPI==3) v = softplus_f(v + bias[gcol]);
            stv(&C[grow*ldc+gcol], v);
          }
        }
      }
    }
  }
}

// ---- causal depthwise conv (k=4) + bias + silu, sliding window. ----
__global__ __launch_bounds__(256) void k_conv(const __hip_bfloat16* __restrict__ xz,
                       const float* __restrict__ cw, const float* __restrict__ cb,
                       __hip_bfloat16* __restrict__ xs_bf){
  int idx = blockIdx.x*256 + threadIdx.x;   // (L_SEQ/CLB)*128 threads
  int cg = idx & 127, lb = idx >> 7;
  int c4 = cg*4;
  int l0 = lb*CLB;
  float w[4][4], bias[4];
#pragma unroll
  for(int j=0;j<4;j++){
    float4 wv = *(const float4*)&cw[(c4+j)*4];
    w[j][0]=wv.x; w[j][1]=wv.y; w[j][2]=wv.z; w[j][3]=wv.w;
  }
  { float4 bv = *(const float4*)&cb[c4];
    bias[0]=bv.x; bias[1]=bv.y; bias[2]=bv.z; bias[3]=bv.w; }
  float xm0[4], xm1[4], xm2[4];   // x[l-3], x[l-2], x[l-1]
#pragma unroll
  for(int j=0;j<4;j++){ xm0[j]=0.f; xm1[j]=0.f; xm2[j]=0.f; }
  if(l0 >= 3){
    ushort4 r0 = *(const ushort4*)&xz[(l0-3)*1024 + c4];
    ushort4 r1 = *(const ushort4*)&xz[(l0-2)*1024 + c4];
    ushort4 r2 = *(const ushort4*)&xz[(l0-1)*1024 + c4];
    xm0[0]=bf2f(r0.x); xm0[1]=bf2f(r0.y); xm0[2]=bf2f(r0.z); xm0[3]=bf2f(r0.w);
    xm1[0]=bf2f(r1.x); xm1[1]=bf2f(r1.y); xm1[2]=bf2f(r1.z); xm1[3]=bf2f(r1.w);
    xm2[0]=bf2f(r2.x); xm2[1]=bf2f(r2.y); xm2[2]=bf2f(r2.z); xm2[3]=bf2f(r2.w);
  }
  for(int l=l0; l<l0+CLB; l++){
    ushort4 rc = *(const ushort4*)&xz[l*1024 + c4];
    float xc[4] = {bf2f(rc.x), bf2f(rc.y), bf2f(rc.z), bf2f(rc.w)};
    __hip_bfloat16 ob[4];
#pragma unroll
    for(int j=0;j<4;j++){
      float acc = bias[j];
      acc = fmaf(xm0[j], w[j][0], acc);
      acc = fmaf(xm1[j], w[j][1], acc);
      acc = fmaf(xm2[j], w[j][2], acc);
      acc = fmaf(xc[j],  w[j][3], acc);
      ob[j] = __float2bfloat16(silu_f(acc));
    }
    *(uint2*)&xs_bf[l*DI + c4] = *(uint2*)ob;
#pragma unroll
    for(int j=0;j<4;j++){ xm0[j]=xm1[j]; xm1[j]=xm2[j]; xm2[j]=xc[j]; }
  }
}

// ---- fused selective scan: pass1(local) -> grid.sync -> chunk prefix -> grid.sync
//      -> pass2(replay from LDS/regs, write y). Cooperative, 1024 blocks x 256. ----
__global__ __launch_bounds__(256,4) void k_scanf(
    const float* __restrict__ delta, const __hip_bfloat16* __restrict__ xs,
    const float* __restrict__ dbc32, const float* __restrict__ A_log,
    const float* __restrict__ Dp, const __hip_bfloat16* __restrict__ xz,
    __hip_bfloat16* __restrict__ y, float* __restrict__ Atot,
    float* __restrict__ Btot, float* __restrict__ h0){
  cg::grid_group grid = cg::this_grid();
  __shared__ float d_lds[CHL*256];   // 32KB: [li][t] (conflict-free)
  __shared__ float bcs[CHL*32];      // 4KB:  [li][B(16)|C(16)]
  int t = threadIdx.x;
  int vb = blockIdx.x;
  int chunk = vb >> 1;
  int e = ((vb & 1) << 8) + t;
  int l0 = chunk*CHL;
  ((float4*)bcs)[t] = ((const float4*)&dbc32[l0*32])[t];   // 256 float4 = CHL*32
  float A[16];
  {
    const float4* al = (const float4*)&A_log[e*DS];
#pragma unroll
    for(int q=0;q<4;q++){
      float4 a = al[q];
      A[q*4+0] = -__expf(a.x); A[q*4+1] = -__expf(a.y);
      A[q*4+2] = -__expf(a.z); A[q*4+3] = -__expf(a.w);
    }
  }
  float carry[16], aprod[16];
#pragma unroll
  for(int n=0;n<16;n++){ carry[n]=0.f; aprod[n]=1.f; }
  unsigned int xpk[CHL/2];
  __syncthreads();
  // ---- pass 1: local scan, stage delta in LDS + xs packed in regs ----
#pragma unroll
  for(int li=0; li<CHL; li++){
    int l = l0 + li;
    float d = delta[l*DI+e];
    unsigned short xu = *(const unsigned short*)&xs[l*DI+e];
    d_lds[li*256+t] = d;
    if((li&1)==0) xpk[li>>1] = xu;
    else          xpk[li>>1] |= ((unsigned int)xu)<<16;
    float xv = bf2f(xu);
    float dxv = d*xv;
    const float4* bp = (const float4*)&bcs[li*32];
    float4 b0=bp[0], b1=bp[1], b2=bp[2], b3=bp[3];
    float B[16] = {b0.x,b0.y,b0.z,b0.w, b1.x,b1.y,b1.z,b1.w,
                   b2.x,b2.y,b2.z,b2.w, b3.x,b3.y,b3.z,b3.w};
#pragma unroll
    for(int n=0;n<16;n++){
      float dA = __expf(d*A[n]);
      carry[n] = fmaf(carry[n], dA, dxv*B[n]);
      aprod[n] *= dA;
    }
  }
  {
    float4* ap = (float4*)&Atot[chunk*8192 + e*DS];
    float4* bp = (float4*)&Btot[chunk*8192 + e*DS];
#pragma unroll
    for(int q=0;q<4;q++){
      ap[q] = make_float4(aprod[q*4],aprod[q*4+1],aprod[q*4+2],aprod[q*4+3]);
      bp[q] = make_float4(carry[q*4],carry[q*4+1],carry[q*4+2],carry[q*4+3]);
    }
  }
  __threadfence();
  grid.sync();
  // ---- chunk-prefix scan (8192 states across first 32 blocks) ----
  int tg = vb*256 + t;
  if(tg < 8192){
    float c2 = 0.f;
    for(int c=0; c<NCH; c++){
      float a = Atot[c*8192+tg];
      float b = Btot[c*8192+tg];
      h0[c*8192+tg] = c2;
      c2 = fmaf(c2, a, b);
    }
  }
  __threadfence();
  grid.sync();
  // ---- pass 2: replay with carry-in, y = (sum h*C + xs*D)*silu(z) ----
  {
    const float4* hp = (const float4*)&h0[chunk*8192 + e*DS];
#pragma unroll
    for(int q=0;q<4;q++){
      float4 h = hp[q];
      carry[q*4+0]=h.x; carry[q*4+1]=h.y; carry[q*4+2]=h.z; carry[q*4+3]=h.w;
    }
  }
  float Dv = Dp[e];
#pragma unroll
  for(int li=0; li<CHL; li++){
    int l = l0 + li;
    float d = d_lds[li*256+t];
    unsigned int xw = xpk[li>>1];
    unsigned short xu = (li&1) ? (unsigned short)(xw>>16) : (unsigned short)(xw&0xffffu);
    float xv = bf2f(xu);
    float dxv = d*xv;
    const float4* bp = (const float4*)&bcs[li*32];
    float4 b0=bp[0], b1=bp[1], b2=bp[2], b3=bp[3];
    float4 c0=bp[4], c1=bp[5], c2=bp[6], c3=bp[7];
    float B[16] = {b0.x,b0.y,b0.z,b0.w, b1.x,b1.y,b1.z,b1.w,
                   b2.x,b2.y,b2.z,b2.w, b3.x,b3.y,b3.z,b3.w};
    float Cv[16] = {c0.x,c0.y,c0.z,c0.w, c1.x,c1.y,c1.z,c1.w,
                    c2.x,c2.y,c2.z,c2.w, c3.x,c3.y,c3.z,c3.w};
    float p[4] = {0.f,0.f,0.f,0.f};
#pragma unroll
    for(int n=0;n<16;n++){
      float dA = __expf(d*A[n]);
      carry[n] = fmaf(carry[n], dA, dxv*B[n]);
      p[n&3] = fmaf(carry[n], Cv[n], p[n&3]);
    }
    float ps = (p[0]+p[1]) + (p[2]+p[3]);
    float z = bf2f(*(const unsigned short*)&xz[l*1024 + 512 + e]);
    y[l*DI+e] = __float2bfloat16(fmaf(xv, Dv, ps) * silu_f(z));
  }
}

// ---- fallback 3-kernel scan (used only if cooperative occupancy check fails) ----
__global__ __launch_bounds__(256) void k_scan1(const float* __restrict__ delta,
                        const __hip_bfloat16* __restrict__ xs,
                        const float* __restrict__ dbc32, const float* __restrict__ A_log,
                        float* __restrict__ Atot, float* __restrict__ Btot){
  __shared__ float bcs[CHL*32];
  int t = threadIdx.x;
  int chunk = blockIdx.x >> 1;
  int e = ((blockIdx.x & 1) << 8) + t;
  int l0 = chunk*CHL;
  ((float4*)bcs)[t] = ((const float4*)&dbc32[l0*32])[t];
  float A[16];
  {
    const float4* al = (const float4*)&A_log[e*DS];
#pragma unroll
    for(int q=0;q<4;q++){
      float4 a = al[q];
      A[q*4+0] = -__expf(a.x); A[q*4+1] = -__expf(a.y);
      A[q*4+2] = -__expf(a.z); A[q*4+3] = -__expf(a.w);
    }
  }
  float carry[16], aprod[16];
#pragma unroll
  for(int n=0;n<16;n++){ carry[n]=0.f; aprod[n]=1.f; }
  __syncthreads();
#pragma unroll 2
  for(int li=0; li<CHL; li++){
    int l = l0 + li;
    float d  = delta[l*DI+e];
    float xv = bf2f(*(const unsigned short*)&xs[l*DI+e]);
    float dxv = d*xv;
    const float4* bp = (const float4*)&bcs[li*32];
    float4 b0=bp[0], b1=bp[1], b2=bp[2], b3=bp[3];
    float B[16] = {b0.x,b0.y,b0.z,b0.w, b1.x,b1.y,b1.z,b1.w,
                   b2.x,b2.y,b2.z,b2.w, b3.x,b3.y,b3.z,b3.w};
#pragma unroll
    for(int n=0;n<16;n++){
      float dA = __expf(d*A[n]);
      carry[n] = fmaf(carry[n], dA, dxv*B[n]);
      aprod[n] *= dA;
    }
  }
  float4* ap = (float4*)&Atot[chunk*8192 + e*DS];
  float4* bp = (float4*)&Btot[chunk*8192 + e*DS];
#pragma unroll
  for(int q=0;q<4;q++){
    ap[q] = make_float4(aprod[q*4],aprod[q*4+1],aprod[q*4+2],aprod[q*4+3]);
    bp[q] = make_float4(carry[q*4],carry[q*4+1],carry[q*4+2],carry[q*4+3]);
  }
}
__global__ void k_scan2(const float* __restrict__ Atot, const float* __restrict__ Btot,
                        float* __restrict__ h0){
  int tg = blockIdx.x*256 + threadIdx.x;
  float carry = 0.f;
  for(int c=0;c<NCH;c++){
    float a = Atot[c*8192+tg];
    float b = Btot[c*8192+tg];
    h0[c*8192+tg] = carry;
    carry = fmaf(carry, a, b);
  }
}
__global__ __launch_bounds__(256) void k_scan3(const float* __restrict__ delta,
                        const __hip_bfloat16* __restrict__ xs,
                        const float* __restrict__ dbc32, const float* __restrict__ A_log,
                        const float* __restrict__ Dp, const float* __restrict__ h0,
                        const __hip_bfloat16* __restrict__ xz, __hip_bfloat16* __restrict__ y){
  __shared__ float bcs[CHL*32];
  int t = threadIdx.x;
  int chunk = blockIdx.x >> 1;
  int e = ((blockIdx.x & 1) << 8) + t;
  int l0 = chunk*CHL;
  ((float4*)bcs)[t] = ((const float4*)&dbc32[l0*32])[t];
  float A[16];
  {
    const float4* al = (const float4*)&A_log[e*DS];
#pragma unroll
    for(int q=0;q<4;q++){
      float4 a = al[q];
      A[q*4+0] = -__expf(a.x); A[q*4+1] = -__expf(a.y);
      A[q*4+2] = -__expf(a.z); A[q*4+3] = -__expf(a.w);
    }
  }
  float carry[16];
  {
    const float4* hp = (const float4*)&h0[chunk*8192 + e*DS];
#pragma unroll
    for(int q=0;q<4;q++){
      float4 h = hp[q];
      carry[q*4+0]=h.x; carry[q*4+1]=h.y; carry[q*4+2]=h.z; carry[q*4+3]=h.w;
    }
  }
  float Dv = Dp[e];
  __syncthreads();
#pragma unroll 2
  for(int li=0; li<CHL; li++){
    int l = l0 + li;
    float d  = delta[l*DI+e];
    float xv = bf2f(*(const unsigned short*)&xs[l*DI+e]);
    float dxv = d*xv;
    const float4* bp = (const float4*)&bcs[li*32];
    float4 b0=bp[0], b1=bp[1], b2=bp[2], b3=bp[3];
    float4 c0=bp[4], c1=bp[5], c2=bp[6], c3=bp[7];
    float B[16] = {b0.x,b0.y,b0.z,b0.w, b1.x,b1.y,b1.z,b1.w,
                   b2.x,b2.y,b2.z,b2.w, b3.x,b3.y,b3.z,b3.w};
    float Cv[16] = {c0.x,c0.y,c0.z,c0.w, c1.x,c1.y,c1.z,c1.w,
                    c2.x,c2.y,c2.z,c2.w, c3.x,c3.y,c3.z,c3.w};
    float p[4] = {0.f,0.f,0.f,0.f};
#pragma unroll
    for(int n=0;n<16;n++){
      float dA = __expf(d*A[n]);
      carry[n] = fmaf(carry[n], dA, dxv*B[n]);
      p[n&3] = fmaf(carry[n], Cv[n], p[n&3]);
    }
    float ps = (p[0]+p[1]) + (p[2]+p[3]);
    float z = bf2f(*(const unsigned short*)&xz[l*1024 + 512 + e]);
    y[l*DI+e] = __float2bfloat16(fmaf(xv, Dv, ps) * silu_f(z));
  }
}

// ---- final: LN(128) -> @W2(128,1)+b2 -> tanh, one wave per row ----
__global__ void k_final(const float* __restrict__ h2, const float* __restrict__ g,
                        const float* __restrict__ b, const float* __restrict__ W2,
                        const float* __restrict__ b2, float* __restrict__ out){
  int lane = threadIdx.x&63;
  int wv = threadIdx.x>>6;
  int r = blockIdx.x*4 + wv;
  float v0 = h2[r*128+lane], v1 = h2[r*128+64+lane];
  float s = v0+v1, sq = v0*v0+v1*v1;
#pragma unroll
  for(int o=32;o;o>>=1){ s += __shfl_xor(s,o); sq += __shfl_xor(sq,o); }
  float mean = s*(1.0f/128), var = sq*(1.0f/128) - mean*mean;
  float rs = rsqrtf(var+1e-5f);
  float n0 = (v0-mean)*rs*g[lane]+b[lane];
  float n1 = (v1-mean)*rs*g[lane+64]+b[lane+64];
  float d = n0*W2[lane] + n1*W2[lane+64];
#pragma unroll
  for(int o=32;o;o>>=1) d += __shfl_xor(d,o);
  if(lane==0) out[r] = tanhf(d + b2[0]);
}

extern "C" void kernel_launch(void* const* d_in, const int* in_sizes, int n_in,
                              void* d_out, int out_size, void* d_ws, size_t ws_size,
                              hipStream_t stream){
  const float* x    = (const float*)d_in[0];
  const float* Win  = (const float*)d_in[1];
  const float* bin  = (const float*)d_in[2];
  const float* ln1g = (const float*)d_in[3];
  const float* ln1b = (const float*)d_in[4];
  const float* rmsw = (const float*)d_in[5];
  const float* inW  = (const float*)d_in[6];
  const float* convW= (const float*)d_in[7];
  const float* convB= (const float*)d_in[8];
  const float* xpW  = (const float*)d_in[9];
  const float* dtW  = (const float*)d_in[10];
  const float* dtB  = (const float*)d_in[11];
  const float* A_log= (const float*)d_in[12];
  const float* Dp   = (const float*)d_in[13];
  const float* outW = (const float*)d_in[14];
  const float* ln2g = (const float*)d_in[15];
  const float* ln2b = (const float*)d_in[16];
  const float* W1   = (const float*)d_in[17];
  const float* b1   = (const float*)d_in[18];
  const float* ln3g = (const float*)d_in[19];
  const float* ln3b = (const float*)d_in[20];
  const float* W2   = (const float*)d_in[21];
  const float* b2   = (const float*)d_in[22];
  float* out = (float*)d_out;
  float* ws = (float*)d_ws;
  float* u     = ws;                                          // 16384*256 f32
  __hip_bfloat16* hn_bf = (__hip_bfloat16*)(ws + 4194304);
  __hip_bfloat16* xz_bf = (__hip_bfloat16*)(ws + 8388608);    // 16384*1024 bf16
  float* dbc32 = ws + 16777216;                               // 16384*32 f32
  float* delta = ws + 17301504;                               // 16384*512 f32
  __hip_bfloat16* y_bf  = (__hip_bfloat16*)(ws + 25690112);   // 16384*512 bf16
  __hip_bfloat16* xs_bf = (__hip_bfloat16*)(ws + 29884416);   // 16384*512 bf16
  float* Atot  = ws + 34078720;                               // NCH*8192
  float* Btot  = ws + 38273024;                               // NCH*8192
  float* h0    = ws + 42467328;                               // NCH*8192
  float* h2    = u;                     // aliased (u dead after k_ln)
  __hip_bfloat16* inWt   = (__hip_bfloat16*)(ws + 46661632);  // 2*1024*256 bf16
  __hip_bfloat16* outWt  = (__hip_bfloat16*)(ws + 46923776);  // 2*256*512 bf16
  __hip_bfloat16* W1t    = (__hip_bfloat16*)(ws + 47054848);  // 128*256 bf16
  __hip_bfloat16* Wdbc_t = (__hip_bfloat16*)(ws + 47071232);  // 2*640*512 bf16

  int maxb = 0;
  hipOccupancyMaxActiveBlocksPerMultiprocessor(&maxb, (const void*)k_scanf, 256, 0);
  bool coop = (maxb >= 4);

  k_cvtw<<<3200,256,0,stream>>>(inW, outW, W1, inWt, outWt, W1t);
  k_wd<<<2560,256,0,stream>>>(xpW, dtW, Wdbc_t);
  k_input<<<L_SEQ,256,0,stream>>>(x,Win,bin,ln1g,ln1b,u);
  for(int i=0;i<2;i++){
    k_rms<<<L_SEQ,256,0,stream>>>(u, rmsw+i*DM, hn_bf);
    k_mgemm<0,__hip_bfloat16><<<dim3(8, L_SEQ/128),256,0,stream>>>(hn_bf, inWt+i*262144, nullptr, nullptr, xz_bf, nullptr, L_SEQ, DM, 1024, 1024);
    k_conv<<<(L_SEQ/CLB)*128/256,256,0,stream>>>(xz_bf, convW+i*DI*4, convB+i*DI, xs_bf);
    k_mgemm<4,float><<<dim3(5, L_SEQ/128),256,0,stream>>>(xs_bf, Wdbc_t+i*327680, dtB+i*DI, nullptr, delta, dbc32, L_SEQ, DI, 512, 544);
    if(coop){
      const float* del_p = delta;
      const __hip_bfloat16* xs_p = xs_bf;
      const float* dbc_p = dbc32;
      const float* alog_p = A_log + i*DI*DS;
      const float* dp_p = Dp + i*DI;
      const __hip_bfloat16* xz_p = xz_bf;
      __hip_bfloat16* y_p = y_bf;
      float* at_p = Atot; float* bt_p = Btot; float* h0_p = h0;
      void* kargs[10] = {&del_p,&xs_p,&dbc_p,&alog_p,&dp_p,&xz_p,&y_p,&at_p,&bt_p,&h0_p};
      hipLaunchCooperativeKernel((const void*)k_scanf, dim3(NCH*2), dim3(256), kargs, 0, stream);
    } else {
      k_scan1<<<NCH*2,256,0,stream>>>(delta, xs_bf, dbc32, A_log+i*DI*DS, Atot, Btot);
      k_scan2<<<32,256,0,stream>>>(Atot, Btot, h0);
      k_scan3<<<NCH*2,256,0,stream>>>(delta, xs_bf, dbc32, A_log+i*DI*DS, Dp+i*DI, h0, xz_bf, y_bf);
    }
    k_mgemm<1,float><<<dim3(2, L_SEQ/128),256,0,stream>>>(y_bf, outWt+i*131072, nullptr, u, u, nullptr, L_SEQ, DI, 256, 256);
  }
  k_ln<<<L_SEQ,256,0,stream>>>(u, ln2g, ln2b, hn_bf);
  k_mgemm<2,float><<<dim3(1, L_SEQ/128),256,0,stream>>>(hn_bf, W1t, b1, nullptr, h2, nullptr, L_SEQ, DM, 128, 128);
  k_final<<<L_SEQ/4,256,0,stream>>>(h2, ln3g, ln3b, W2, b2, out);
}

// Round 8
// 523.766 us; speedup vs baseline: 1.0718x; 1.0718x over previous
//
#include <hip/hip_runtime.h>
#include <hip/hip_bf16.h>
#include <math.h>

#define L_SEQ 16384
#define DM 256
#define DI 512
#define DS 16
#define NCH 512   // number of scan chunks
#define CHL 32    // chunk length (NCH*CHL == L_SEQ)
#define CLB 16    // conv: timesteps per thread

typedef __attribute__((ext_vector_type(8))) short short8v;
typedef __attribute__((ext_vector_type(4))) float f32x4;

__device__ __forceinline__ float warpSum(float v){
#pragma unroll
  for(int o=32;o;o>>=1) v += __shfl_xor(v,o);
  return v;
}
__device__ __forceinline__ float gelu_f(float x){
  float x3 = x*x*x;
  return 0.5f*x*(1.0f + tanhf(0.7978845608028654f*(x + 0.044715f*x3)));
}
__device__ __forceinline__ float silu_f(float x){
  return x / (1.0f + __expf(-x));
}
__device__ __forceinline__ float softplus_f(float x){
  return fmaxf(x,0.0f) + log1pf(__expf(-fabsf(x)));
}
__device__ __forceinline__ float bf2f(unsigned short u){
  return __uint_as_float(((unsigned int)u)<<16);
}
__device__ __forceinline__ void gload16(const void* g, void* l){
  __builtin_amdgcn_global_load_lds((const __attribute__((address_space(1))) void*)g,
                                   (__attribute__((address_space(3))) void*)l, 16, 0, 0);
}
__device__ __forceinline__ void stv(float* p, float v){ *p = v; }
__device__ __forceinline__ void stv(__hip_bfloat16* p, float v){ *p = __float2bfloat16(v); }

// r^(n+1) for n=0..15, ~16 muls, depth ~4 (replaces 16 quarter-rate exps)
__device__ __forceinline__ void powers16(float r, float* dA){
  float r2 = r*r;
  float r4 = r2*r2;
  float r8 = r4*r4;
  dA[0]=r;        dA[1]=r2;       dA[2]=r2*r;     dA[3]=r4;
  dA[4]=r4*r;     dA[5]=r4*r2;    dA[6]=r4*dA[2]; dA[7]=r8;
  dA[8]=r8*r;     dA[9]=r8*r2;    dA[10]=r8*dA[2];dA[11]=r8*r4;
  dA[12]=r8*dA[4];dA[13]=r8*dA[5];dA[14]=r8*dA[6];dA[15]=r8*r8;
}

// ---- weight convert + transpose to bf16: Wt[n][k] = bf16(W[k][n]) ----
__global__ void k_cvtw(const float* __restrict__ inW, const float* __restrict__ outW,
                       const float* __restrict__ W1, __hip_bfloat16* __restrict__ inWt,
                       __hip_bfloat16* __restrict__ outWt, __hip_bfloat16* __restrict__ W1t){
  int idx = blockIdx.x*256 + threadIdx.x;
  if(idx < 524288){                      // inW: 2 layers of [256][1024] -> [1024][256]
    int layer = idx >> 18;
    int r = idx & 262143;
    int n = r >> 8, k = r & 255;
    inWt[idx] = __float2bfloat16(inW[layer*262144 + k*1024 + n]);
  } else if(idx < 786432){               // outW: 2 layers of [512][256] -> [256][512]
    int j = idx - 524288;
    int layer = j >> 17;
    int r = j & 131071;
    int n = r >> 9, k = r & 511;
    outWt[j] = __float2bfloat16(outW[layer*131072 + k*256 + n]);
  } else if(idx < 819200){               // W1: [256][128] -> [128][256]
    int j = idx - 786432;
    int n = j >> 8, k = j & 255;
    W1t[j] = __float2bfloat16(W1[k*128 + n]);
  }
}

// ---- build merged delta|BC weight: Wdbc_t[layer][640][512]:
//      rows 0..511 = (xpW[:,:16] @ dtW)^T; rows 512..543 = xpW[:,16:48]^T; pad 0 ----
__global__ void k_wd(const float* __restrict__ xpW, const float* __restrict__ dtW,
                     __hip_bfloat16* __restrict__ Wdbc_t){
  int idx = blockIdx.x*256 + threadIdx.x;   // 2*640*512 = 655360
  if(idx >= 655360) return;
  int layer = idx / 327680;
  int r = idx % 327680;
  int n = r >> 9, k = r & 511;
  const float* xp = xpW + layer*512*48;
  float v;
  if(n < 512){
    const float* dt = dtW + layer*16*512;
    float s = 0.f;
#pragma unroll
    for(int j=0;j<16;j++) s = fmaf(xp[k*48+j], dt[j*512+n], s);
    v = s;
  } else if(n < 544){
    v = xp[k*48 + 16 + (n-512)];
  } else v = 0.f;
  Wdbc_t[idx] = __float2bfloat16(v);
}

// ---- input projection + LN + gelu: u = gelu(LN(x@Win + bin)) ----
__global__ void k_input(const float* __restrict__ x, const float* __restrict__ Win,
                        const float* __restrict__ bin, const float* __restrict__ g,
                        const float* __restrict__ b, float* __restrict__ u){
  int r = blockIdx.x, t = threadIdx.x;
  __shared__ float xr[32];
  __shared__ float sA[4], sB[4];
  if(t<32) xr[t] = x[r*32+t];
  __syncthreads();
  float v = bin[t];
#pragma unroll
  for(int k=0;k<32;k++) v = fmaf(xr[k], Win[k*DM+t], v);
  float s = warpSum(v), sq = warpSum(v*v);
  if((t&63)==0){ sA[t>>6]=s; sB[t>>6]=sq; }
  __syncthreads();
  float mean = (sA[0]+sA[1]+sA[2]+sA[3])*(1.0f/DM);
  float msq  = (sB[0]+sB[1]+sB[2]+sB[3])*(1.0f/DM);
  float var = msq - mean*mean;
  float nv = (v-mean)*rsqrtf(var+1e-5f)*g[t]+b[t];
  u[r*DM+t] = gelu_f(nv);
}

// ---- rmsnorm over 256 -> bf16 ----
__global__ void k_rms(const float* __restrict__ u, const float* __restrict__ w,
                      __hip_bfloat16* __restrict__ o){
  int r=blockIdx.x, t=threadIdx.x;
  __shared__ float sA[4];
  float v = u[r*DM+t];
  float sq = warpSum(v*v);
  if((t&63)==0) sA[t>>6]=sq;
  __syncthreads();
  float ms = (sA[0]+sA[1]+sA[2]+sA[3])*(1.0f/DM);
  o[r*DM+t] = __float2bfloat16(v*rsqrtf(ms+1e-5f)*w[t]);
}

// ---- layernorm over 256 -> bf16 ----
__global__ void k_ln(const float* __restrict__ u, const float* __restrict__ g,
                     const float* __restrict__ b, __hip_bfloat16* __restrict__ o){
  int r=blockIdx.x, t=threadIdx.x;
  __shared__ float sA[4], sB[4];
  float v = u[r*DM+t];
  float s = warpSum(v), sq = warpSum(v*v);
  if((t&63)==0){ sA[t>>6]=s; sB[t>>6]=sq; }
  __syncthreads();
  float mean = (sA[0]+sA[1]+sA[2]+sA[3])*(1.0f/DM);
  float msq  = (sB[0]+sB[1]+sB[2]+sB[3])*(1.0f/DM);
  float var = msq - mean*mean;
  o[r*DM+t] = __float2bfloat16((v-mean)*rsqrtf(var+1e-5f)*g[t]+b[t]);
}

// ---- bf16 MFMA GEMM: C[M,:](OT, stride ldc) = A[M,K](bf16) @ Wt[N,K](bf16)^T
//      EPI: 0=store, 1=+R, 2=gelu(+bias), 3=softplus(+bias),
//      4=split delta|BC: col<512 -> softplus(+bias)->C; 512<=col<544 -> C2. ----
template<int EPI, typename OT>
__global__ __launch_bounds__(256) void k_mgemm(const __hip_bfloat16* __restrict__ A,
    const __hip_bfloat16* __restrict__ Wt, const float* __restrict__ bias,
    const float* __restrict__ R, OT* __restrict__ C, float* __restrict__ C2,
    int M, int K, int ldc, int Nout){
  __shared__ short As[8192];   // [128 rows][64 k] bf16, slot-swizzled
  __shared__ short Bs[8192];
  int t = threadIdx.x, lane = t&63, wave = t>>6;
  int m0 = blockIdx.y*128, n0 = blockIdx.x*128;
  int wm = (wave>>1)*64, wn = (wave&1)*64;
  f32x4 acc[4][4] = {};
  // staging descriptors: LDS linear dest (base+lane*16), pre-swizzled global src
  int soff[4], srow[4], scol[4];
#pragma unroll
  for(int c=0;c<4;c++){
    int off = (wave*4+c)*1024 + lane*16;   // byte offset in 16KB tile
    int row = off>>7;                       // 128B per row
    int sl  = ((off>>4)&7) ^ (row&7);       // logical 16B slot for this phys slot
    soff[c]=off; srow[c]=row; scol[c]=sl*8;
  }
  for(int kt=0; kt<K; kt+=64){
#pragma unroll
    for(int c=0;c<4;c++){
      gload16(&A [(m0+srow[c])*K + kt + scol[c]], (char*)As + soff[c]);
      gload16(&Wt[(n0+srow[c])*K + kt + scol[c]], (char*)Bs + soff[c]);
    }
    asm volatile("s_waitcnt vmcnt(0)" ::: "memory");
    __syncthreads();
#pragma unroll
    for(int ks=0; ks<2; ks++){
      short8v a[4], b[4];
      int k8 = ks*4 + (lane>>4);
#pragma unroll
      for(int i=0;i<4;i++){
        int lr = wm + i*16 + (lane&15);
        a[i] = *(const short8v*)&As[lr*64 + (k8 ^ (lr&7))*8];
      }
#pragma unroll
      for(int j=0;j<4;j++){
        int lr = wn + j*16 + (lane&15);
        b[j] = *(const short8v*)&Bs[lr*64 + (k8 ^ (lr&7))*8];
      }
#pragma unroll
      for(int i=0;i<4;i++)
#pragma unroll
        for(int j=0;j<4;j++)
          acc[i][j] = __builtin_amdgcn_mfma_f32_16x16x32_bf16(a[i], b[j], acc[i][j], 0,0,0);
    }
    __syncthreads();
  }
#pragma unroll
  for(int i=0;i<4;i++){
    int grow0 = m0 + wm + i*16 + (lane>>4)*4;
#pragma unroll
    for(int j=0;j<4;j++){
      int gcol = n0 + wn + j*16 + (lane&15);
      if(gcol < Nout){
#pragma unroll
        for(int r=0;r<4;r++){
          float v = acc[i][j][r];
          int grow = grow0 + r;
          if(EPI==4){
            if(gcol < 512) stv(&C[grow*ldc+gcol], softplus_f(v + bias[gcol]));
            else           C2[grow*32 + (gcol-512)] = v;
          } else {
            if(EPI==1) v += R[grow*ldc+gcol];
            if(EPI==2) v = gelu_f(v + bias[gcol]);
            if(EPI==3) v = softplus_f(v + bias[gcol]);
            stv(&C[grow*ldc+gcol], v);
          }
        }
      }
    }
  }
}

// ---- causal depthwise conv (k=4) + bias + silu, sliding window. ----
__global__ __launch_bounds__(256) void k_conv(const __hip_bfloat16* __restrict__ xz,
                       const float* __restrict__ cw, const float* __restrict__ cb,
                       __hip_bfloat16* __restrict__ xs_bf){
  int idx = blockIdx.x*256 + threadIdx.x;   // (L_SEQ/CLB)*128 threads
  int cg = idx & 127, lb = idx >> 7;
  int c4 = cg*4;
  int l0 = lb*CLB;
  float w[4][4], bias[4];
#pragma unroll
  for(int j=0;j<4;j++){
    float4 wv = *(const float4*)&cw[(c4+j)*4];
    w[j][0]=wv.x; w[j][1]=wv.y; w[j][2]=wv.z; w[j][3]=wv.w;
  }
  { float4 bv = *(const float4*)&cb[c4];
    bias[0]=bv.x; bias[1]=bv.y; bias[2]=bv.z; bias[3]=bv.w; }
  float xm0[4], xm1[4], xm2[4];   // x[l-3], x[l-2], x[l-1]
#pragma unroll
  for(int j=0;j<4;j++){ xm0[j]=0.f; xm1[j]=0.f; xm2[j]=0.f; }
  if(l0 >= 3){
    ushort4 r0 = *(const ushort4*)&xz[(l0-3)*1024 + c4];
    ushort4 r1 = *(const ushort4*)&xz[(l0-2)*1024 + c4];
    ushort4 r2 = *(const ushort4*)&xz[(l0-1)*1024 + c4];
    xm0[0]=bf2f(r0.x); xm0[1]=bf2f(r0.y); xm0[2]=bf2f(r0.z); xm0[3]=bf2f(r0.w);
    xm1[0]=bf2f(r1.x); xm1[1]=bf2f(r1.y); xm1[2]=bf2f(r1.z); xm1[3]=bf2f(r1.w);
    xm2[0]=bf2f(r2.x); xm2[1]=bf2f(r2.y); xm2[2]=bf2f(r2.z); xm2[3]=bf2f(r2.w);
  }
  for(int l=l0; l<l0+CLB; l++){
    ushort4 rc = *(const ushort4*)&xz[l*1024 + c4];
    float xc[4] = {bf2f(rc.x), bf2f(rc.y), bf2f(rc.z), bf2f(rc.w)};
    __hip_bfloat16 ob[4];
#pragma unroll
    for(int j=0;j<4;j++){
      float acc = bias[j];
      acc = fmaf(xm0[j], w[j][0], acc);
      acc = fmaf(xm1[j], w[j][1], acc);
      acc = fmaf(xm2[j], w[j][2], acc);
      acc = fmaf(xc[j],  w[j][3], acc);
      ob[j] = __float2bfloat16(silu_f(acc));
    }
    *(uint2*)&xs_bf[l*DI + c4] = *(uint2*)ob;
#pragma unroll
    for(int j=0;j<4;j++){ xm0[j]=xm1[j]; xm1[j]=xm2[j]; xm2[j]=xc[j]; }
  }
}

// ---- scan phase 1: per-chunk (prod dA, local carry) per state.
//      Fast path: A[n] == (n+1)*A[0] -> dA[n] = r^(n+1), r = exp(d*A[0]). ----
__global__ __launch_bounds__(256) void k_scan1(const float* __restrict__ delta,
                        const __hip_bfloat16* __restrict__ xs,
                        const float* __restrict__ dbc32, const float* __restrict__ A_log,
                        float* __restrict__ Atot, float* __restrict__ Btot){
  __shared__ float bcs[CHL*32];
  int t = threadIdx.x;
  int chunk = blockIdx.x >> 1;
  int e = ((blockIdx.x & 1) << 8) + t;
  int l0 = chunk*CHL;
  ((float4*)bcs)[t] = ((const float4*)&dbc32[l0*32])[t];
  float A[16];
  {
    const float4* al = (const float4*)&A_log[e*DS];
#pragma unroll
    for(int q=0;q<4;q++){
      float4 a = al[q];
      A[q*4+0] = -__expf(a.x); A[q*4+1] = -__expf(a.y);
      A[q*4+2] = -__expf(a.z); A[q*4+3] = -__expf(a.w);
    }
  }
  bool pf = true;
#pragma unroll
  for(int n=1;n<16;n++) pf = pf && (fabsf(A[n] - (n+1)*A[0]) <= 1e-4f*fabsf(A[n]));
  float carry[16], aprod[16];
#pragma unroll
  for(int n=0;n<16;n++){ carry[n]=0.f; aprod[n]=1.f; }
  __syncthreads();
  if(pf){
    float A0 = A[0];
#pragma unroll 2
    for(int li=0; li<CHL; li++){
      int l = l0 + li;
      float d  = delta[l*DI+e];
      float xv = bf2f(*(const unsigned short*)&xs[l*DI+e]);
      float dxv = d*xv;
      const float4* bp = (const float4*)&bcs[li*32];
      float4 b0=bp[0], b1=bp[1], b2=bp[2], b3=bp[3];
      float B[16] = {b0.x,b0.y,b0.z,b0.w, b1.x,b1.y,b1.z,b1.w,
                     b2.x,b2.y,b2.z,b2.w, b3.x,b3.y,b3.z,b3.w};
      float r = __expf(d*A0);
      float dA[16]; powers16(r, dA);
#pragma unroll
      for(int n=0;n<16;n++){
        carry[n] = fmaf(carry[n], dA[n], dxv*B[n]);
        aprod[n] *= dA[n];
      }
    }
  } else {
#pragma unroll 2
    for(int li=0; li<CHL; li++){
      int l = l0 + li;
      float d  = delta[l*DI+e];
      float xv = bf2f(*(const unsigned short*)&xs[l*DI+e]);
      float dxv = d*xv;
      const float4* bp = (const float4*)&bcs[li*32];
      float4 b0=bp[0], b1=bp[1], b2=bp[2], b3=bp[3];
      float B[16] = {b0.x,b0.y,b0.z,b0.w, b1.x,b1.y,b1.z,b1.w,
                     b2.x,b2.y,b2.z,b2.w, b3.x,b3.y,b3.z,b3.w};
#pragma unroll
      for(int n=0;n<16;n++){
        float dA = __expf(d*A[n]);
        carry[n] = fmaf(carry[n], dA, dxv*B[n]);
        aprod[n] *= dA;
      }
    }
  }
  float4* ap = (float4*)&Atot[chunk*8192 + e*DS];
  float4* bp = (float4*)&Btot[chunk*8192 + e*DS];
#pragma unroll
  for(int q=0;q<4;q++){
    ap[q] = make_float4(aprod[q*4],aprod[q*4+1],aprod[q*4+2],aprod[q*4+3]);
    bp[q] = make_float4(carry[q*4],carry[q*4+1],carry[q*4+2],carry[q*4+3]);
  }
}

// ---- scan phase 2: carry-in per chunk (h0 aliases Btot: load-before-store) ----
__global__ void k_scan2(const float* __restrict__ Atot, const float* __restrict__ Btot,
                        float* __restrict__ h0){
  int tg = blockIdx.x*256 + threadIdx.x;
  float carry = 0.f;
  for(int c=0;c<NCH;c++){
    float a = Atot[c*8192+tg];
    float b = Btot[c*8192+tg];
    h0[c*8192+tg] = carry;
    carry = fmaf(carry, a, b);
  }
}

// ---- scan phase 3: replay with carry-in, y = (sum h*C + xs*D)*silu(z) -> bf16 ----
__global__ __launch_bounds__(256) void k_scan3(const float* __restrict__ delta,
                        const __hip_bfloat16* __restrict__ xs,
                        const float* __restrict__ dbc32, const float* __restrict__ A_log,
                        const float* __restrict__ Dp, const float* __restrict__ h0,
                        const __hip_bfloat16* __restrict__ xz, __hip_bfloat16* __restrict__ y){
  __shared__ float bcs[CHL*32];
  int t = threadIdx.x;
  int chunk = blockIdx.x >> 1;
  int e = ((blockIdx.x & 1) << 8) + t;
  int l0 = chunk*CHL;
  ((float4*)bcs)[t] = ((const float4*)&dbc32[l0*32])[t];
  float A[16];
  {
    const float4* al = (const float4*)&A_log[e*DS];
#pragma unroll
    for(int q=0;q<4;q++){
      float4 a = al[q];
      A[q*4+0] = -__expf(a.x); A[q*4+1] = -__expf(a.y);
      A[q*4+2] = -__expf(a.z); A[q*4+3] = -__expf(a.w);
    }
  }
  bool pf = true;
#pragma unroll
  for(int n=1;n<16;n++) pf = pf && (fabsf(A[n] - (n+1)*A[0]) <= 1e-4f*fabsf(A[n]));
  float carry[16];
  {
    const float4* hp = (const float4*)&h0[chunk*8192 + e*DS];
#pragma unroll
    for(int q=0;q<4;q++){
      float4 h = hp[q];
      carry[q*4+0]=h.x; carry[q*4+1]=h.y; carry[q*4+2]=h.z; carry[q*4+3]=h.w;
    }
  }
  float Dv = Dp[e];
  __syncthreads();
  if(pf){
    float A0 = A[0];
#pragma unroll 2
    for(int li=0; li<CHL; li++){
      int l = l0 + li;
      float d  = delta[l*DI+e];
      float xv = bf2f(*(const unsigned short*)&xs[l*DI+e]);
      float dxv = d*xv;
      const float4* bp = (const float4*)&bcs[li*32];
      float4 b0=bp[0], b1=bp[1], b2=bp[2], b3=bp[3];
      float4 c0=bp[4], c1=bp[5], c2=bp[6], c3=bp[7];
      float B[16] = {b0.x,b0.y,b0.z,b0.w, b1.x,b1.y,b1.z,b1.w,
                     b2.x,b2.y,b2.z,b2.w, b3.x,b3.y,b3.z,b3.w};
      float Cv[16] = {c0.x,c0.y,c0.z,c0.w, c1.x,c1.y,c1.z,c1.w,
                      c2.x,c2.y,c2.z,c2.w, c3.x,c3.y,c3.z,c3.w};
      float r = __expf(d*A0);
      float dA[16]; powers16(r, dA);
      float p[4] = {0.f,0.f,0.f,0.f};
#pragma unroll
      for(int n=0;n<16;n++){
        carry[n] = fmaf(carry[n], dA[n], dxv*B[n]);
        p[n&3] = fmaf(carry[n], Cv[n], p[n&3]);
      }
      float ps = (p[0]+p[1]) + (p[2]+p[3]);
      float z = bf2f(*(const unsigned short*)&xz[l*1024 + 512 + e]);
      y[l*DI+e] = __float2bfloat16(fmaf(xv, Dv, ps) * silu_f(z));
    }
  } else {
#pragma unroll 2
    for(int li=0; li<CHL; li++){
      int l = l0 + li;
      float d  = delta[l*DI+e];
      float xv = bf2f(*(const unsigned short*)&xs[l*DI+e]);
      float dxv = d*xv;
      const float4* bp = (const float4*)&bcs[li*32];
      float4 b0=bp[0], b1=bp[1], b2=bp[2], b3=bp[3];
      float4 c0=bp[4], c1=bp[5], c2=bp[6], c3=bp[7];
      float B[16] = {b0.x,b0.y,b0.z,b0.w, b1.x,b1.y,b1.z,b1.w,
                     b2.x,b2.y,b2.z,b2.w, b3.x,b3.y,b3.z,b3.w};
      float Cv[16] = {c0.x,c0.y,c0.z,c0.w, c1.x,c1.y,c1.z,c1.w,
                      c2.x,c2.y,c2.z,c2.w, c3.x,c3.y,c3.z,c3.w};
      float p[4] = {0.f,0.f,0.f,0.f};
#pragma unroll
      for(int n=0;n<16;n++){
        float dA = __expf(d*A[n]);
        carry[n] = fmaf(carry[n], dA, dxv*B[n]);
        p[n&3] = fmaf(carry[n], Cv[n], p[n&3]);
      }
      float ps = (p[0]+p[1]) + (p[2]+p[3]);
      float z = bf2f(*(const unsigned short*)&xz[l*1024 + 512 + e]);
      y[l*DI+e] = __float2bfloat16(fmaf(xv, Dv, ps) * silu_f(z));
    }
  }
}

// ---- final: LN(128) -> @W2(128,1)+b2 -> tanh, one wave per row ----
__global__ void k_final(const float* __restrict__ h2, const float* __restrict__ g,
                        const float* __restrict__ b, const float* __restrict__ W2,
                        const float* __restrict__ b2, float* __restrict__ out){
  int lane = threadIdx.x&63;
  int wv = threadIdx.x>>6;
  int r = blockIdx.x*4 + wv;
  float v0 = h2[r*128+lane], v1 = h2[r*128+64+lane];
  float s = v0+v1, sq = v0*v0+v1*v1;
#pragma unroll
  for(int o=32;o;o>>=1){ s += __shfl_xor(s,o); sq += __shfl_xor(sq,o); }
  float mean = s*(1.0f/128), var = sq*(1.0f/128) - mean*mean;
  float rs = rsqrtf(var+1e-5f);
  float n0 = (v0-mean)*rs*g[lane]+b[lane];
  float n1 = (v1-mean)*rs*g[lane+64]+b[lane+64];
  float d = n0*W2[lane] + n1*W2[lane+64];
#pragma unroll
  for(int o=32;o;o>>=1) d += __shfl_xor(d,o);
  if(lane==0) out[r] = tanhf(d + b2[0]);
}

extern "C" void kernel_launch(void* const* d_in, const int* in_sizes, int n_in,
                              void* d_out, int out_size, void* d_ws, size_t ws_size,
                              hipStream_t stream){
  const float* x    = (const float*)d_in[0];
  const float* Win  = (const float*)d_in[1];
  const float* bin  = (const float*)d_in[2];
  const float* ln1g = (const float*)d_in[3];
  const float* ln1b = (const float*)d_in[4];
  const float* rmsw = (const float*)d_in[5];
  const float* inW  = (const float*)d_in[6];
  const float* convW= (const float*)d_in[7];
  const float* convB= (const float*)d_in[8];
  const float* xpW  = (const float*)d_in[9];
  const float* dtW  = (const float*)d_in[10];
  const float* dtB  = (const float*)d_in[11];
  const float* A_log= (const float*)d_in[12];
  const float* Dp   = (const float*)d_in[13];
  const float* outW = (const float*)d_in[14];
  const float* ln2g = (const float*)d_in[15];
  const float* ln2b = (const float*)d_in[16];
  const float* W1   = (const float*)d_in[17];
  const float* b1   = (const float*)d_in[18];
  const float* ln3g = (const float*)d_in[19];
  const float* ln3b = (const float*)d_in[20];
  const float* W2   = (const float*)d_in[21];
  const float* b2   = (const float*)d_in[22];
  float* out = (float*)d_out;
  float* ws = (float*)d_ws;
  float* u     = ws;                                          // 16384*256 f32
  __hip_bfloat16* hn_bf = (__hip_bfloat16*)(ws + 4194304);
  __hip_bfloat16* xz_bf = (__hip_bfloat16*)(ws + 8388608);    // 16384*1024 bf16
  float* dbc32 = ws + 16777216;                               // 16384*32 f32
  float* delta = ws + 17301504;                               // 16384*512 f32
  __hip_bfloat16* y_bf  = (__hip_bfloat16*)(ws + 25690112);   // 16384*512 bf16
  __hip_bfloat16* xs_bf = (__hip_bfloat16*)(ws + 29884416);   // 16384*512 bf16
  float* Atot  = ws + 34078720;                               // NCH*8192
  float* Btot  = ws + 38273024;                               // NCH*8192
  float* h0    = Btot;                  // aliased (scan2 loads before store)
  float* h2    = u;                     // aliased (u dead after k_ln)
  __hip_bfloat16* inWt   = (__hip_bfloat16*)(ws + 42467328);  // 2*1024*256 bf16
  __hip_bfloat16* outWt  = (__hip_bfloat16*)(ws + 42729472);  // 2*256*512 bf16
  __hip_bfloat16* W1t    = (__hip_bfloat16*)(ws + 42860544);  // 128*256 bf16
  __hip_bfloat16* Wdbc_t = (__hip_bfloat16*)(ws + 42876928);  // 2*640*512 bf16

  k_cvtw<<<3200,256,0,stream>>>(inW, outW, W1, inWt, outWt, W1t);
  k_wd<<<2560,256,0,stream>>>(xpW, dtW, Wdbc_t);
  k_input<<<L_SEQ,256,0,stream>>>(x,Win,bin,ln1g,ln1b,u);
  for(int i=0;i<2;i++){
    k_rms<<<L_SEQ,256,0,stream>>>(u, rmsw+i*DM, hn_bf);
    k_mgemm<0,__hip_bfloat16><<<dim3(8, L_SEQ/128),256,0,stream>>>(hn_bf, inWt+i*262144, nullptr, nullptr, xz_bf, nullptr, L_SEQ, DM, 1024, 1024);
    k_conv<<<(L_SEQ/CLB)*128/256,256,0,stream>>>(xz_bf, convW+i*DI*4, convB+i*DI, xs_bf);
    k_mgemm<4,float><<<dim3(5, L_SEQ/128),256,0,stream>>>(xs_bf, Wdbc_t+i*327680, dtB+i*DI, nullptr, delta, dbc32, L_SEQ, DI, 512, 544);
    k_scan1<<<NCH*2,256,0,stream>>>(delta, xs_bf, dbc32, A_log+i*DI*DS, Atot, Btot);
    k_scan2<<<32,256,0,stream>>>(Atot, Btot, h0);
    k_scan3<<<NCH*2,256,0,stream>>>(delta, xs_bf, dbc32, A_log+i*DI*DS, Dp+i*DI, h0, xz_bf, y_bf);
    k_mgemm<1,float><<<dim3(2, L_SEQ/128),256,0,stream>>>(y_bf, outWt+i*131072, nullptr, u, u, nullptr, L_SEQ, DI, 256, 256);
  }
  k_ln<<<L_SEQ,256,0,stream>>>(u, ln2g, ln2b, hn_bf);
  k_mgemm<2,float><<<dim3(1, L_SEQ/128),256,0,stream>>>(hn_bf, W1t, b1, nullptr, h2, nullptr, L_SEQ, DM, 128, 128);
  k_final<<<L_SEQ/4,256,0,stream>>>(h2, ln3g, ln3b, W2, b2, out);
}

// Round 9
// 485.494 us; speedup vs baseline: 1.1563x; 1.0788x over previous
//
#include <hip/hip_runtime.h>
#include <hip/hip_bf16.h>
#include <math.h>

#define L_SEQ 16384
#define DM 256
#define DI 512
#define DS 16
#define NCH 512   // number of scan chunks
#define CHL 32    // chunk length (NCH*CHL == L_SEQ)
#define CLB 16    // conv: timesteps per thread

typedef __attribute__((ext_vector_type(8))) short short8v;
typedef __attribute__((ext_vector_type(4))) float f32x4;

__device__ __forceinline__ float warpSum(float v){
#pragma unroll
  for(int o=32;o;o>>=1) v += __shfl_xor(v,o);
  return v;
}
__device__ __forceinline__ float gelu_f(float x){
  float x3 = x*x*x;
  return 0.5f*x*(1.0f + tanhf(0.7978845608028654f*(x + 0.044715f*x3)));
}
__device__ __forceinline__ float silu_f(float x){
  return x / (1.0f + __expf(-x));
}
__device__ __forceinline__ float softplus_f(float x){
  return fmaxf(x,0.0f) + log1pf(__expf(-fabsf(x)));
}
__device__ __forceinline__ float bf2f(unsigned short u){
  return __uint_as_float(((unsigned int)u)<<16);
}
__device__ __forceinline__ void gload16(const void* g, void* l){
  __builtin_amdgcn_global_load_lds((const __attribute__((address_space(1))) void*)g,
                                   (__attribute__((address_space(3))) void*)l, 16, 0, 0);
}
__device__ __forceinline__ void stv(float* p, float v){ *p = v; }
__device__ __forceinline__ void stv(__hip_bfloat16* p, float v){ *p = __float2bfloat16(v); }

// r^(n+1) for n=0..15, ~16 muls, depth ~4 (replaces 16 quarter-rate exps)
__device__ __forceinline__ void powers16(float r, float* dA){
  float r2 = r*r;
  float r4 = r2*r2;
  float r8 = r4*r4;
  dA[0]=r;        dA[1]=r2;       dA[2]=r2*r;     dA[3]=r4;
  dA[4]=r4*r;     dA[5]=r4*r2;    dA[6]=r4*dA[2]; dA[7]=r8;
  dA[8]=r8*r;     dA[9]=r8*r2;    dA[10]=r8*dA[2];dA[11]=r8*r4;
  dA[12]=r8*dA[4];dA[13]=r8*dA[5];dA[14]=r8*dA[6];dA[15]=r8*r8;
}

// ---- weight convert + transpose to bf16: Wt[n][k] = bf16(W[k][n]) ----
__global__ void k_cvtw(const float* __restrict__ inW, const float* __restrict__ outW,
                       const float* __restrict__ W1, __hip_bfloat16* __restrict__ inWt,
                       __hip_bfloat16* __restrict__ outWt, __hip_bfloat16* __restrict__ W1t){
  int idx = blockIdx.x*256 + threadIdx.x;
  if(idx < 524288){                      // inW: 2 layers of [256][1024] -> [1024][256]
    int layer = idx >> 18;
    int r = idx & 262143;
    int n = r >> 8, k = r & 255;
    inWt[idx] = __float2bfloat16(inW[layer*262144 + k*1024 + n]);
  } else if(idx < 786432){               // outW: 2 layers of [512][256] -> [256][512]
    int j = idx - 524288;
    int layer = j >> 17;
    int r = j & 131071;
    int n = r >> 9, k = r & 511;
    outWt[j] = __float2bfloat16(outW[layer*131072 + k*256 + n]);
  } else if(idx < 819200){               // W1: [256][128] -> [128][256]
    int j = idx - 786432;
    int n = j >> 8, k = j & 255;
    W1t[j] = __float2bfloat16(W1[k*128 + n]);
  }
}

// ---- build merged delta|BC weight: Wdbc_t[layer][640][512] ----
__global__ void k_wd(const float* __restrict__ xpW, const float* __restrict__ dtW,
                     __hip_bfloat16* __restrict__ Wdbc_t){
  int idx = blockIdx.x*256 + threadIdx.x;   // 2*640*512 = 655360
  if(idx >= 655360) return;
  int layer = idx / 327680;
  int r = idx % 327680;
  int n = r >> 9, k = r & 511;
  const float* xp = xpW + layer*512*48;
  float v;
  if(n < 512){
    const float* dt = dtW + layer*16*512;
    float s = 0.f;
#pragma unroll
    for(int j=0;j<16;j++) s = fmaf(xp[k*48+j], dt[j*512+n], s);
    v = s;
  } else if(n < 544){
    v = xp[k*48 + 16 + (n-512)];
  } else v = 0.f;
  Wdbc_t[idx] = __float2bfloat16(v);
}

// ---- input projection + LN + gelu: u = gelu(LN(x@Win + bin)) ----
__global__ void k_input(const float* __restrict__ x, const float* __restrict__ Win,
                        const float* __restrict__ bin, const float* __restrict__ g,
                        const float* __restrict__ b, float* __restrict__ u){
  int r = blockIdx.x, t = threadIdx.x;
  __shared__ float xr[32];
  __shared__ float sA[4], sB[4];
  if(t<32) xr[t] = x[r*32+t];
  __syncthreads();
  float v = bin[t];
#pragma unroll
  for(int k=0;k<32;k++) v = fmaf(xr[k], Win[k*DM+t], v);
  float s = warpSum(v), sq = warpSum(v*v);
  if((t&63)==0){ sA[t>>6]=s; sB[t>>6]=sq; }
  __syncthreads();
  float mean = (sA[0]+sA[1]+sA[2]+sA[3])*(1.0f/DM);
  float msq  = (sB[0]+sB[1]+sB[2]+sB[3])*(1.0f/DM);
  float var = msq - mean*mean;
  float nv = (v-mean)*rsqrtf(var+1e-5f)*g[t]+b[t];
  u[r*DM+t] = gelu_f(nv);
}

// ---- rmsnorm over 256 -> bf16 ----
__global__ void k_rms(const float* __restrict__ u, const float* __restrict__ w,
                      __hip_bfloat16* __restrict__ o){
  int r=blockIdx.x, t=threadIdx.x;
  __shared__ float sA[4];
  float v = u[r*DM+t];
  float sq = warpSum(v*v);
  if((t&63)==0) sA[t>>6]=sq;
  __syncthreads();
  float ms = (sA[0]+sA[1]+sA[2]+sA[3])*(1.0f/DM);
  o[r*DM+t] = __float2bfloat16(v*rsqrtf(ms+1e-5f)*w[t]);
}

// ---- layernorm over 256 -> bf16 ----
__global__ void k_ln(const float* __restrict__ u, const float* __restrict__ g,
                     const float* __restrict__ b, __hip_bfloat16* __restrict__ o){
  int r=blockIdx.x, t=threadIdx.x;
  __shared__ float sA[4], sB[4];
  float v = u[r*DM+t];
  float s = warpSum(v), sq = warpSum(v*v);
  if((t&63)==0){ sA[t>>6]=s; sB[t>>6]=sq; }
  __syncthreads();
  float mean = (sA[0]+sA[1]+sA[2]+sA[3])*(1.0f/DM);
  float msq  = (sB[0]+sB[1]+sB[2]+sB[3])*(1.0f/DM);
  float var = msq - mean*mean;
  o[r*DM+t] = __float2bfloat16((v-mean)*rsqrtf(var+1e-5f)*g[t]+b[t]);
}

// ---- bf16 MFMA GEMM, double-buffered + counted-vmcnt pipeline + XCD tile remap.
//      C[M,:](OT, stride ldc) = A[M,K](bf16) @ Wt[N,K](bf16)^T
//      EPI: 0=store, 1=+R, 2=gelu(+bias), 3=softplus(+bias),
//      4=split delta|BC: col<512 -> softplus(+bias)->C; 512<=col<544 -> C2. ----
template<int EPI, typename OT>
__global__ __launch_bounds__(256) void k_mgemm(const __hip_bfloat16* __restrict__ A,
    const __hip_bfloat16* __restrict__ Wt, const float* __restrict__ bias,
    const float* __restrict__ R, OT* __restrict__ C, float* __restrict__ C2,
    int M, int K, int ldc, int Nout){
  __shared__ short As[2][8192];   // [buf][128 rows][64 k] bf16, slot-swizzled
  __shared__ short Bs[2][8192];
  int t = threadIdx.x, lane = t&63, wave = t>>6;
  // XCD-aware tile remap: all N-blocks of a y-panel group land on one XCD
  // (HW: block f runs on XCD f%8; give XCD k the y-panels [k*gy/8,(k+1)*gy/8))
  int gx = gridDim.x;
  int f = blockIdx.y*gx + blockIdx.x;
  int s = f >> 3;
  int sy = s/gx;
  int yb = (f&7)*(gridDim.y>>3) + sy;
  int xb = s - sy*gx;
  int m0 = yb*128, n0 = xb*128;
  int wm = (wave>>1)*64, wn = (wave&1)*64;
  f32x4 acc[4][4] = {};
  // staging descriptors: LDS linear dest (base+lane*16), pre-swizzled global src
  int soff[4], srow[4], scol[4];
#pragma unroll
  for(int c=0;c<4;c++){
    int off = (wave*4+c)*1024 + lane*16;   // byte offset in 16KB tile
    int row = off>>7;                       // 128B per row
    int sl  = ((off>>4)&7) ^ (row&7);       // logical 16B slot for this phys slot
    soff[c]=off; srow[c]=row; scol[c]=sl*8;
  }
  int nk = K >> 6;
  // prologue: stage tile 0 into buffer 0
#pragma unroll
  for(int c=0;c<4;c++){
    gload16(&A [(m0+srow[c])*K + scol[c]], (char*)As[0] + soff[c]);
    gload16(&Wt[(n0+srow[c])*K + scol[c]], (char*)Bs[0] + soff[c]);
  }
  for(int ki=0; ki<nk; ki++){
    int cur = ki & 1;
    if(ki+1 < nk){
      int kt = (ki+1)<<6;
#pragma unroll
      for(int c=0;c<4;c++){
        gload16(&A [(m0+srow[c])*K + kt + scol[c]], (char*)As[cur^1] + soff[c]);
        gload16(&Wt[(n0+srow[c])*K + kt + scol[c]], (char*)Bs[cur^1] + soff[c]);
      }
      asm volatile("s_waitcnt vmcnt(8)" ::: "memory");   // tile ki landed, next 8 in flight
    } else {
      asm volatile("s_waitcnt vmcnt(0)" ::: "memory");
    }
    __builtin_amdgcn_s_barrier();            // all waves' tile-ki stores visible
    asm volatile("" ::: "memory");
    const short* Asc = As[cur];
    const short* Bsc = Bs[cur];
#pragma unroll
    for(int ks=0; ks<2; ks++){
      short8v a[4], b[4];
      int k8 = ks*4 + (lane>>4);
#pragma unroll
      for(int i=0;i<4;i++){
        int lr = wm + i*16 + (lane&15);
        a[i] = *(const short8v*)&Asc[lr*64 + (k8 ^ (lr&7))*8];
      }
#pragma unroll
      for(int j=0;j<4;j++){
        int lr = wn + j*16 + (lane&15);
        b[j] = *(const short8v*)&Bsc[lr*64 + (k8 ^ (lr&7))*8];
      }
#pragma unroll
      for(int i=0;i<4;i++)
#pragma unroll
        for(int j=0;j<4;j++)
          acc[i][j] = __builtin_amdgcn_mfma_f32_16x16x32_bf16(a[i], b[j], acc[i][j], 0,0,0);
    }
    asm volatile("" ::: "memory");
    __builtin_amdgcn_s_barrier();            // all reads of buf[cur] done before restage
  }
#pragma unroll
  for(int i=0;i<4;i++){
    int grow0 = m0 + wm + i*16 + (lane>>4)*4;
#pragma unroll
    for(int j=0;j<4;j++){
      int gcol = n0 + wn + j*16 + (lane&15);
      if(gcol < Nout){
#pragma unroll
        for(int r=0;r<4;r++){
          float v = acc[i][j][r];
          int grow = grow0 + r;
          if(EPI==4){
            if(gcol < 512) stv(&C[grow*ldc+gcol], softplus_f(v + bias[gcol]));
            else           C2[grow*32 + (gcol-512)] = v;
          } else {
            if(EPI==1) v += R[grow*ldc+gcol];
            if(EPI==2) v = gelu_f(v + bias[gcol]);
            if(EPI==3) v = softplus_f(v + bias[gcol]);
            stv(&C[grow*ldc+gcol], v);
          }
        }
      }
    }
  }
}

// ---- causal depthwise conv (k=4) + bias + silu, sliding window. ----
__global__ __launch_bounds__(256) void k_conv(const __hip_bfloat16* __restrict__ xz,
                       const float* __restrict__ cw, const float* __restrict__ cb,
                       __hip_bfloat16* __restrict__ xs_bf){
  int idx = blockIdx.x*256 + threadIdx.x;   // (L_SEQ/CLB)*128 threads
  int cg = idx & 127, lb = idx >> 7;
  int c4 = cg*4;
  int l0 = lb*CLB;
  float w[4][4], bias[4];
#pragma unroll
  for(int j=0;j<4;j++){
    float4 wv = *(const float4*)&cw[(c4+j)*4];
    w[j][0]=wv.x; w[j][1]=wv.y; w[j][2]=wv.z; w[j][3]=wv.w;
  }
  { float4 bv = *(const float4*)&cb[c4];
    bias[0]=bv.x; bias[1]=bv.y; bias[2]=bv.z; bias[3]=bv.w; }
  float xm0[4], xm1[4], xm2[4];   // x[l-3], x[l-2], x[l-1]
#pragma unroll
  for(int j=0;j<4;j++){ xm0[j]=0.f; xm1[j]=0.f; xm2[j]=0.f; }
  if(l0 >= 3){
    ushort4 r0 = *(const ushort4*)&xz[(l0-3)*1024 + c4];
    ushort4 r1 = *(const ushort4*)&xz[(l0-2)*1024 + c4];
    ushort4 r2 = *(const ushort4*)&xz[(l0-1)*1024 + c4];
    xm0[0]=bf2f(r0.x); xm0[1]=bf2f(r0.y); xm0[2]=bf2f(r0.z); xm0[3]=bf2f(r0.w);
    xm1[0]=bf2f(r1.x); xm1[1]=bf2f(r1.y); xm1[2]=bf2f(r1.z); xm1[3]=bf2f(r1.w);
    xm2[0]=bf2f(r2.x); xm2[1]=bf2f(r2.y); xm2[2]=bf2f(r2.z); xm2[3]=bf2f(r2.w);
  }
  for(int l=l0; l<l0+CLB; l++){
    ushort4 rc = *(const ushort4*)&xz[l*1024 + c4];
    float xc[4] = {bf2f(rc.x), bf2f(rc.y), bf2f(rc.z), bf2f(rc.w)};
    __hip_bfloat16 ob[4];
#pragma unroll
    for(int j=0;j<4;j++){
      float acc = bias[j];
      acc = fmaf(xm0[j], w[j][0], acc);
      acc = fmaf(xm1[j], w[j][1], acc);
      acc = fmaf(xm2[j], w[j][2], acc);
      acc = fmaf(xc[j],  w[j][3], acc);
      ob[j] = __float2bfloat16(silu_f(acc));
    }
    *(uint2*)&xs_bf[l*DI + c4] = *(uint2*)ob;
#pragma unroll
    for(int j=0;j<4;j++){ xm0[j]=xm1[j]; xm1[j]=xm2[j]; xm2[j]=xc[j]; }
  }
}

// ---- scan phase 1: per-chunk (prod dA, local carry) per state.
//      Fast path: A[n] == (n+1)*A[0] -> dA[n] = r^(n+1), r = exp(d*A[0]). ----
__global__ __launch_bounds__(256) void k_scan1(const float* __restrict__ delta,
                        const __hip_bfloat16* __restrict__ xs,
                        const float* __restrict__ dbc32, const float* __restrict__ A_log,
                        float* __restrict__ Atot, float* __restrict__ Btot){
  __shared__ float bcs[CHL*32];
  int t = threadIdx.x;
  int chunk = blockIdx.x >> 1;
  int e = ((blockIdx.x & 1) << 8) + t;
  int l0 = chunk*CHL;
  ((float4*)bcs)[t] = ((const float4*)&dbc32[l0*32])[t];
  float A[16];
  {
    const float4* al = (const float4*)&A_log[e*DS];
#pragma unroll
    for(int q=0;q<4;q++){
      float4 a = al[q];
      A[q*4+0] = -__expf(a.x); A[q*4+1] = -__expf(a.y);
      A[q*4+2] = -__expf(a.z); A[q*4+3] = -__expf(a.w);
    }
  }
  bool pf = true;
#pragma unroll
  for(int n=1;n<16;n++) pf = pf && (fabsf(A[n] - (n+1)*A[0]) <= 1e-4f*fabsf(A[n]));
  float carry[16], aprod[16];
#pragma unroll
  for(int n=0;n<16;n++){ carry[n]=0.f; aprod[n]=1.f; }
  __syncthreads();
  if(pf){
    float A0 = A[0];
#pragma unroll 2
    for(int li=0; li<CHL; li++){
      int l = l0 + li;
      float d  = delta[l*DI+e];
      float xv = bf2f(*(const unsigned short*)&xs[l*DI+e]);
      float dxv = d*xv;
      const float4* bp = (const float4*)&bcs[li*32];
      float4 b0=bp[0], b1=bp[1], b2=bp[2], b3=bp[3];
      float B[16] = {b0.x,b0.y,b0.z,b0.w, b1.x,b1.y,b1.z,b1.w,
                     b2.x,b2.y,b2.z,b2.w, b3.x,b3.y,b3.z,b3.w};
      float r = __expf(d*A0);
      float dA[16]; powers16(r, dA);
#pragma unroll
      for(int n=0;n<16;n++){
        carry[n] = fmaf(carry[n], dA[n], dxv*B[n]);
        aprod[n] *= dA[n];
      }
    }
  } else {
#pragma unroll 2
    for(int li=0; li<CHL; li++){
      int l = l0 + li;
      float d  = delta[l*DI+e];
      float xv = bf2f(*(const unsigned short*)&xs[l*DI+e]);
      float dxv = d*xv;
      const float4* bp = (const float4*)&bcs[li*32];
      float4 b0=bp[0], b1=bp[1], b2=bp[2], b3=bp[3];
      float B[16] = {b0.x,b0.y,b0.z,b0.w, b1.x,b1.y,b1.z,b1.w,
                     b2.x,b2.y,b2.z,b2.w, b3.x,b3.y,b3.z,b3.w};
#pragma unroll
      for(int n=0;n<16;n++){
        float dA = __expf(d*A[n]);
        carry[n] = fmaf(carry[n], dA, dxv*B[n]);
        aprod[n] *= dA;
      }
    }
  }
  float4* ap = (float4*)&Atot[chunk*8192 + e*DS];
  float4* bp = (float4*)&Btot[chunk*8192 + e*DS];
#pragma unroll
  for(int q=0;q<4;q++){
    ap[q] = make_float4(aprod[q*4],aprod[q*4+1],aprod[q*4+2],aprod[q*4+3]);
    bp[q] = make_float4(carry[q*4],carry[q*4+1],carry[q*4+2],carry[q*4+3]);
  }
}

// ---- scan phase 2: carry-in per chunk (h0 aliases Btot: load-before-store) ----
__global__ void k_scan2(const float* __restrict__ Atot, const float* __restrict__ Btot,
                        float* __restrict__ h0){
  int tg = blockIdx.x*256 + threadIdx.x;
  float carry = 0.f;
  for(int c=0;c<NCH;c++){
    float a = Atot[c*8192+tg];
    float b = Btot[c*8192+tg];
    h0[c*8192+tg] = carry;
    carry = fmaf(carry, a, b);
  }
}

// ---- scan phase 3: replay with carry-in, y = (sum h*C + xs*D)*silu(z) -> bf16 ----
__global__ __launch_bounds__(256) void k_scan3(const float* __restrict__ delta,
                        const __hip_bfloat16* __restrict__ xs,
                        const float* __restrict__ dbc32, const float* __restrict__ A_log,
                        const float* __restrict__ Dp, const float* __restrict__ h0,
                        const __hip_bfloat16* __restrict__ xz, __hip_bfloat16* __restrict__ y){
  __shared__ float bcs[CHL*32];
  int t = threadIdx.x;
  int chunk = blockIdx.x >> 1;
  int e = ((blockIdx.x & 1) << 8) + t;
  int l0 = chunk*CHL;
  ((float4*)bcs)[t] = ((const float4*)&dbc32[l0*32])[t];
  float A[16];
  {
    const float4* al = (const float4*)&A_log[e*DS];
#pragma unroll
    for(int q=0;q<4;q++){
      float4 a = al[q];
      A[q*4+0] = -__expf(a.x); A[q*4+1] = -__expf(a.y);
      A[q*4+2] = -__expf(a.z); A[q*4+3] = -__expf(a.w);
    }
  }
  bool pf = true;
#pragma unroll
  for(int n=1;n<16;n++) pf = pf && (fabsf(A[n] - (n+1)*A[0]) <= 1e-4f*fabsf(A[n]));
  float carry[16];
  {
    const float4* hp = (const float4*)&h0[chunk*8192 + e*DS];
#pragma unroll
    for(int q=0;q<4;q++){
      float4 h = hp[q];
      carry[q*4+0]=h.x; carry[q*4+1]=h.y; carry[q*4+2]=h.z; carry[q*4+3]=h.w;
    }
  }
  float Dv = Dp[e];
  __syncthreads();
  if(pf){
    float A0 = A[0];
#pragma unroll 2
    for(int li=0; li<CHL; li++){
      int l = l0 + li;
      float d  = delta[l*DI+e];
      float xv = bf2f(*(const unsigned short*)&xs[l*DI+e]);
      float dxv = d*xv;
      const float4* bp = (const float4*)&bcs[li*32];
      float4 b0=bp[0], b1=bp[1], b2=bp[2], b3=bp[3];
      float4 c0=bp[4], c1=bp[5], c2=bp[6], c3=bp[7];
      float B[16] = {b0.x,b0.y,b0.z,b0.w, b1.x,b1.y,b1.z,b1.w,
                     b2.x,b2.y,b2.z,b2.w, b3.x,b3.y,b3.z,b3.w};
      float Cv[16] = {c0.x,c0.y,c0.z,c0.w, c1.x,c1.y,c1.z,c1.w,
                      c2.x,c2.y,c2.z,c2.w, c3.x,c3.y,c3.z,c3.w};
      float r = __expf(d*A0);
      float dA[16]; powers16(r, dA);
      float p[4] = {0.f,0.f,0.f,0.f};
#pragma unroll
      for(int n=0;n<16;n++){
        carry[n] = fmaf(carry[n], dA[n], dxv*B[n]);
        p[n&3] = fmaf(carry[n], Cv[n], p[n&3]);
      }
      float ps = (p[0]+p[1]) + (p[2]+p[3]);
      float z = bf2f(*(const unsigned short*)&xz[l*1024 + 512 + e]);
      y[l*DI+e] = __float2bfloat16(fmaf(xv, Dv, ps) * silu_f(z));
    }
  } else {
#pragma unroll 2
    for(int li=0; li<CHL; li++){
      int l = l0 + li;
      float d  = delta[l*DI+e];
      float xv = bf2f(*(const unsigned short*)&xs[l*DI+e]);
      float dxv = d*xv;
      const float4* bp = (const float4*)&bcs[li*32];
      float4 b0=bp[0], b1=bp[1], b2=bp[2], b3=bp[3];
      float4 c0=bp[4], c1=bp[5], c2=bp[6], c3=bp[7];
      float B[16] = {b0.x,b0.y,b0.z,b0.w, b1.x,b1.y,b1.z,b1.w,
                     b2.x,b2.y,b2.z,b2.w, b3.x,b3.y,b3.z,b3.w};
      float Cv[16] = {c0.x,c0.y,c0.z,c0.w, c1.x,c1.y,c1.z,c1.w,
                      c2.x,c2.y,c2.z,c2.w, c3.x,c3.y,c3.z,c3.w};
      float p[4] = {0.f,0.f,0.f,0.f};
#pragma unroll
      for(int n=0;n<16;n++){
        float dA = __expf(d*A[n]);
        carry[n] = fmaf(carry[n], dA, dxv*B[n]);
        p[n&3] = fmaf(carry[n], Cv[n], p[n&3]);
      }
      float ps = (p[0]+p[1]) + (p[2]+p[3]);
      float z = bf2f(*(const unsigned short*)&xz[l*1024 + 512 + e]);
      y[l*DI+e] = __float2bfloat16(fmaf(xv, Dv, ps) * silu_f(z));
    }
  }
}

// ---- final: LN(128) -> @W2(128,1)+b2 -> tanh, one wave per row ----
__global__ void k_final(const float* __restrict__ h2, const float* __restrict__ g,
                        const float* __restrict__ b, const float* __restrict__ W2,
                        const float* __restrict__ b2, float* __restrict__ out){
  int lane = threadIdx.x&63;
  int wv = threadIdx.x>>6;
  int r = blockIdx.x*4 + wv;
  float v0 = h2[r*128+lane], v1 = h2[r*128+64+lane];
  float s = v0+v1, sq = v0*v0+v1*v1;
#pragma unroll
  for(int o=32;o;o>>=1){ s += __shfl_xor(s,o); sq += __shfl_xor(sq,o); }
  float mean = s*(1.0f/128), var = sq*(1.0f/128) - mean*mean;
  float rs = rsqrtf(var+1e-5f);
  float n0 = (v0-mean)*rs*g[lane]+b[lane];
  float n1 = (v1-mean)*rs*g[lane+64]+b[lane+64];
  float d = n0*W2[lane] + n1*W2[lane+64];
#pragma unroll
  for(int o=32;o;o>>=1) d += __shfl_xor(d,o);
  if(lane==0) out[r] = tanhf(d + b2[0]);
}

extern "C" void kernel_launch(void* const* d_in, const int* in_sizes, int n_in,
                              void* d_out, int out_size, void* d_ws, size_t ws_size,
                              hipStream_t stream){
  const float* x    = (const float*)d_in[0];
  const float* Win  = (const float*)d_in[1];
  const float* bin  = (const float*)d_in[2];
  const float* ln1g = (const float*)d_in[3];
  const float* ln1b = (const float*)d_in[4];
  const float* rmsw = (const float*)d_in[5];
  const float* inW  = (const float*)d_in[6];
  const float* convW= (const float*)d_in[7];
  const float* convB= (const float*)d_in[8];
  const float* xpW  = (const float*)d_in[9];
  const float* dtW  = (const float*)d_in[10];
  const float* dtB  = (const float*)d_in[11];
  const float* A_log= (const float*)d_in[12];
  const float* Dp   = (const float*)d_in[13];
  const float* outW = (const float*)d_in[14];
  const float* ln2g = (const float*)d_in[15];
  const float* ln2b = (const float*)d_in[16];
  const float* W1   = (const float*)d_in[17];
  const float* b1   = (const float*)d_in[18];
  const float* ln3g = (const float*)d_in[19];
  const float* ln3b = (const float*)d_in[20];
  const float* W2   = (const float*)d_in[21];
  const float* b2   = (const float*)d_in[22];
  float* out = (float*)d_out;
  float* ws = (float*)d_ws;
  float* u     = ws;                                          // 16384*256 f32
  __hip_bfloat16* hn_bf = (__hip_bfloat16*)(ws + 4194304);
  __hip_bfloat16* xz_bf = (__hip_bfloat16*)(ws + 8388608);    // 16384*1024 bf16
  float* dbc32 = ws + 16777216;                               // 16384*32 f32
  float* delta = ws + 17301504;                               // 16384*512 f32
  __hip_bfloat16* y_bf  = (__hip_bfloat16*)(ws + 25690112);   // 16384*512 bf16
  __hip_bfloat16* xs_bf = (__hip_bfloat16*)(ws + 29884416);   // 16384*512 bf16
  float* Atot  = ws + 34078720;                               // NCH*8192
  float* Btot  = ws + 38273024;                               // NCH*8192
  float* h0    = Btot;                  // aliased (scan2 loads before store)
  float* h2    = u;                     // aliased (u dead after k_ln)
  __hip_bfloat16* inWt   = (__hip_bfloat16*)(ws + 42467328);  // 2*1024*256 bf16
  __hip_bfloat16* outWt  = (__hip_bfloat16*)(ws + 42729472);  // 2*256*512 bf16
  __hip_bfloat16* W1t    = (__hip_bfloat16*)(ws + 42860544);  // 128*256 bf16
  __hip_bfloat16* Wdbc_t = (__hip_bfloat16*)(ws + 42876928);  // 2*640*512 bf16

  k_cvtw<<<3200,256,0,stream>>>(inW, outW, W1, inWt, outWt, W1t);
  k_wd<<<2560,256,0,stream>>>(xpW, dtW, Wdbc_t);
  k_input<<<L_SEQ,256,0,stream>>>(x,Win,bin,ln1g,ln1b,u);
  for(int i=0;i<2;i++){
    k_rms<<<L_SEQ,256,0,stream>>>(u, rmsw+i*DM, hn_bf);
    k_mgemm<0,__hip_bfloat16><<<dim3(8, L_SEQ/128),256,0,stream>>>(hn_bf, inWt+i*262144, nullptr, nullptr, xz_bf, nullptr, L_SEQ, DM, 1024, 1024);
    k_conv<<<(L_SEQ/CLB)*128/256,256,0,stream>>>(xz_bf, convW+i*DI*4, convB+i*DI, xs_bf);
    k_mgemm<4,float><<<dim3(5, L_SEQ/128),256,0,stream>>>(xs_bf, Wdbc_t+i*327680, dtB+i*DI, nullptr, delta, dbc32, L_SEQ, DI, 512, 544);
    k_scan1<<<NCH*2,256,0,stream>>>(delta, xs_bf, dbc32, A_log+i*DI*DS, Atot, Btot);
    k_scan2<<<32,256,0,stream>>>(Atot, Btot, h0);
    k_scan3<<<NCH*2,256,0,stream>>>(delta, xs_bf, dbc32, A_log+i*DI*DS, Dp+i*DI, h0, xz_bf, y_bf);
    k_mgemm<1,float><<<dim3(2, L_SEQ/128),256,0,stream>>>(y_bf, outWt+i*131072, nullptr, u, u, nullptr, L_SEQ, DI, 256, 256);
  }
  k_ln<<<L_SEQ,256,0,stream>>>(u, ln2g, ln2b, hn_bf);
  k_mgemm<2,float><<<dim3(1, L_SEQ/128),256,0,stream>>>(hn_bf, W1t, b1, nullptr, h2, nullptr, L_SEQ, DM, 128, 128);
  k_final<<<L_SEQ/4,256,0,stream>>>(h2, ln3g, ln3b, W2, b2, out);
}

// Round 10
// 474.938 us; speedup vs baseline: 1.1820x; 1.0222x over previous
//
#include <hip/hip_runtime.h>
#include <hip/hip_bf16.h>
#include <math.h>

#define L_SEQ 16384
#define DM 256
#define DI 512
#define DS 16
#define NCH 512   // number of scan chunks
#define CHL 32    // chunk length (NCH*CHL == L_SEQ)
#define CLB 16    // conv: timesteps per thread

typedef __attribute__((ext_vector_type(8))) short short8v;
typedef __attribute__((ext_vector_type(4))) float f32x4;

__device__ __forceinline__ float warpSum(float v){
#pragma unroll
  for(int o=32;o;o>>=1) v += __shfl_xor(v,o);
  return v;
}
__device__ __forceinline__ float tanh_fast(float x){
  float xc = fminf(x, 15.f);
  float t = __expf(2.f*xc);
  return (t-1.f)/(t+1.f);
}
__device__ __forceinline__ float gelu_f(float x){
  float x3 = x*x*x;
  return 0.5f*x*(1.0f + tanh_fast(0.7978845608028654f*(x + 0.044715f*x3)));
}
__device__ __forceinline__ float silu_f(float x){
  return x / (1.0f + __expf(-x));
}
__device__ __forceinline__ float softplus_f(float x){
  return fmaxf(x,0.0f) + __logf(1.0f + __expf(-fabsf(x)));
}
__device__ __forceinline__ float bf2f(unsigned short u){
  return __uint_as_float(((unsigned int)u)<<16);
}
__device__ __forceinline__ void gload16(const void* g, void* l){
  __builtin_amdgcn_global_load_lds((const __attribute__((address_space(1))) void*)g,
                                   (__attribute__((address_space(3))) void*)l, 16, 0, 0);
}

// r^(n+1) for n=0..15, ~16 muls, depth ~4 (replaces 16 quarter-rate exps)
__device__ __forceinline__ void powers16(float r, float* dA){
  float r2 = r*r;
  float r4 = r2*r2;
  float r8 = r4*r4;
  dA[0]=r;        dA[1]=r2;       dA[2]=r2*r;     dA[3]=r4;
  dA[4]=r4*r;     dA[5]=r4*r2;    dA[6]=r4*dA[2]; dA[7]=r8;
  dA[8]=r8*r;     dA[9]=r8*r2;    dA[10]=r8*dA[2];dA[11]=r8*r4;
  dA[12]=r8*dA[4];dA[13]=r8*dA[5];dA[14]=r8*dA[6];dA[15]=r8*r8;
}

// ---- weight convert + transpose to bf16: Wt[n][k] = bf16(W[k][n]) ----
__global__ void k_cvtw(const float* __restrict__ inW, const float* __restrict__ outW,
                       const float* __restrict__ W1, __hip_bfloat16* __restrict__ inWt,
                       __hip_bfloat16* __restrict__ outWt, __hip_bfloat16* __restrict__ W1t){
  int idx = blockIdx.x*256 + threadIdx.x;
  if(idx < 524288){                      // inW: 2 layers of [256][1024] -> [1024][256]
    int layer = idx >> 18;
    int r = idx & 262143;
    int n = r >> 8, k = r & 255;
    inWt[idx] = __float2bfloat16(inW[layer*262144 + k*1024 + n]);
  } else if(idx < 786432){               // outW: 2 layers of [512][256] -> [256][512]
    int j = idx - 524288;
    int layer = j >> 17;
    int r = j & 131071;
    int n = r >> 9, k = r & 511;
    outWt[j] = __float2bfloat16(outW[layer*131072 + k*256 + n]);
  } else if(idx < 819200){               // W1: [256][128] -> [128][256]
    int j = idx - 786432;
    int n = j >> 8, k = j & 255;
    W1t[j] = __float2bfloat16(W1[k*128 + n]);
  }
}

// ---- fold xpW/dtW: Wd_t[layer][n][k] = sum_j xpW[k][j]*dtW[j][n] (delta pre-act),
//      Wbc_t[layer][n][k] = xpW[k][16+n] for n<32, 0 pad to 128 rows ----
__global__ void k_wd(const float* __restrict__ xpW, const float* __restrict__ dtW,
                     __hip_bfloat16* __restrict__ Wd_t, __hip_bfloat16* __restrict__ Wbc_t){
  int idx = blockIdx.x*256 + threadIdx.x;
  if(idx < 524288){                      // 2 layers x [512 n][512 k]
    int layer = idx >> 18;
    int r = idx & 262143;
    int n = r >> 9, k = r & 511;
    const float* xp = xpW + layer*512*48;
    const float* dt = dtW + layer*16*512;
    float s = 0.f;
#pragma unroll
    for(int j=0;j<16;j++) s = fmaf(xp[k*48+j], dt[j*512+n], s);
    Wd_t[idx] = __float2bfloat16(s);
  } else if(idx < 655360){               // 2 layers x [128 n][512 k]
    int j2 = idx - 524288;
    int layer = j2 >> 16;
    int r = j2 & 65535;
    int n = r >> 9, k = r & 511;
    float v = (n < 32) ? xpW[layer*512*48 + k*48 + 16 + n] : 0.f;
    Wbc_t[j2] = __float2bfloat16(v);
  }
}

// ---- input projection + LN + gelu: u = gelu(LN(x@Win + bin)) ----
__global__ void k_input(const float* __restrict__ x, const float* __restrict__ Win,
                        const float* __restrict__ bin, const float* __restrict__ g,
                        const float* __restrict__ b, float* __restrict__ u){
  int r = blockIdx.x, t = threadIdx.x;
  __shared__ float xr[32];
  __shared__ float sA[4], sB[4];
  if(t<32) xr[t] = x[r*32+t];
  __syncthreads();
  float v = bin[t];
#pragma unroll
  for(int k=0;k<32;k++) v = fmaf(xr[k], Win[k*DM+t], v);
  float s = warpSum(v), sq = warpSum(v*v);
  if((t&63)==0){ sA[t>>6]=s; sB[t>>6]=sq; }
  __syncthreads();
  float mean = (sA[0]+sA[1]+sA[2]+sA[3])*(1.0f/DM);
  float msq  = (sB[0]+sB[1]+sB[2]+sB[3])*(1.0f/DM);
  float var = msq - mean*mean;
  float nv = (v-mean)*rsqrtf(var+1e-5f)*g[t]+b[t];
  u[r*DM+t] = gelu_f(nv);
}

// ---- rmsnorm over 256 -> bf16 ----
__global__ void k_rms(const float* __restrict__ u, const float* __restrict__ w,
                      __hip_bfloat16* __restrict__ o){
  int r=blockIdx.x, t=threadIdx.x;
  __shared__ float sA[4];
  float v = u[r*DM+t];
  float sq = warpSum(v*v);
  if((t&63)==0) sA[t>>6]=sq;
  __syncthreads();
  float ms = (sA[0]+sA[1]+sA[2]+sA[3])*(1.0f/DM);
  o[r*DM+t] = __float2bfloat16(v*rsqrtf(ms+1e-5f)*w[t]);
}

// ---- layernorm over 256 -> bf16 ----
__global__ void k_ln(const float* __restrict__ u, const float* __restrict__ g,
                     const float* __restrict__ b, __hip_bfloat16* __restrict__ o){
  int r=blockIdx.x, t=threadIdx.x;
  __shared__ float sA[4], sB[4];
  float v = u[r*DM+t];
  float s = warpSum(v), sq = warpSum(v*v);
  if((t&63)==0){ sA[t>>6]=s; sB[t>>6]=sq; }
  __syncthreads();
  float mean = (sA[0]+sA[1]+sA[2]+sA[3])*(1.0f/DM);
  float msq  = (sB[0]+sB[1]+sB[2]+sB[3])*(1.0f/DM);
  float var = msq - mean*mean;
  o[r*DM+t] = __float2bfloat16((v-mean)*rsqrtf(var+1e-5f)*g[t]+b[t]);
}

// ---- bf16 MFMA GEMM, BK=128 single-buffer + XCD tile remap + LDS-staged
//      coalesced epilogue. C[M,:](OT, stride ldc) = A[M,K](bf16) @ Wt[N,K]^T.
//      EPI: 0=store, 1=+R, 2=gelu(+bias), 3=softplus(+bias). ----
template<int EPI, typename OT>
__global__ __launch_bounds__(256) void k_mgemm(const __hip_bfloat16* __restrict__ A,
    const __hip_bfloat16* __restrict__ Wt, const float* __restrict__ bias,
    const float* __restrict__ R, OT* __restrict__ C, int M, int K, int ldc, int Nout){
  __shared__ char lds[69632];          // stage: As 32K | Bs 32K ; epi: Obuf 128x132 f32
  short* As = (short*)lds;             // [128 rows][128 k], 16-slot XOR swizzle
  short* Bs = (short*)(lds + 32768);
  float* Ob = (float*)lds;             // [128][132]
  int t = threadIdx.x, lane = t&63, wave = t>>6;
  // XCD-aware tile remap (block f -> XCD f%8; XCD owns contiguous y-panels)
  int gx = gridDim.x;
  int f = blockIdx.y*gx + blockIdx.x;
  int s = f >> 3;
  int sy = s/gx;
  int yb = (f&7)*(gridDim.y>>3) + sy;
  int xb = s - sy*gx;
  int m0 = yb*128, n0 = xb*128;
  int wm = (wave>>1)*64, wn = (wave&1)*64;
  f32x4 acc[4][4] = {};
  int nk = K >> 7;
  for(int ki=0; ki<nk; ki++){
    int kt = ki<<7;
    __syncthreads();
#pragma unroll
    for(int c=0;c<8;c++){
      int off = c*4096 + t*16;         // byte offset in 32KB half
      int row = off>>8;                // 256B rows
      int sl  = ((off>>4)&15) ^ (row&15);
      gload16(&A [(m0+row)*K + kt + sl*8], (char*)As + off);
      gload16(&Wt[(n0+row)*K + kt + sl*8], (char*)Bs + off);
    }
    asm volatile("s_waitcnt vmcnt(0)" ::: "memory");
    __syncthreads();
#pragma unroll
    for(int ks=0; ks<4; ks++){
      short8v a[4], b[4];
      int k8 = ks*4 + (lane>>4);
#pragma unroll
      for(int i=0;i<4;i++){
        int lr = wm + i*16 + (lane&15);
        a[i] = *(const short8v*)&As[lr*128 + (k8 ^ (lr&15))*8];
      }
#pragma unroll
      for(int j=0;j<4;j++){
        int lr = wn + j*16 + (lane&15);
        b[j] = *(const short8v*)&Bs[lr*128 + (k8 ^ (lr&15))*8];
      }
#pragma unroll
      for(int i=0;i<4;i++)
#pragma unroll
        for(int j=0;j<4;j++)
          acc[i][j] = __builtin_amdgcn_mfma_f32_16x16x32_bf16(a[i], b[j], acc[i][j], 0,0,0);
    }
  }
  __syncthreads();   // all LDS reads done before Obuf overwrites stage buffers
#pragma unroll
  for(int i=0;i<4;i++){
    int r0 = wm + i*16 + (lane>>4)*4;
#pragma unroll
    for(int j=0;j<4;j++){
      int cl = wn + j*16 + (lane&15);
#pragma unroll
      for(int r=0;r<4;r++) Ob[(r0+r)*132 + cl] = acc[i][j][r];
    }
  }
  __syncthreads();
  // coalesced copy + epilogue: thread t owns fidx [t*64, t*64+64)
#pragma unroll
  for(int v=0; v<16; v++){
    int fidx = (t*16+v)*4;
    int row = fidx>>7, col = fidx&127;
    if(col < Nout){
      float4 o = *(const float4*)&Ob[row*132 + col];
      int grow = m0 + row, gcol = n0 + col;
      if(EPI==1){
        float4 rv = *(const float4*)&R[grow*ldc+gcol];
        o.x+=rv.x; o.y+=rv.y; o.z+=rv.z; o.w+=rv.w;
      }
      if(EPI==2){
        float4 bv = *(const float4*)&bias[gcol];
        o.x=gelu_f(o.x+bv.x); o.y=gelu_f(o.y+bv.y);
        o.z=gelu_f(o.z+bv.z); o.w=gelu_f(o.w+bv.w);
      }
      if(EPI==3){
        float4 bv = *(const float4*)&bias[gcol];
        o.x=softplus_f(o.x+bv.x); o.y=softplus_f(o.y+bv.y);
        o.z=softplus_f(o.z+bv.z); o.w=softplus_f(o.w+bv.w);
      }
      if constexpr(sizeof(OT)==2){
        __hip_bfloat16 ob[4] = {__float2bfloat16(o.x),__float2bfloat16(o.y),
                                __float2bfloat16(o.z),__float2bfloat16(o.w)};
        *(uint2*)&C[grow*ldc+gcol] = *(uint2*)ob;
      } else {
        *(float4*)&C[grow*ldc+gcol] = o;
      }
    }
  }
}

// ---- causal depthwise conv (k=4) + bias + silu, sliding window. ----
__global__ __launch_bounds__(256) void k_conv(const __hip_bfloat16* __restrict__ xz,
                       const float* __restrict__ cw, const float* __restrict__ cb,
                       __hip_bfloat16* __restrict__ xs_bf){
  int idx = blockIdx.x*256 + threadIdx.x;   // (L_SEQ/CLB)*128 threads
  int cg = idx & 127, lb = idx >> 7;
  int c4 = cg*4;
  int l0 = lb*CLB;
  float w[4][4], bias[4];
#pragma unroll
  for(int j=0;j<4;j++){
    float4 wv = *(const float4*)&cw[(c4+j)*4];
    w[j][0]=wv.x; w[j][1]=wv.y; w[j][2]=wv.z; w[j][3]=wv.w;
  }
  { float4 bv = *(const float4*)&cb[c4];
    bias[0]=bv.x; bias[1]=bv.y; bias[2]=bv.z; bias[3]=bv.w; }
  float xm0[4], xm1[4], xm2[4];   // x[l-3], x[l-2], x[l-1]
#pragma unroll
  for(int j=0;j<4;j++){ xm0[j]=0.f; xm1[j]=0.f; xm2[j]=0.f; }
  if(l0 >= 3){
    ushort4 r0 = *(const ushort4*)&xz[(l0-3)*1024 + c4];
    ushort4 r1 = *(const ushort4*)&xz[(l0-2)*1024 + c4];
    ushort4 r2 = *(const ushort4*)&xz[(l0-1)*1024 + c4];
    xm0[0]=bf2f(r0.x); xm0[1]=bf2f(r0.y); xm0[2]=bf2f(r0.z); xm0[3]=bf2f(r0.w);
    xm1[0]=bf2f(r1.x); xm1[1]=bf2f(r1.y); xm1[2]=bf2f(r1.z); xm1[3]=bf2f(r1.w);
    xm2[0]=bf2f(r2.x); xm2[1]=bf2f(r2.y); xm2[2]=bf2f(r2.z); xm2[3]=bf2f(r2.w);
  }
  for(int l=l0; l<l0+CLB; l++){
    ushort4 rc = *(const ushort4*)&xz[l*1024 + c4];
    float xc[4] = {bf2f(rc.x), bf2f(rc.y), bf2f(rc.z), bf2f(rc.w)};
    __hip_bfloat16 ob[4];
#pragma unroll
    for(int j=0;j<4;j++){
      float acc = bias[j];
      acc = fmaf(xm0[j], w[j][0], acc);
      acc = fmaf(xm1[j], w[j][1], acc);
      acc = fmaf(xm2[j], w[j][2], acc);
      acc = fmaf(xc[j],  w[j][3], acc);
      ob[j] = __float2bfloat16(silu_f(acc));
    }
    *(uint2*)&xs_bf[l*DI + c4] = *(uint2*)ob;
#pragma unroll
    for(int j=0;j<4;j++){ xm0[j]=xm1[j]; xm1[j]=xm2[j]; xm2[j]=xc[j]; }
  }
}

// ---- scan phase 1: per-chunk (prod dA, local carry) per state.
//      Fast path: A[n] == (n+1)*A[0] -> dA[n] = r^(n+1), r = exp(d*A[0]). ----
__global__ __launch_bounds__(256) void k_scan1(const float* __restrict__ delta,
                        const __hip_bfloat16* __restrict__ xs,
                        const float* __restrict__ dbc32, const float* __restrict__ A_log,
                        float* __restrict__ Atot, float* __restrict__ Btot){
  __shared__ float bcs[CHL*32];
  int t = threadIdx.x;
  int chunk = blockIdx.x >> 1;
  int e = ((blockIdx.x & 1) << 8) + t;
  int l0 = chunk*CHL;
  ((float4*)bcs)[t] = ((const float4*)&dbc32[l0*32])[t];
  float A[16];
  {
    const float4* al = (const float4*)&A_log[e*DS];
#pragma unroll
    for(int q=0;q<4;q++){
      float4 a = al[q];
      A[q*4+0] = -__expf(a.x); A[q*4+1] = -__expf(a.y);
      A[q*4+2] = -__expf(a.z); A[q*4+3] = -__expf(a.w);
    }
  }
  bool pf = true;
#pragma unroll
  for(int n=1;n<16;n++) pf = pf && (fabsf(A[n] - (n+1)*A[0]) <= 1e-4f*fabsf(A[n]));
  float carry[16], aprod[16];
#pragma unroll
  for(int n=0;n<16;n++){ carry[n]=0.f; aprod[n]=1.f; }
  __syncthreads();
  if(pf){
    float A0 = A[0];
#pragma unroll 2
    for(int li=0; li<CHL; li++){
      int l = l0 + li;
      float d  = delta[l*DI+e];
      float xv = bf2f(*(const unsigned short*)&xs[l*DI+e]);
      float dxv = d*xv;
      const float4* bp = (const float4*)&bcs[li*32];
      float4 b0=bp[0], b1=bp[1], b2=bp[2], b3=bp[3];
      float B[16] = {b0.x,b0.y,b0.z,b0.w, b1.x,b1.y,b1.z,b1.w,
                     b2.x,b2.y,b2.z,b2.w, b3.x,b3.y,b3.z,b3.w};
      float r = __expf(d*A0);
      float dA[16]; powers16(r, dA);
#pragma unroll
      for(int n=0;n<16;n++){
        carry[n] = fmaf(carry[n], dA[n], dxv*B[n]);
        aprod[n] *= dA[n];
      }
    }
  } else {
#pragma unroll 2
    for(int li=0; li<CHL; li++){
      int l = l0 + li;
      float d  = delta[l*DI+e];
      float xv = bf2f(*(const unsigned short*)&xs[l*DI+e]);
      float dxv = d*xv;
      const float4* bp = (const float4*)&bcs[li*32];
      float4 b0=bp[0], b1=bp[1], b2=bp[2], b3=bp[3];
      float B[16] = {b0.x,b0.y,b0.z,b0.w, b1.x,b1.y,b1.z,b1.w,
                     b2.x,b2.y,b2.z,b2.w, b3.x,b3.y,b3.z,b3.w};
#pragma unroll
      for(int n=0;n<16;n++){
        float dA = __expf(d*A[n]);
        carry[n] = fmaf(carry[n], dA, dxv*B[n]);
        aprod[n] *= dA;
      }
    }
  }
  float4* ap = (float4*)&Atot[chunk*8192 + e*DS];
  float4* bp = (float4*)&Btot[chunk*8192 + e*DS];
#pragma unroll
  for(int q=0;q<4;q++){
    ap[q] = make_float4(aprod[q*4],aprod[q*4+1],aprod[q*4+2],aprod[q*4+3]);
    bp[q] = make_float4(carry[q*4],carry[q*4+1],carry[q*4+2],carry[q*4+3]);
  }
}

// ---- scan phase 2: carry-in per chunk (h0 aliases Btot: load-before-store) ----
__global__ void k_scan2(const float* __restrict__ Atot, const float* __restrict__ Btot,
                        float* __restrict__ h0){
  int tg = blockIdx.x*256 + threadIdx.x;
  float carry = 0.f;
  for(int c=0;c<NCH;c++){
    float a = Atot[c*8192+tg];
    float b = Btot[c*8192+tg];
    h0[c*8192+tg] = carry;
    carry = fmaf(carry, a, b);
  }
}

// ---- scan phase 3: replay with carry-in, y = (sum h*C + xs*D)*silu(z) -> bf16 ----
__global__ __launch_bounds__(256) void k_scan3(const float* __restrict__ delta,
                        const __hip_bfloat16* __restrict__ xs,
                        const float* __restrict__ dbc32, const float* __restrict__ A_log,
                        const float* __restrict__ Dp, const float* __restrict__ h0,
                        const __hip_bfloat16* __restrict__ xz, __hip_bfloat16* __restrict__ y){
  __shared__ float bcs[CHL*32];
  int t = threadIdx.x;
  int chunk = blockIdx.x >> 1;
  int e = ((blockIdx.x & 1) << 8) + t;
  int l0 = chunk*CHL;
  ((float4*)bcs)[t] = ((const float4*)&dbc32[l0*32])[t];
  float A[16];
  {
    const float4* al = (const float4*)&A_log[e*DS];
#pragma unroll
    for(int q=0;q<4;q++){
      float4 a = al[q];
      A[q*4+0] = -__expf(a.x); A[q*4+1] = -__expf(a.y);
      A[q*4+2] = -__expf(a.z); A[q*4+3] = -__expf(a.w);
    }
  }
  bool pf = true;
#pragma unroll
  for(int n=1;n<16;n++) pf = pf && (fabsf(A[n] - (n+1)*A[0]) <= 1e-4f*fabsf(A[n]));
  float carry[16];
  {
    const float4* hp = (const float4*)&h0[chunk*8192 + e*DS];
#pragma unroll
    for(int q=0;q<4;q++){
      float4 h = hp[q];
      carry[q*4+0]=h.x; carry[q*4+1]=h.y; carry[q*4+2]=h.z; carry[q*4+3]=h.w;
    }
  }
  float Dv = Dp[e];
  __syncthreads();
  if(pf){
    float A0 = A[0];
#pragma unroll 2
    for(int li=0; li<CHL; li++){
      int l = l0 + li;
      float d  = delta[l*DI+e];
      float xv = bf2f(*(const unsigned short*)&xs[l*DI+e]);
      float dxv = d*xv;
      const float4* bp = (const float4*)&bcs[li*32];
      float4 b0=bp[0], b1=bp[1], b2=bp[2], b3=bp[3];
      float4 c0=bp[4], c1=bp[5], c2=bp[6], c3=bp[7];
      float B[16] = {b0.x,b0.y,b0.z,b0.w, b1.x,b1.y,b1.z,b1.w,
                     b2.x,b2.y,b2.z,b2.w, b3.x,b3.y,b3.z,b3.w};
      float Cv[16] = {c0.x,c0.y,c0.z,c0.w, c1.x,c1.y,c1.z,c1.w,
                      c2.x,c2.y,c2.z,c2.w, c3.x,c3.y,c3.z,c3.w};
      float r = __expf(d*A0);
      float dA[16]; powers16(r, dA);
      float p[4] = {0.f,0.f,0.f,0.f};
#pragma unroll
      for(int n=0;n<16;n++){
        carry[n] = fmaf(carry[n], dA[n], dxv*B[n]);
        p[n&3] = fmaf(carry[n], Cv[n], p[n&3]);
      }
      float ps = (p[0]+p[1]) + (p[2]+p[3]);
      float z = bf2f(*(const unsigned short*)&xz[l*1024 + 512 + e]);
      y[l*DI+e] = __float2bfloat16(fmaf(xv, Dv, ps) * silu_f(z));
    }
  } else {
#pragma unroll 2
    for(int li=0; li<CHL; li++){
      int l = l0 + li;
      float d  = delta[l*DI+e];
      float xv = bf2f(*(const unsigned short*)&xs[l*DI+e]);
      float dxv = d*xv;
      const float4* bp = (const float4*)&bcs[li*32];
      float4 b0=bp[0], b1=bp[1], b2=bp[2], b3=bp[3];
      float4 c0=bp[4], c1=bp[5], c2=bp[6], c3=bp[7];
      float B[16] = {b0.x,b0.y,b0.z,b0.w, b1.x,b1.y,b1.z,b1.w,
                     b2.x,b2.y,b2.z,b2.w, b3.x,b3.y,b3.z,b3.w};
      float Cv[16] = {c0.x,c0.y,c0.z,c0.w, c1.x,c1.y,c1.z,c1.w,
                      c2.x,c2.y,c2.z,c2.w, c3.x,c3.y,c3.z,c3.w};
      float p[4] = {0.f,0.f,0.f,0.f};
#pragma unroll
      for(int n=0;n<16;n++){
        float dA = __expf(d*A[n]);
        carry[n] = fmaf(carry[n], dA, dxv*B[n]);
        p[n&3] = fmaf(carry[n], Cv[n], p[n&3]);
      }
      float ps = (p[0]+p[1]) + (p[2]+p[3]);
      float z = bf2f(*(const unsigned short*)&xz[l*1024 + 512 + e]);
      y[l*DI+e] = __float2bfloat16(fmaf(xv, Dv, ps) * silu_f(z));
    }
  }
}

// ---- final: LN(128) -> @W2(128,1)+b2 -> tanh, one wave per row ----
__global__ void k_final(const float* __restrict__ h2, const float* __restrict__ g,
                        const float* __restrict__ b, const float* __restrict__ W2,
                        const float* __restrict__ b2, float* __restrict__ out){
  int lane = threadIdx.x&63;
  int wv = threadIdx.x>>6;
  int r = blockIdx.x*4 + wv;
  float v0 = h2[r*128+lane], v1 = h2[r*128+64+lane];
  float s = v0+v1, sq = v0*v0+v1*v1;
#pragma unroll
  for(int o=32;o;o>>=1){ s += __shfl_xor(s,o); sq += __shfl_xor(sq,o); }
  float mean = s*(1.0f/128), var = sq*(1.0f/128) - mean*mean;
  float rs = rsqrtf(var+1e-5f);
  float n0 = (v0-mean)*rs*g[lane]+b[lane];
  float n1 = (v1-mean)*rs*g[lane+64]+b[lane+64];
  float d = n0*W2[lane] + n1*W2[lane+64];
#pragma unroll
  for(int o=32;o;o>>=1) d += __shfl_xor(d,o);
  if(lane==0) out[r] = tanhf(d + b2[0]);
}

extern "C" void kernel_launch(void* const* d_in, const int* in_sizes, int n_in,
                              void* d_out, int out_size, void* d_ws, size_t ws_size,
                              hipStream_t stream){
  const float* x    = (const float*)d_in[0];
  const float* Win  = (const float*)d_in[1];
  const float* bin  = (const float*)d_in[2];
  const float* ln1g = (const float*)d_in[3];
  const float* ln1b = (const float*)d_in[4];
  const float* rmsw = (const float*)d_in[5];
  const float* inW  = (const float*)d_in[6];
  const float* convW= (const float*)d_in[7];
  const float* convB= (const float*)d_in[8];
  const float* xpW  = (const float*)d_in[9];
  const float* dtW  = (const float*)d_in[10];
  const float* dtB  = (const float*)d_in[11];
  const float* A_log= (const float*)d_in[12];
  const float* Dp   = (const float*)d_in[13];
  const float* outW = (const float*)d_in[14];
  const float* ln2g = (const float*)d_in[15];
  const float* ln2b = (const float*)d_in[16];
  const float* W1   = (const float*)d_in[17];
  const float* b1   = (const float*)d_in[18];
  const float* ln3g = (const float*)d_in[19];
  const float* ln3b = (const float*)d_in[20];
  const float* W2   = (const float*)d_in[21];
  const float* b2   = (const float*)d_in[22];
  float* out = (float*)d_out;
  float* ws = (float*)d_ws;
  float* u     = ws;                                          // 16384*256 f32
  __hip_bfloat16* hn_bf = (__hip_bfloat16*)(ws + 4194304);
  __hip_bfloat16* xz_bf = (__hip_bfloat16*)(ws + 8388608);    // 16384*1024 bf16
  float* dbc32 = ws + 16777216;                               // 16384*32 f32
  float* delta = ws + 17301504;                               // 16384*512 f32
  __hip_bfloat16* y_bf  = (__hip_bfloat16*)(ws + 25690112);   // 16384*512 bf16
  __hip_bfloat16* xs_bf = (__hip_bfloat16*)(ws + 29884416);   // 16384*512 bf16
  float* Atot  = ws + 34078720;                               // NCH*8192
  float* Btot  = ws + 38273024;                               // NCH*8192
  float* h0    = Btot;                  // aliased (scan2 loads before store)
  float* h2    = u;                     // aliased (u dead after k_ln)
  __hip_bfloat16* inWt   = (__hip_bfloat16*)(ws + 42467328);  // 2*1024*256 bf16
  __hip_bfloat16* outWt  = (__hip_bfloat16*)(ws + 42729472);  // 2*256*512 bf16
  __hip_bfloat16* W1t    = (__hip_bfloat16*)(ws + 42860544);  // 128*256 bf16
  __hip_bfloat16* Wd_t   = (__hip_bfloat16*)(ws + 42876928);  // 2*512*512 bf16
  __hip_bfloat16* Wbc_t  = (__hip_bfloat16*)(ws + 43139072);  // 2*128*512 bf16

  k_cvtw<<<3200,256,0,stream>>>(inW, outW, W1, inWt, outWt, W1t);
  k_wd<<<2560,256,0,stream>>>(xpW, dtW, Wd_t, Wbc_t);
  k_input<<<L_SEQ,256,0,stream>>>(x,Win,bin,ln1g,ln1b,u);
  for(int i=0;i<2;i++){
    k_rms<<<L_SEQ,256,0,stream>>>(u, rmsw+i*DM, hn_bf);
    k_mgemm<0,__hip_bfloat16><<<dim3(8, L_SEQ/128),256,0,stream>>>(hn_bf, inWt+i*262144, nullptr, nullptr, xz_bf, L_SEQ, DM, 1024, 1024);
    k_conv<<<(L_SEQ/CLB)*128/256,256,0,stream>>>(xz_bf, convW+i*DI*4, convB+i*DI, xs_bf);
    k_mgemm<3,float><<<dim3(4, L_SEQ/128),256,0,stream>>>(xs_bf, Wd_t+i*262144, dtB+i*DI, nullptr, delta, L_SEQ, DI, 512, 512);
    k_mgemm<0,float><<<dim3(1, L_SEQ/128),256,0,stream>>>(xs_bf, Wbc_t+i*65536, nullptr, nullptr, dbc32, L_SEQ, DI, 32, 32);
    k_scan1<<<NCH*2,256,0,stream>>>(delta, xs_bf, dbc32, A_log+i*DI*DS, Atot, Btot);
    k_scan2<<<32,256,0,stream>>>(Atot, Btot, h0);
    k_scan3<<<NCH*2,256,0,stream>>>(delta, xs_bf, dbc32, A_log+i*DI*DS, Dp+i*DI, h0, xz_bf, y_bf);
    k_mgemm<1,float><<<dim3(2, L_SEQ/128),256,0,stream>>>(y_bf, outWt+i*131072, nullptr, u, u, L_SEQ, DI, 256, 256);
  }
  k_ln<<<L_SEQ,256,0,stream>>>(u, ln2g, ln2b, hn_bf);
  k_mgemm<2,float><<<dim3(1, L_SEQ/128),256,0,stream>>>(hn_bf, W1t, b1, nullptr, h2, L_SEQ, DM, 128, 128);
  k_final<<<L_SEQ/4,256,0,stream>>>(h2, ln3g, ln3b, W2, b2, out);
}

// Round 11
// 451.965 us; speedup vs baseline: 1.2421x; 1.0508x over previous
//
#include <hip/hip_runtime.h>
#include <hip/hip_bf16.h>
#include <math.h>

#define L_SEQ 16384
#define DM 256
#define DI 512
#define DS 16
#define NCH 512   // number of scan chunks
#define CHL 32    // chunk length (NCH*CHL == L_SEQ)
#define CLB 16    // conv: timesteps per thread

typedef __attribute__((ext_vector_type(8))) short short8v;
typedef __attribute__((ext_vector_type(4))) float f32x4;

__device__ __forceinline__ float tanh_fast(float x){
  float xc = fminf(x, 15.f);
  float t = __expf(2.f*xc);
  return (t-1.f)/(t+1.f);
}
__device__ __forceinline__ float gelu_f(float x){
  float x3 = x*x*x;
  return 0.5f*x*(1.0f + tanh_fast(0.7978845608028654f*(x + 0.044715f*x3)));
}
__device__ __forceinline__ float silu_f(float x){
  return x / (1.0f + __expf(-x));
}
__device__ __forceinline__ float softplus_f(float x){
  return fmaxf(x,0.0f) + __logf(1.0f + __expf(-fabsf(x)));
}
__device__ __forceinline__ float bf2f(unsigned short u){
  return __uint_as_float(((unsigned int)u)<<16);
}
__device__ __forceinline__ void gload16(const void* g, void* l){
  __builtin_amdgcn_global_load_lds((const __attribute__((address_space(1))) void*)g,
                                   (__attribute__((address_space(3))) void*)l, 16, 0, 0);
}

// r^(n+1) for n=0..15, ~16 muls, depth ~4 (replaces 16 quarter-rate exps)
__device__ __forceinline__ void powers16(float r, float* dA){
  float r2 = r*r;
  float r4 = r2*r2;
  float r8 = r4*r4;
  dA[0]=r;        dA[1]=r2;       dA[2]=r2*r;     dA[3]=r4;
  dA[4]=r4*r;     dA[5]=r4*r2;    dA[6]=r4*dA[2]; dA[7]=r8;
  dA[8]=r8*r;     dA[9]=r8*r2;    dA[10]=r8*dA[2];dA[11]=r8*r4;
  dA[12]=r8*dA[4];dA[13]=r8*dA[5];dA[14]=r8*dA[6];dA[15]=r8*r8;
}

// ---- weight convert + transpose to bf16: Wt[n][k] = bf16(W[k][n]) ----
__global__ void k_cvtw(const float* __restrict__ inW, const float* __restrict__ outW,
                       const float* __restrict__ W1, __hip_bfloat16* __restrict__ inWt,
                       __hip_bfloat16* __restrict__ outWt, __hip_bfloat16* __restrict__ W1t){
  int idx = blockIdx.x*256 + threadIdx.x;
  if(idx < 524288){                      // inW: 2 layers of [256][1024] -> [1024][256]
    int layer = idx >> 18;
    int r = idx & 262143;
    int n = r >> 8, k = r & 255;
    inWt[idx] = __float2bfloat16(inW[layer*262144 + k*1024 + n]);
  } else if(idx < 786432){               // outW: 2 layers of [512][256] -> [256][512]
    int j = idx - 524288;
    int layer = j >> 17;
    int r = j & 131071;
    int n = r >> 9, k = r & 511;
    outWt[j] = __float2bfloat16(outW[layer*131072 + k*256 + n]);
  } else if(idx < 819200){               // W1: [256][128] -> [128][256]
    int j = idx - 786432;
    int n = j >> 8, k = j & 255;
    W1t[j] = __float2bfloat16(W1[k*128 + n]);
  }
}

// ---- fold xpW/dtW: Wd_t[layer][n][k] = sum_j xpW[k][j]*dtW[j][n] (delta pre-act),
//      Wbc_t[layer][n][k] = xpW[k][16+n] for n<32, 0 pad to 128 rows ----
__global__ void k_wd(const float* __restrict__ xpW, const float* __restrict__ dtW,
                     __hip_bfloat16* __restrict__ Wd_t, __hip_bfloat16* __restrict__ Wbc_t){
  int idx = blockIdx.x*256 + threadIdx.x;
  if(idx < 524288){                      // 2 layers x [512 n][512 k]
    int layer = idx >> 18;
    int r = idx & 262143;
    int n = r >> 9, k = r & 511;
    const float* xp = xpW + layer*512*48;
    const float* dt = dtW + layer*16*512;
    float s = 0.f;
#pragma unroll
    for(int j=0;j<16;j++) s = fmaf(xp[k*48+j], dt[j*512+n], s);
    Wd_t[idx] = __float2bfloat16(s);
  } else if(idx < 655360){               // 2 layers x [128 n][512 k]
    int j2 = idx - 524288;
    int layer = j2 >> 16;
    int r = j2 & 65535;
    int n = r >> 9, k = r & 511;
    float v = (n < 32) ? xpW[layer*512*48 + k*48 + 16 + n] : 0.f;
    Wbc_t[j2] = __float2bfloat16(v);
  }
}

// ---- input projection + LN + gelu: u = gelu(LN(x@Win + bin)) -> bf16.
//      4 rows/block, wave per row, lane owns 4 contiguous cols, no barriers. ----
__global__ __launch_bounds__(256) void k_input(const float* __restrict__ x,
                        const float* __restrict__ Win, const float* __restrict__ bin,
                        const float* __restrict__ g, const float* __restrict__ b,
                        __hip_bfloat16* __restrict__ u){
  int wv = threadIdx.x>>6, lane = threadIdx.x&63;
  int r = blockIdx.x*4 + wv;
  int c0 = lane*4;
  float acc[4];
  { float4 bv = *(const float4*)&bin[c0];
    acc[0]=bv.x; acc[1]=bv.y; acc[2]=bv.z; acc[3]=bv.w; }
#pragma unroll
  for(int k=0;k<32;k++){
    float xk = x[r*32+k];
    float4 wv4 = *(const float4*)&Win[k*DM+c0];
    acc[0]=fmaf(xk,wv4.x,acc[0]); acc[1]=fmaf(xk,wv4.y,acc[1]);
    acc[2]=fmaf(xk,wv4.z,acc[2]); acc[3]=fmaf(xk,wv4.w,acc[3]);
  }
  float s = (acc[0]+acc[1])+(acc[2]+acc[3]);
  float sq = acc[0]*acc[0]+acc[1]*acc[1]+acc[2]*acc[2]+acc[3]*acc[3];
#pragma unroll
  for(int o=32;o;o>>=1){ s += __shfl_xor(s,o); sq += __shfl_xor(sq,o); }
  float mean = s*(1.0f/DM);
  float var = sq*(1.0f/DM) - mean*mean;
  float rs = rsqrtf(var+1e-5f);
  float4 gv = *(const float4*)&g[c0];
  float4 bv = *(const float4*)&b[c0];
  __hip_bfloat16 ob[4] = {
    __float2bfloat16(gelu_f((acc[0]-mean)*rs*gv.x+bv.x)),
    __float2bfloat16(gelu_f((acc[1]-mean)*rs*gv.y+bv.y)),
    __float2bfloat16(gelu_f((acc[2]-mean)*rs*gv.z+bv.z)),
    __float2bfloat16(gelu_f((acc[3]-mean)*rs*gv.w+bv.w))};
  *(uint2*)&u[r*DM+c0] = *(uint2*)ob;
}

// ---- rmsnorm over 256 (bf16 in -> bf16 out), wave per row ----
__global__ __launch_bounds__(256) void k_rms(const __hip_bfloat16* __restrict__ u,
                      const float* __restrict__ w, __hip_bfloat16* __restrict__ o){
  int wv = threadIdx.x>>6, lane = threadIdx.x&63;
  int r = blockIdx.x*4 + wv;
  int c0 = lane*4;
  ushort4 uv = *(const ushort4*)&u[r*DM+c0];
  float v0=bf2f(uv.x), v1=bf2f(uv.y), v2=bf2f(uv.z), v3=bf2f(uv.w);
  float sq = v0*v0+v1*v1+v2*v2+v3*v3;
#pragma unroll
  for(int s=32;s;s>>=1) sq += __shfl_xor(sq,s);
  float rs = rsqrtf(sq*(1.0f/DM)+1e-5f);
  float4 wv4 = *(const float4*)&w[c0];
  __hip_bfloat16 ob[4] = {
    __float2bfloat16(v0*rs*wv4.x), __float2bfloat16(v1*rs*wv4.y),
    __float2bfloat16(v2*rs*wv4.z), __float2bfloat16(v3*rs*wv4.w)};
  *(uint2*)&o[r*DM+c0] = *(uint2*)ob;
}

// ---- layernorm over 256 (bf16 in -> bf16 out), wave per row ----
__global__ __launch_bounds__(256) void k_ln(const __hip_bfloat16* __restrict__ u,
                     const float* __restrict__ g, const float* __restrict__ b,
                     __hip_bfloat16* __restrict__ o){
  int wv = threadIdx.x>>6, lane = threadIdx.x&63;
  int r = blockIdx.x*4 + wv;
  int c0 = lane*4;
  ushort4 uv = *(const ushort4*)&u[r*DM+c0];
  float v[4] = {bf2f(uv.x), bf2f(uv.y), bf2f(uv.z), bf2f(uv.w)};
  float s = (v[0]+v[1])+(v[2]+v[3]);
  float sq = v[0]*v[0]+v[1]*v[1]+v[2]*v[2]+v[3]*v[3];
#pragma unroll
  for(int o2=32;o2;o2>>=1){ s += __shfl_xor(s,o2); sq += __shfl_xor(sq,o2); }
  float mean = s*(1.0f/DM);
  float var = sq*(1.0f/DM) - mean*mean;
  float rs = rsqrtf(var+1e-5f);
  float4 gv = *(const float4*)&g[c0];
  float4 bv = *(const float4*)&b[c0];
  __hip_bfloat16 ob[4] = {
    __float2bfloat16((v[0]-mean)*rs*gv.x+bv.x),
    __float2bfloat16((v[1]-mean)*rs*gv.y+bv.y),
    __float2bfloat16((v[2]-mean)*rs*gv.z+bv.z),
    __float2bfloat16((v[3]-mean)*rs*gv.w+bv.w)};
  *(uint2*)&o[r*DM+c0] = *(uint2*)ob;
}

// ---- bf16 MFMA GEMM, BK=128 single-buffer + XCD tile remap + LDS-staged
//      coalesced epilogue. C[M,:](OT, stride ldc) = A[M,K](bf16) @ Wt[N,K]^T.
//      EPI: 0=store, 1=+R, 2=gelu(+bias), 3=softplus(+bias). ----
template<int EPI, typename OT>
__global__ __launch_bounds__(256) void k_mgemm(const __hip_bfloat16* __restrict__ A,
    const __hip_bfloat16* __restrict__ Wt, const float* __restrict__ bias,
    const OT* __restrict__ R, OT* __restrict__ C, int M, int K, int ldc, int Nout){
  __shared__ char lds[69632];          // stage: As 32K | Bs 32K ; epi: Obuf 128x132 f32
  short* As = (short*)lds;             // [128 rows][128 k], 16-slot XOR swizzle
  short* Bs = (short*)(lds + 32768);
  float* Ob = (float*)lds;             // [128][132]
  int t = threadIdx.x, lane = t&63, wave = t>>6;
  // XCD-aware tile remap (block f -> XCD f%8; XCD owns contiguous y-panels)
  int gx = gridDim.x;
  int f = blockIdx.y*gx + blockIdx.x;
  int s = f >> 3;
  int sy = s/gx;
  int yb = (f&7)*(gridDim.y>>3) + sy;
  int xb = s - sy*gx;
  int m0 = yb*128, n0 = xb*128;
  int wm = (wave>>1)*64, wn = (wave&1)*64;
  f32x4 acc[4][4] = {};
  int nk = K >> 7;
  for(int ki=0; ki<nk; ki++){
    int kt = ki<<7;
    __syncthreads();
#pragma unroll
    for(int c=0;c<8;c++){
      int off = c*4096 + t*16;         // byte offset in 32KB half
      int row = off>>8;                // 256B rows
      int sl  = ((off>>4)&15) ^ (row&15);
      gload16(&A [(m0+row)*K + kt + sl*8], (char*)As + off);
      gload16(&Wt[(n0+row)*K + kt + sl*8], (char*)Bs + off);
    }
    asm volatile("s_waitcnt vmcnt(0)" ::: "memory");
    __syncthreads();
#pragma unroll
    for(int ks=0; ks<4; ks++){
      short8v a[4], b[4];
      int k8 = ks*4 + (lane>>4);
#pragma unroll
      for(int i=0;i<4;i++){
        int lr = wm + i*16 + (lane&15);
        a[i] = *(const short8v*)&As[lr*128 + (k8 ^ (lr&15))*8];
      }
#pragma unroll
      for(int j=0;j<4;j++){
        int lr = wn + j*16 + (lane&15);
        b[j] = *(const short8v*)&Bs[lr*128 + (k8 ^ (lr&15))*8];
      }
#pragma unroll
      for(int i=0;i<4;i++)
#pragma unroll
        for(int j=0;j<4;j++)
          acc[i][j] = __builtin_amdgcn_mfma_f32_16x16x32_bf16(a[i], b[j], acc[i][j], 0,0,0);
    }
  }
  __syncthreads();   // all LDS reads done before Obuf overwrites stage buffers
#pragma unroll
  for(int i=0;i<4;i++){
    int r0 = wm + i*16 + (lane>>4)*4;
#pragma unroll
    for(int j=0;j<4;j++){
      int cl = wn + j*16 + (lane&15);
#pragma unroll
      for(int r=0;r<4;r++) Ob[(r0+r)*132 + cl] = acc[i][j][r];
    }
  }
  __syncthreads();
  // coalesced copy + epilogue: thread t owns fidx [t*64, t*64+64)
#pragma unroll
  for(int v=0; v<16; v++){
    int fidx = (t*16+v)*4;
    int row = fidx>>7, col = fidx&127;
    if(col < Nout){
      float4 o = *(const float4*)&Ob[row*132 + col];
      int grow = m0 + row, gcol = n0 + col;
      if(EPI==1){
        if constexpr(sizeof(OT)==2){
          ushort4 rv = *(const ushort4*)&R[grow*ldc+gcol];
          o.x+=bf2f(rv.x); o.y+=bf2f(rv.y); o.z+=bf2f(rv.z); o.w+=bf2f(rv.w);
        } else {
          float4 rv = *(const float4*)&R[grow*ldc+gcol];
          o.x+=rv.x; o.y+=rv.y; o.z+=rv.z; o.w+=rv.w;
        }
      }
      if(EPI==2){
        float4 bv = *(const float4*)&bias[gcol];
        o.x=gelu_f(o.x+bv.x); o.y=gelu_f(o.y+bv.y);
        o.z=gelu_f(o.z+bv.z); o.w=gelu_f(o.w+bv.w);
      }
      if(EPI==3){
        float4 bv = *(const float4*)&bias[gcol];
        o.x=softplus_f(o.x+bv.x); o.y=softplus_f(o.y+bv.y);
        o.z=softplus_f(o.z+bv.z); o.w=softplus_f(o.w+bv.w);
      }
      if constexpr(sizeof(OT)==2){
        __hip_bfloat16 ob[4] = {__float2bfloat16(o.x),__float2bfloat16(o.y),
                                __float2bfloat16(o.z),__float2bfloat16(o.w)};
        *(uint2*)&C[grow*ldc+gcol] = *(uint2*)ob;
      } else {
        *(float4*)&C[grow*ldc+gcol] = o;
      }
    }
  }
}

// ---- causal depthwise conv (k=4) + bias + silu, sliding window. ----
__global__ __launch_bounds__(256) void k_conv(const __hip_bfloat16* __restrict__ xz,
                       const float* __restrict__ cw, const float* __restrict__ cb,
                       __hip_bfloat16* __restrict__ xs_bf){
  int idx = blockIdx.x*256 + threadIdx.x;   // (L_SEQ/CLB)*128 threads
  int cg = idx & 127, lb = idx >> 7;
  int c4 = cg*4;
  int l0 = lb*CLB;
  float w[4][4], bias[4];
#pragma unroll
  for(int j=0;j<4;j++){
    float4 wv = *(const float4*)&cw[(c4+j)*4];
    w[j][0]=wv.x; w[j][1]=wv.y; w[j][2]=wv.z; w[j][3]=wv.w;
  }
  { float4 bv = *(const float4*)&cb[c4];
    bias[0]=bv.x; bias[1]=bv.y; bias[2]=bv.z; bias[3]=bv.w; }
  float xm0[4], xm1[4], xm2[4];   // x[l-3], x[l-2], x[l-1]
#pragma unroll
  for(int j=0;j<4;j++){ xm0[j]=0.f; xm1[j]=0.f; xm2[j]=0.f; }
  if(l0 >= 3){
    ushort4 r0 = *(const ushort4*)&xz[(l0-3)*1024 + c4];
    ushort4 r1 = *(const ushort4*)&xz[(l0-2)*1024 + c4];
    ushort4 r2 = *(const ushort4*)&xz[(l0-1)*1024 + c4];
    xm0[0]=bf2f(r0.x); xm0[1]=bf2f(r0.y); xm0[2]=bf2f(r0.z); xm0[3]=bf2f(r0.w);
    xm1[0]=bf2f(r1.x); xm1[1]=bf2f(r1.y); xm1[2]=bf2f(r1.z); xm1[3]=bf2f(r1.w);
    xm2[0]=bf2f(r2.x); xm2[1]=bf2f(r2.y); xm2[2]=bf2f(r2.z); xm2[3]=bf2f(r2.w);
  }
  for(int l=l0; l<l0+CLB; l++){
    ushort4 rc = *(const ushort4*)&xz[l*1024 + c4];
    float xc[4] = {bf2f(rc.x), bf2f(rc.y), bf2f(rc.z), bf2f(rc.w)};
    __hip_bfloat16 ob[4];
#pragma unroll
    for(int j=0;j<4;j++){
      float acc = bias[j];
      acc = fmaf(xm0[j], w[j][0], acc);
      acc = fmaf(xm1[j], w[j][1], acc);
      acc = fmaf(xm2[j], w[j][2], acc);
      acc = fmaf(xc[j],  w[j][3], acc);
      ob[j] = __float2bfloat16(silu_f(acc));
    }
    *(uint2*)&xs_bf[l*DI + c4] = *(uint2*)ob;
#pragma unroll
    for(int j=0;j<4;j++){ xm0[j]=xm1[j]; xm1[j]=xm2[j]; xm2[j]=xc[j]; }
  }
}

// ---- scan phase 1: per-chunk (prod dA, local carry) per state.
//      Fast path: A[n] == (n+1)*A[0] -> dA[n] = r^(n+1), r = exp(d*A[0]). ----
__global__ __launch_bounds__(256) void k_scan1(const __hip_bfloat16* __restrict__ delta,
                        const __hip_bfloat16* __restrict__ xs,
                        const float* __restrict__ dbc32, const float* __restrict__ A_log,
                        float* __restrict__ Atot, float* __restrict__ Btot){
  __shared__ float bcs[CHL*32];
  int t = threadIdx.x;
  int chunk = blockIdx.x >> 1;
  int e = ((blockIdx.x & 1) << 8) + t;
  int l0 = chunk*CHL;
  ((float4*)bcs)[t] = ((const float4*)&dbc32[l0*32])[t];
  float A[16];
  {
    const float4* al = (const float4*)&A_log[e*DS];
#pragma unroll
    for(int q=0;q<4;q++){
      float4 a = al[q];
      A[q*4+0] = -__expf(a.x); A[q*4+1] = -__expf(a.y);
      A[q*4+2] = -__expf(a.z); A[q*4+3] = -__expf(a.w);
    }
  }
  bool pf = true;
#pragma unroll
  for(int n=1;n<16;n++) pf = pf && (fabsf(A[n] - (n+1)*A[0]) <= 1e-4f*fabsf(A[n]));
  float carry[16], aprod[16];
#pragma unroll
  for(int n=0;n<16;n++){ carry[n]=0.f; aprod[n]=1.f; }
  __syncthreads();
  if(pf){
    float A0 = A[0];
#pragma unroll 2
    for(int li=0; li<CHL; li++){
      int l = l0 + li;
      float d  = bf2f(*(const unsigned short*)&delta[l*DI+e]);
      float xv = bf2f(*(const unsigned short*)&xs[l*DI+e]);
      float dxv = d*xv;
      const float4* bp = (const float4*)&bcs[li*32];
      float4 b0=bp[0], b1=bp[1], b2=bp[2], b3=bp[3];
      float B[16] = {b0.x,b0.y,b0.z,b0.w, b1.x,b1.y,b1.z,b1.w,
                     b2.x,b2.y,b2.z,b2.w, b3.x,b3.y,b3.z,b3.w};
      float r = __expf(d*A0);
      float dA[16]; powers16(r, dA);
#pragma unroll
      for(int n=0;n<16;n++){
        carry[n] = fmaf(carry[n], dA[n], dxv*B[n]);
        aprod[n] *= dA[n];
      }
    }
  } else {
#pragma unroll 2
    for(int li=0; li<CHL; li++){
      int l = l0 + li;
      float d  = bf2f(*(const unsigned short*)&delta[l*DI+e]);
      float xv = bf2f(*(const unsigned short*)&xs[l*DI+e]);
      float dxv = d*xv;
      const float4* bp = (const float4*)&bcs[li*32];
      float4 b0=bp[0], b1=bp[1], b2=bp[2], b3=bp[3];
      float B[16] = {b0.x,b0.y,b0.z,b0.w, b1.x,b1.y,b1.z,b1.w,
                     b2.x,b2.y,b2.z,b2.w, b3.x,b3.y,b3.z,b3.w};
#pragma unroll
      for(int n=0;n<16;n++){
        float dA = __expf(d*A[n]);
        carry[n] = fmaf(carry[n], dA, dxv*B[n]);
        aprod[n] *= dA;
      }
    }
  }
  float4* ap = (float4*)&Atot[chunk*8192 + e*DS];
  float4* bp = (float4*)&Btot[chunk*8192 + e*DS];
#pragma unroll
  for(int q=0;q<4;q++){
    ap[q] = make_float4(aprod[q*4],aprod[q*4+1],aprod[q*4+2],aprod[q*4+3]);
    bp[q] = make_float4(carry[q*4],carry[q*4+1],carry[q*4+2],carry[q*4+3]);
  }
}

// ---- scan phase 2: carry-in per chunk (h0 aliases Btot: load-before-store) ----
__global__ void k_scan2(const float* __restrict__ Atot, const float* __restrict__ Btot,
                        float* __restrict__ h0){
  int tg = blockIdx.x*256 + threadIdx.x;
  float carry = 0.f;
  for(int c=0;c<NCH;c++){
    float a = Atot[c*8192+tg];
    float b = Btot[c*8192+tg];
    h0[c*8192+tg] = carry;
    carry = fmaf(carry, a, b);
  }
}

// ---- scan phase 3: replay with carry-in, y = (sum h*C + xs*D)*silu(z) -> bf16 ----
__global__ __launch_bounds__(256) void k_scan3(const __hip_bfloat16* __restrict__ delta,
                        const __hip_bfloat16* __restrict__ xs,
                        const float* __restrict__ dbc32, const float* __restrict__ A_log,
                        const float* __restrict__ Dp, const float* __restrict__ h0,
                        const __hip_bfloat16* __restrict__ xz, __hip_bfloat16* __restrict__ y){
  __shared__ float bcs[CHL*32];
  int t = threadIdx.x;
  int chunk = blockIdx.x >> 1;
  int e = ((blockIdx.x & 1) << 8) + t;
  int l0 = chunk*CHL;
  ((float4*)bcs)[t] = ((const float4*)&dbc32[l0*32])[t];
  float A[16];
  {
    const float4* al = (const float4*)&A_log[e*DS];
#pragma unroll
    for(int q=0;q<4;q++){
      float4 a = al[q];
      A[q*4+0] = -__expf(a.x); A[q*4+1] = -__expf(a.y);
      A[q*4+2] = -__expf(a.z); A[q*4+3] = -__expf(a.w);
    }
  }
  bool pf = true;
#pragma unroll
  for(int n=1;n<16;n++) pf = pf && (fabsf(A[n] - (n+1)*A[0]) <= 1e-4f*fabsf(A[n]));
  float carry[16];
  {
    const float4* hp = (const float4*)&h0[chunk*8192 + e*DS];
#pragma unroll
    for(int q=0;q<4;q++){
      float4 h = hp[q];
      carry[q*4+0]=h.x; carry[q*4+1]=h.y; carry[q*4+2]=h.z; carry[q*4+3]=h.w;
    }
  }
  float Dv = Dp[e];
  __syncthreads();
  if(pf){
    float A0 = A[0];
#pragma unroll 2
    for(int li=0; li<CHL; li++){
      int l = l0 + li;
      float d  = bf2f(*(const unsigned short*)&delta[l*DI+e]);
      float xv = bf2f(*(const unsigned short*)&xs[l*DI+e]);
      float dxv = d*xv;
      const float4* bp = (const float4*)&bcs[li*32];
      float4 b0=bp[0], b1=bp[1], b2=bp[2], b3=bp[3];
      float4 c0=bp[4], c1=bp[5], c2=bp[6], c3=bp[7];
      float B[16] = {b0.x,b0.y,b0.z,b0.w, b1.x,b1.y,b1.z,b1.w,
                     b2.x,b2.y,b2.z,b2.w, b3.x,b3.y,b3.z,b3.w};
      float Cv[16] = {c0.x,c0.y,c0.z,c0.w, c1.x,c1.y,c1.z,c1.w,
                      c2.x,c2.y,c2.z,c2.w, c3.x,c3.y,c3.z,c3.w};
      float r = __expf(d*A0);
      float dA[16]; powers16(r, dA);
      float p[4] = {0.f,0.f,0.f,0.f};
#pragma unroll
      for(int n=0;n<16;n++){
        carry[n] = fmaf(carry[n], dA[n], dxv*B[n]);
        p[n&3] = fmaf(carry[n], Cv[n], p[n&3]);
      }
      float ps = (p[0]+p[1]) + (p[2]+p[3]);
      float z = bf2f(*(const unsigned short*)&xz[l*1024 + 512 + e]);
      y[l*DI+e] = __float2bfloat16(fmaf(xv, Dv, ps) * silu_f(z));
    }
  } else {
#pragma unroll 2
    for(int li=0; li<CHL; li++){
      int l = l0 + li;
      float d  = bf2f(*(const unsigned short*)&delta[l*DI+e]);
      float xv = bf2f(*(const unsigned short*)&xs[l*DI+e]);
      float dxv = d*xv;
      const float4* bp = (const float4*)&bcs[li*32];
      float4 b0=bp[0], b1=bp[1], b2=bp[2], b3=bp[3];
      float4 c0=bp[4], c1=bp[5], c2=bp[6], c3=bp[7];
      float B[16] = {b0.x,b0.y,b0.z,b0.w, b1.x,b1.y,b1.z,b1.w,
                     b2.x,b2.y,b2.z,b2.w, b3.x,b3.y,b3.z,b3.w};
      float Cv[16] = {c0.x,c0.y,c0.z,c0.w, c1.x,c1.y,c1.z,c1.w,
                      c2.x,c2.y,c2.z,c2.w, c3.x,c3.y,c3.z,c3.w};
      float p[4] = {0.f,0.f,0.f,0.f};
#pragma unroll
      for(int n=0;n<16;n++){
        float dA = __expf(d*A[n]);
        carry[n] = fmaf(carry[n], dA, dxv*B[n]);
        p[n&3] = fmaf(carry[n], Cv[n], p[n&3]);
      }
      float ps = (p[0]+p[1]) + (p[2]+p[3]);
      float z = bf2f(*(const unsigned short*)&xz[l*1024 + 512 + e]);
      y[l*DI+e] = __float2bfloat16(fmaf(xv, Dv, ps) * silu_f(z));
    }
  }
}

// ---- final: LN(128) -> @W2(128,1)+b2 -> tanh, one wave per row ----
__global__ void k_final(const float* __restrict__ h2, const float* __restrict__ g,
                        const float* __restrict__ b, const float* __restrict__ W2,
                        const float* __restrict__ b2, float* __restrict__ out){
  int lane = threadIdx.x&63;
  int wv = threadIdx.x>>6;
  int r = blockIdx.x*4 + wv;
  float v0 = h2[r*128+lane], v1 = h2[r*128+64+lane];
  float s = v0+v1, sq = v0*v0+v1*v1;
#pragma unroll
  for(int o=32;o;o>>=1){ s += __shfl_xor(s,o); sq += __shfl_xor(sq,o); }
  float mean = s*(1.0f/128), var = sq*(1.0f/128) - mean*mean;
  float rs = rsqrtf(var+1e-5f);
  float n0 = (v0-mean)*rs*g[lane]+b[lane];
  float n1 = (v1-mean)*rs*g[lane+64]+b[lane+64];
  float d = n0*W2[lane] + n1*W2[lane+64];
#pragma unroll
  for(int o=32;o;o>>=1) d += __shfl_xor(d,o);
  if(lane==0) out[r] = tanhf(d + b2[0]);
}

extern "C" void kernel_launch(void* const* d_in, const int* in_sizes, int n_in,
                              void* d_out, int out_size, void* d_ws, size_t ws_size,
                              hipStream_t stream){
  const float* x    = (const float*)d_in[0];
  const float* Win  = (const float*)d_in[1];
  const float* bin  = (const float*)d_in[2];
  const float* ln1g = (const float*)d_in[3];
  const float* ln1b = (const float*)d_in[4];
  const float* rmsw = (const float*)d_in[5];
  const float* inW  = (const float*)d_in[6];
  const float* convW= (const float*)d_in[7];
  const float* convB= (const float*)d_in[8];
  const float* xpW  = (const float*)d_in[9];
  const float* dtW  = (const float*)d_in[10];
  const float* dtB  = (const float*)d_in[11];
  const float* A_log= (const float*)d_in[12];
  const float* Dp   = (const float*)d_in[13];
  const float* outW = (const float*)d_in[14];
  const float* ln2g = (const float*)d_in[15];
  const float* ln2b = (const float*)d_in[16];
  const float* W1   = (const float*)d_in[17];
  const float* b1   = (const float*)d_in[18];
  const float* ln3g = (const float*)d_in[19];
  const float* ln3b = (const float*)d_in[20];
  const float* W2   = (const float*)d_in[21];
  const float* b2   = (const float*)d_in[22];
  float* out = (float*)d_out;
  float* ws = (float*)d_ws;
  __hip_bfloat16* u_bf = (__hip_bfloat16*)ws;                 // 16384*256 bf16 (8MB)
  __hip_bfloat16* hn_bf = (__hip_bfloat16*)(ws + 4194304);    // 16384*256 bf16
  __hip_bfloat16* xz_bf = (__hip_bfloat16*)(ws + 8388608);    // 16384*1024 bf16
  float* dbc32 = ws + 16777216;                               // 16384*32 f32
  __hip_bfloat16* delta_bf = (__hip_bfloat16*)(ws + 17301504);// 16384*512 bf16
  __hip_bfloat16* y_bf  = (__hip_bfloat16*)(ws + 25690112);   // 16384*512 bf16
  __hip_bfloat16* xs_bf = (__hip_bfloat16*)(ws + 29884416);   // 16384*512 bf16
  float* Atot  = ws + 34078720;                               // NCH*8192 f32
  float* Btot  = ws + 38273024;                               // NCH*8192 f32
  float* h0    = Btot;                  // aliased (scan2 loads before store)
  float* h2    = ws;                    // aliased (u dead after k_ln; 8MB fits)
  __hip_bfloat16* inWt   = (__hip_bfloat16*)(ws + 42467328);  // 2*1024*256 bf16
  __hip_bfloat16* outWt  = (__hip_bfloat16*)(ws + 42729472);  // 2*256*512 bf16
  __hip_bfloat16* W1t    = (__hip_bfloat16*)(ws + 42860544);  // 128*256 bf16
  __hip_bfloat16* Wd_t   = (__hip_bfloat16*)(ws + 42876928);  // 2*512*512 bf16
  __hip_bfloat16* Wbc_t  = (__hip_bfloat16*)(ws + 43139072);  // 2*128*512 bf16

  k_cvtw<<<3200,256,0,stream>>>(inW, outW, W1, inWt, outWt, W1t);
  k_wd<<<2560,256,0,stream>>>(xpW, dtW, Wd_t, Wbc_t);
  k_input<<<L_SEQ/4,256,0,stream>>>(x,Win,bin,ln1g,ln1b,u_bf);
  for(int i=0;i<2;i++){
    k_rms<<<L_SEQ/4,256,0,stream>>>(u_bf, rmsw+i*DM, hn_bf);
    k_mgemm<0,__hip_bfloat16><<<dim3(8, L_SEQ/128),256,0,stream>>>(hn_bf, inWt+i*262144, nullptr, nullptr, xz_bf, L_SEQ, DM, 1024, 1024);
    k_conv<<<(L_SEQ/CLB)*128/256,256,0,stream>>>(xz_bf, convW+i*DI*4, convB+i*DI, xs_bf);
    k_mgemm<3,__hip_bfloat16><<<dim3(4, L_SEQ/128),256,0,stream>>>(xs_bf, Wd_t+i*262144, dtB+i*DI, nullptr, delta_bf, L_SEQ, DI, 512, 512);
    k_mgemm<0,float><<<dim3(1, L_SEQ/128),256,0,stream>>>(xs_bf, Wbc_t+i*65536, nullptr, nullptr, dbc32, L_SEQ, DI, 32, 32);
    k_scan1<<<NCH*2,256,0,stream>>>(delta_bf, xs_bf, dbc32, A_log+i*DI*DS, Atot, Btot);
    k_scan2<<<32,256,0,stream>>>(Atot, Btot, h0);
    k_scan3<<<NCH*2,256,0,stream>>>(delta_bf, xs_bf, dbc32, A_log+i*DI*DS, Dp+i*DI, h0, xz_bf, y_bf);
    k_mgemm<1,__hip_bfloat16><<<dim3(2, L_SEQ/128),256,0,stream>>>(y_bf, outWt+i*131072, nullptr, u_bf, u_bf, L_SEQ, DI, 256, 256);
  }
  k_ln<<<L_SEQ/4,256,0,stream>>>(u_bf, ln2g, ln2b, hn_bf);
  k_mgemm<2,float><<<dim3(1, L_SEQ/128),256,0,stream>>>(hn_bf, W1t, b1, nullptr, h2, L_SEQ, DM, 128, 128);
  k_final<<<L_SEQ/4,256,0,stream>>>(h2, ln3g, ln3b, W2, b2, out);
}

// Round 12
// 445.207 us; speedup vs baseline: 1.2610x; 1.0152x over previous
//
#include <hip/hip_runtime.h>
#include <hip/hip_bf16.h>
#include <math.h>

#define L_SEQ 16384
#define DM 256
#define DI 512
#define DS 16
#define NCH 512   // number of scan chunks
#define CHL 32    // chunk length (NCH*CHL == L_SEQ)
#define CLB 16    // conv: timesteps per thread

typedef __attribute__((ext_vector_type(8))) short short8v;
typedef __attribute__((ext_vector_type(4))) float f32x4;

__device__ __forceinline__ float tanh_fast(float x){
  float xc = fminf(x, 15.f);
  float t = __expf(2.f*xc);
  return (t-1.f)/(t+1.f);
}
__device__ __forceinline__ float gelu_f(float x){
  float x3 = x*x*x;
  return 0.5f*x*(1.0f + tanh_fast(0.7978845608028654f*(x + 0.044715f*x3)));
}
__device__ __forceinline__ float silu_f(float x){
  return x / (1.0f + __expf(-x));
}
__device__ __forceinline__ float softplus_f(float x){
  return fmaxf(x,0.0f) + __logf(1.0f + __expf(-fabsf(x)));
}
__device__ __forceinline__ float bf2f(unsigned short u){
  return __uint_as_float(((unsigned int)u)<<16);
}
__device__ __forceinline__ void gload16(const void* g, void* l){
  __builtin_amdgcn_global_load_lds((const __attribute__((address_space(1))) void*)g,
                                   (__attribute__((address_space(3))) void*)l, 16, 0, 0);
}

// r^(n+1) for n=0..15, ~16 muls, depth ~4 (replaces 16 quarter-rate exps)
__device__ __forceinline__ void powers16(float r, float* dA){
  float r2 = r*r;
  float r4 = r2*r2;
  float r8 = r4*r4;
  dA[0]=r;        dA[1]=r2;       dA[2]=r2*r;     dA[3]=r4;
  dA[4]=r4*r;     dA[5]=r4*r2;    dA[6]=r4*dA[2]; dA[7]=r8;
  dA[8]=r8*r;     dA[9]=r8*r2;    dA[10]=r8*dA[2];dA[11]=r8*r4;
  dA[12]=r8*dA[4];dA[13]=r8*dA[5];dA[14]=r8*dA[6];dA[15]=r8*r8;
}

// ---- weight convert + transpose to bf16: Wt[n][k] = bf16(W[k][n]) ----
__global__ void k_cvtw(const float* __restrict__ inW, const float* __restrict__ outW,
                       const float* __restrict__ W1, __hip_bfloat16* __restrict__ inWt,
                       __hip_bfloat16* __restrict__ outWt, __hip_bfloat16* __restrict__ W1t){
  int idx = blockIdx.x*256 + threadIdx.x;
  if(idx < 524288){                      // inW: 2 layers of [256][1024] -> [1024][256]
    int layer = idx >> 18;
    int r = idx & 262143;
    int n = r >> 8, k = r & 255;
    inWt[idx] = __float2bfloat16(inW[layer*262144 + k*1024 + n]);
  } else if(idx < 786432){               // outW: 2 layers of [512][256] -> [256][512]
    int j = idx - 524288;
    int layer = j >> 17;
    int r = j & 131071;
    int n = r >> 9, k = r & 511;
    outWt[j] = __float2bfloat16(outW[layer*131072 + k*256 + n]);
  } else if(idx < 819200){               // W1: [256][128] -> [128][256]
    int j = idx - 786432;
    int n = j >> 8, k = j & 255;
    W1t[j] = __float2bfloat16(W1[k*128 + n]);
  }
}

// ---- fold xpW/dtW: Wd_t[layer][n][k] = sum_j xpW[k][j]*dtW[j][n] (delta pre-act),
//      Wbc_t[layer][n][k] = xpW[k][16+n] for n<32, 0 pad to 128 rows ----
__global__ void k_wd(const float* __restrict__ xpW, const float* __restrict__ dtW,
                     __hip_bfloat16* __restrict__ Wd_t, __hip_bfloat16* __restrict__ Wbc_t){
  int idx = blockIdx.x*256 + threadIdx.x;
  if(idx < 524288){                      // 2 layers x [512 n][512 k]
    int layer = idx >> 18;
    int r = idx & 262143;
    int n = r >> 9, k = r & 511;
    const float* xp = xpW + layer*512*48;
    const float* dt = dtW + layer*16*512;
    float s = 0.f;
#pragma unroll
    for(int j=0;j<16;j++) s = fmaf(xp[k*48+j], dt[j*512+n], s);
    Wd_t[idx] = __float2bfloat16(s);
  } else if(idx < 655360){               // 2 layers x [128 n][512 k]
    int j2 = idx - 524288;
    int layer = j2 >> 16;
    int r = j2 & 65535;
    int n = r >> 9, k = r & 511;
    float v = (n < 32) ? xpW[layer*512*48 + k*48 + 16 + n] : 0.f;
    Wbc_t[j2] = __float2bfloat16(v);
  }
}

// ---- input projection + LN + gelu: u = gelu(LN(x@Win + bin)) -> bf16. ----
__global__ __launch_bounds__(256) void k_input(const float* __restrict__ x,
                        const float* __restrict__ Win, const float* __restrict__ bin,
                        const float* __restrict__ g, const float* __restrict__ b,
                        __hip_bfloat16* __restrict__ u){
  int wv = threadIdx.x>>6, lane = threadIdx.x&63;
  int r = blockIdx.x*4 + wv;
  int c0 = lane*4;
  float acc[4];
  { float4 bv = *(const float4*)&bin[c0];
    acc[0]=bv.x; acc[1]=bv.y; acc[2]=bv.z; acc[3]=bv.w; }
#pragma unroll
  for(int k=0;k<32;k++){
    float xk = x[r*32+k];
    float4 wv4 = *(const float4*)&Win[k*DM+c0];
    acc[0]=fmaf(xk,wv4.x,acc[0]); acc[1]=fmaf(xk,wv4.y,acc[1]);
    acc[2]=fmaf(xk,wv4.z,acc[2]); acc[3]=fmaf(xk,wv4.w,acc[3]);
  }
  float s = (acc[0]+acc[1])+(acc[2]+acc[3]);
  float sq = acc[0]*acc[0]+acc[1]*acc[1]+acc[2]*acc[2]+acc[3]*acc[3];
#pragma unroll
  for(int o=32;o;o>>=1){ s += __shfl_xor(s,o); sq += __shfl_xor(sq,o); }
  float mean = s*(1.0f/DM);
  float var = sq*(1.0f/DM) - mean*mean;
  float rs = rsqrtf(var+1e-5f);
  float4 gv = *(const float4*)&g[c0];
  float4 bv = *(const float4*)&b[c0];
  __hip_bfloat16 ob[4] = {
    __float2bfloat16(gelu_f((acc[0]-mean)*rs*gv.x+bv.x)),
    __float2bfloat16(gelu_f((acc[1]-mean)*rs*gv.y+bv.y)),
    __float2bfloat16(gelu_f((acc[2]-mean)*rs*gv.z+bv.z)),
    __float2bfloat16(gelu_f((acc[3]-mean)*rs*gv.w+bv.w))};
  *(uint2*)&u[r*DM+c0] = *(uint2*)ob;
}

// ---- rmsnorm over 256 (bf16 in -> bf16 out), wave per row ----
__global__ __launch_bounds__(256) void k_rms(const __hip_bfloat16* __restrict__ u,
                      const float* __restrict__ w, __hip_bfloat16* __restrict__ o){
  int wv = threadIdx.x>>6, lane = threadIdx.x&63;
  int r = blockIdx.x*4 + wv;
  int c0 = lane*4;
  ushort4 uv = *(const ushort4*)&u[r*DM+c0];
  float v0=bf2f(uv.x), v1=bf2f(uv.y), v2=bf2f(uv.z), v3=bf2f(uv.w);
  float sq = v0*v0+v1*v1+v2*v2+v3*v3;
#pragma unroll
  for(int s=32;s;s>>=1) sq += __shfl_xor(sq,s);
  float rs = rsqrtf(sq*(1.0f/DM)+1e-5f);
  float4 wv4 = *(const float4*)&w[c0];
  __hip_bfloat16 ob[4] = {
    __float2bfloat16(v0*rs*wv4.x), __float2bfloat16(v1*rs*wv4.y),
    __float2bfloat16(v2*rs*wv4.z), __float2bfloat16(v3*rs*wv4.w)};
  *(uint2*)&o[r*DM+c0] = *(uint2*)ob;
}

// ---- layernorm over 256 (bf16 in -> bf16 out), wave per row ----
__global__ __launch_bounds__(256) void k_ln(const __hip_bfloat16* __restrict__ u,
                     const float* __restrict__ g, const float* __restrict__ b,
                     __hip_bfloat16* __restrict__ o){
  int wv = threadIdx.x>>6, lane = threadIdx.x&63;
  int r = blockIdx.x*4 + wv;
  int c0 = lane*4;
  ushort4 uv = *(const ushort4*)&u[r*DM+c0];
  float v[4] = {bf2f(uv.x), bf2f(uv.y), bf2f(uv.z), bf2f(uv.w)};
  float s = (v[0]+v[1])+(v[2]+v[3]);
  float sq = v[0]*v[0]+v[1]*v[1]+v[2]*v[2]+v[3]*v[3];
#pragma unroll
  for(int o2=32;o2;o2>>=1){ s += __shfl_xor(s,o2); sq += __shfl_xor(sq,o2); }
  float mean = s*(1.0f/DM);
  float var = sq*(1.0f/DM) - mean*mean;
  float rs = rsqrtf(var+1e-5f);
  float4 gv = *(const float4*)&g[c0];
  float4 bv = *(const float4*)&b[c0];
  __hip_bfloat16 ob[4] = {
    __float2bfloat16((v[0]-mean)*rs*gv.x+bv.x),
    __float2bfloat16((v[1]-mean)*rs*gv.y+bv.y),
    __float2bfloat16((v[2]-mean)*rs*gv.z+bv.z),
    __float2bfloat16((v[3]-mean)*rs*gv.w+bv.w)};
  *(uint2*)&o[r*DM+c0] = *(uint2*)ob;
}

// ---- bf16 MFMA GEMM, 8 waves (512 thr), BK=128 single-buffer + XCD remap +
//      LDS-staged coalesced epilogue. C = A[M,K] @ Wt[N,K]^T.
//      EPI: 0=store, 1=+R, 2=gelu(+bias), 3=softplus(+bias). ----
template<int EPI, typename OT>
__global__ __launch_bounds__(512) void k_mgemm(const __hip_bfloat16* __restrict__ A,
    const __hip_bfloat16* __restrict__ Wt, const float* __restrict__ bias,
    const OT* __restrict__ R, OT* __restrict__ C, int M, int K, int ldc, int Nout){
  __shared__ char lds[69632];          // stage: As 32K | Bs 32K ; epi: Obuf 128x132 f32
  short* As = (short*)lds;             // [128 rows][128 k], 16-slot XOR swizzle
  short* Bs = (short*)(lds + 32768);
  float* Ob = (float*)lds;             // [128][132]
  int t = threadIdx.x, lane = t&63, wave = t>>6;   // 8 waves
  // XCD-aware tile remap (block f -> XCD f%8; XCD owns contiguous y-panels)
  int gx = gridDim.x;
  int f = blockIdx.y*gx + blockIdx.x;
  int s = f >> 3;
  int sy = s/gx;
  int yb = (f&7)*(gridDim.y>>3) + sy;
  int xb = s - sy*gx;
  int m0 = yb*128, n0 = xb*128;
  int wm = (wave>>1)*32, wn = (wave&1)*64;   // wave owns 32 rows x 64 cols
  f32x4 acc[2][4] = {};
  int nk = K >> 7;
  for(int ki=0; ki<nk; ki++){
    int kt = ki<<7;
    __syncthreads();
#pragma unroll
    for(int c=0;c<4;c++){
      int off = c*8192 + t*16;         // byte offset in 32KB half
      int row = off>>8;                // 256B rows
      int sl  = ((off>>4)&15) ^ (row&15);
      gload16(&A [(m0+row)*K + kt + sl*8], (char*)As + off);
      gload16(&Wt[(n0+row)*K + kt + sl*8], (char*)Bs + off);
    }
    asm volatile("s_waitcnt vmcnt(0)" ::: "memory");
    __syncthreads();
#pragma unroll
    for(int ks=0; ks<4; ks++){
      short8v a[2], b[4];
      int k8 = ks*4 + (lane>>4);
#pragma unroll
      for(int i=0;i<2;i++){
        int lr = wm + i*16 + (lane&15);
        a[i] = *(const short8v*)&As[lr*128 + (k8 ^ (lr&15))*8];
      }
#pragma unroll
      for(int j=0;j<4;j++){
        int lr = wn + j*16 + (lane&15);
        b[j] = *(const short8v*)&Bs[lr*128 + (k8 ^ (lr&15))*8];
      }
#pragma unroll
      for(int i=0;i<2;i++)
#pragma unroll
        for(int j=0;j<4;j++)
          acc[i][j] = __builtin_amdgcn_mfma_f32_16x16x32_bf16(a[i], b[j], acc[i][j], 0,0,0);
    }
  }
  __syncthreads();   // all LDS reads done before Obuf overwrites stage buffers
#pragma unroll
  for(int i=0;i<2;i++){
    int r0 = wm + i*16 + (lane>>4)*4;
#pragma unroll
    for(int j=0;j<4;j++){
      int cl = wn + j*16 + (lane&15);
#pragma unroll
      for(int r=0;r<4;r++) Ob[(r0+r)*132 + cl] = acc[i][j][r];
    }
  }
  __syncthreads();
  // coalesced copy + epilogue: 512 threads x 8 float4 = 128x128
#pragma unroll
  for(int v=0; v<8; v++){
    int fidx = (t*8+v)*4;
    int row = fidx>>7, col = fidx&127;
    if(col < Nout){
      float4 o = *(const float4*)&Ob[row*132 + col];
      int grow = m0 + row, gcol = n0 + col;
      if(EPI==1){
        if constexpr(sizeof(OT)==2){
          ushort4 rv = *(const ushort4*)&R[grow*ldc+gcol];
          o.x+=bf2f(rv.x); o.y+=bf2f(rv.y); o.z+=bf2f(rv.z); o.w+=bf2f(rv.w);
        } else {
          float4 rv = *(const float4*)&R[grow*ldc+gcol];
          o.x+=rv.x; o.y+=rv.y; o.z+=rv.z; o.w+=rv.w;
        }
      }
      if(EPI==2){
        float4 bv = *(const float4*)&bias[gcol];
        o.x=gelu_f(o.x+bv.x); o.y=gelu_f(o.y+bv.y);
        o.z=gelu_f(o.z+bv.z); o.w=gelu_f(o.w+bv.w);
      }
      if(EPI==3){
        float4 bv = *(const float4*)&bias[gcol];
        o.x=softplus_f(o.x+bv.x); o.y=softplus_f(o.y+bv.y);
        o.z=softplus_f(o.z+bv.z); o.w=softplus_f(o.w+bv.w);
      }
      if constexpr(sizeof(OT)==2){
        __hip_bfloat16 ob[4] = {__float2bfloat16(o.x),__float2bfloat16(o.y),
                                __float2bfloat16(o.z),__float2bfloat16(o.w)};
        *(uint2*)&C[grow*ldc+gcol] = *(uint2*)ob;
      } else {
        *(float4*)&C[grow*ldc+gcol] = o;
      }
    }
  }
}

// ---- causal depthwise conv (k=4) + bias + silu, sliding window. ----
__global__ __launch_bounds__(256) void k_conv(const __hip_bfloat16* __restrict__ xz,
                       const float* __restrict__ cw, const float* __restrict__ cb,
                       __hip_bfloat16* __restrict__ xs_bf){
  int idx = blockIdx.x*256 + threadIdx.x;   // (L_SEQ/CLB)*128 threads
  int cg = idx & 127, lb = idx >> 7;
  int c4 = cg*4;
  int l0 = lb*CLB;
  float w[4][4], bias[4];
#pragma unroll
  for(int j=0;j<4;j++){
    float4 wv = *(const float4*)&cw[(c4+j)*4];
    w[j][0]=wv.x; w[j][1]=wv.y; w[j][2]=wv.z; w[j][3]=wv.w;
  }
  { float4 bv = *(const float4*)&cb[c4];
    bias[0]=bv.x; bias[1]=bv.y; bias[2]=bv.z; bias[3]=bv.w; }
  float xm0[4], xm1[4], xm2[4];   // x[l-3], x[l-2], x[l-1]
#pragma unroll
  for(int j=0;j<4;j++){ xm0[j]=0.f; xm1[j]=0.f; xm2[j]=0.f; }
  if(l0 >= 3){
    ushort4 r0 = *(const ushort4*)&xz[(l0-3)*1024 + c4];
    ushort4 r1 = *(const ushort4*)&xz[(l0-2)*1024 + c4];
    ushort4 r2 = *(const ushort4*)&xz[(l0-1)*1024 + c4];
    xm0[0]=bf2f(r0.x); xm0[1]=bf2f(r0.y); xm0[2]=bf2f(r0.z); xm0[3]=bf2f(r0.w);
    xm1[0]=bf2f(r1.x); xm1[1]=bf2f(r1.y); xm1[2]=bf2f(r1.z); xm1[3]=bf2f(r1.w);
    xm2[0]=bf2f(r2.x); xm2[1]=bf2f(r2.y); xm2[2]=bf2f(r2.z); xm2[3]=bf2f(r2.w);
  }
#pragma unroll 4
  for(int l=l0; l<l0+CLB; l++){
    ushort4 rc = *(const ushort4*)&xz[l*1024 + c4];
    float xc[4] = {bf2f(rc.x), bf2f(rc.y), bf2f(rc.z), bf2f(rc.w)};
    __hip_bfloat16 ob[4];
#pragma unroll
    for(int j=0;j<4;j++){
      float acc = bias[j];
      acc = fmaf(xm0[j], w[j][0], acc);
      acc = fmaf(xm1[j], w[j][1], acc);
      acc = fmaf(xm2[j], w[j][2], acc);
      acc = fmaf(xc[j],  w[j][3], acc);
      ob[j] = __float2bfloat16(silu_f(acc));
    }
    *(uint2*)&xs_bf[l*DI + c4] = *(uint2*)ob;
#pragma unroll
    for(int j=0;j<4;j++){ xm0[j]=xm1[j]; xm1[j]=xm2[j]; xm2[j]=xc[j]; }
  }
}

// ---- scan phase 1: per-chunk (prod dA, local carry) per state.
//      Fast path: A[n] == (n+1)*A[0] -> dA[n] = r^(n+1), r = exp(d*A[0]). ----
__global__ __launch_bounds__(256) void k_scan1(const __hip_bfloat16* __restrict__ delta,
                        const __hip_bfloat16* __restrict__ xs,
                        const float* __restrict__ dbc32, const float* __restrict__ A_log,
                        float* __restrict__ Atot, float* __restrict__ Btot){
  __shared__ float bcs[CHL*32];
  int t = threadIdx.x;
  int chunk = blockIdx.x >> 1;
  int e = ((blockIdx.x & 1) << 8) + t;
  int l0 = chunk*CHL;
  ((float4*)bcs)[t] = ((const float4*)&dbc32[l0*32])[t];
  float A[16];
  {
    const float4* al = (const float4*)&A_log[e*DS];
#pragma unroll
    for(int q=0;q<4;q++){
      float4 a = al[q];
      A[q*4+0] = -__expf(a.x); A[q*4+1] = -__expf(a.y);
      A[q*4+2] = -__expf(a.z); A[q*4+3] = -__expf(a.w);
    }
  }
  bool pf = true;
#pragma unroll
  for(int n=1;n<16;n++) pf = pf && (fabsf(A[n] - (n+1)*A[0]) <= 1e-4f*fabsf(A[n]));
  float carry[16], aprod[16];
#pragma unroll
  for(int n=0;n<16;n++){ carry[n]=0.f; aprod[n]=1.f; }
  __syncthreads();
  if(pf){
    float A0 = A[0];
#pragma unroll 2
    for(int li=0; li<CHL; li++){
      int l = l0 + li;
      float d  = bf2f(*(const unsigned short*)&delta[l*DI+e]);
      float xv = bf2f(*(const unsigned short*)&xs[l*DI+e]);
      float dxv = d*xv;
      const float4* bp = (const float4*)&bcs[li*32];
      float4 b0=bp[0], b1=bp[1], b2=bp[2], b3=bp[3];
      float B[16] = {b0.x,b0.y,b0.z,b0.w, b1.x,b1.y,b1.z,b1.w,
                     b2.x,b2.y,b2.z,b2.w, b3.x,b3.y,b3.z,b3.w};
      float r = __expf(d*A0);
      float dA[16]; powers16(r, dA);
#pragma unroll
      for(int n=0;n<16;n++){
        carry[n] = fmaf(carry[n], dA[n], dxv*B[n]);
        aprod[n] *= dA[n];
      }
    }
  } else {
#pragma unroll 2
    for(int li=0; li<CHL; li++){
      int l = l0 + li;
      float d  = bf2f(*(const unsigned short*)&delta[l*DI+e]);
      float xv = bf2f(*(const unsigned short*)&xs[l*DI+e]);
      float dxv = d*xv;
      const float4* bp = (const float4*)&bcs[li*32];
      float4 b0=bp[0], b1=bp[1], b2=bp[2], b3=bp[3];
      float B[16] = {b0.x,b0.y,b0.z,b0.w, b1.x,b1.y,b1.z,b1.w,
                     b2.x,b2.y,b2.z,b2.w, b3.x,b3.y,b3.z,b3.w};
#pragma unroll
      for(int n=0;n<16;n++){
        float dA = __expf(d*A[n]);
        carry[n] = fmaf(carry[n], dA, dxv*B[n]);
        aprod[n] *= dA;
      }
    }
  }
  float4* ap = (float4*)&Atot[chunk*8192 + e*DS];
  float4* bp = (float4*)&Btot[chunk*8192 + e*DS];
#pragma unroll
  for(int q=0;q<4;q++){
    ap[q] = make_float4(aprod[q*4],aprod[q*4+1],aprod[q*4+2],aprod[q*4+3]);
    bp[q] = make_float4(carry[q*4],carry[q*4+1],carry[q*4+2],carry[q*4+3]);
  }
}

// ---- scan phase 2: carry-in per chunk (h0 aliases Btot: load-before-store) ----
__global__ void k_scan2(const float* __restrict__ Atot, const float* __restrict__ Btot,
                        float* __restrict__ h0){
  int tg = blockIdx.x*256 + threadIdx.x;
  float carry = 0.f;
  for(int c=0;c<NCH;c++){
    float a = Atot[c*8192+tg];
    float b = Btot[c*8192+tg];
    h0[c*8192+tg] = carry;
    carry = fmaf(carry, a, b);
  }
}

// ---- scan phase 3: replay with carry-in, y = (sum h*C + xs*D)*silu(z) -> bf16 ----
__global__ __launch_bounds__(256) void k_scan3(const __hip_bfloat16* __restrict__ delta,
                        const __hip_bfloat16* __restrict__ xs,
                        const float* __restrict__ dbc32, const float* __restrict__ A_log,
                        const float* __restrict__ Dp, const float* __restrict__ h0,
                        const __hip_bfloat16* __restrict__ xz, __hip_bfloat16* __restrict__ y){
  __shared__ float bcs[CHL*32];
  int t = threadIdx.x;
  int chunk = blockIdx.x >> 1;
  int e = ((blockIdx.x & 1) << 8) + t;
  int l0 = chunk*CHL;
  ((float4*)bcs)[t] = ((const float4*)&dbc32[l0*32])[t];
  float A[16];
  {
    const float4* al = (const float4*)&A_log[e*DS];
#pragma unroll
    for(int q=0;q<4;q++){
      float4 a = al[q];
      A[q*4+0] = -__expf(a.x); A[q*4+1] = -__expf(a.y);
      A[q*4+2] = -__expf(a.z); A[q*4+3] = -__expf(a.w);
    }
  }
  bool pf = true;
#pragma unroll
  for(int n=1;n<16;n++) pf = pf && (fabsf(A[n] - (n+1)*A[0]) <= 1e-4f*fabsf(A[n]));
  float carry[16];
  {
    const float4* hp = (const float4*)&h0[chunk*8192 + e*DS];
#pragma unroll
    for(int q=0;q<4;q++){
      float4 h = hp[q];
      carry[q*4+0]=h.x; carry[q*4+1]=h.y; carry[q*4+2]=h.z; carry[q*4+3]=h.w;
    }
  }
  float Dv = Dp[e];
  __syncthreads();
  if(pf){
    float A0 = A[0];
#pragma unroll 2
    for(int li=0; li<CHL; li++){
      int l = l0 + li;
      float d  = bf2f(*(const unsigned short*)&delta[l*DI+e]);
      float xv = bf2f(*(const unsigned short*)&xs[l*DI+e]);
      float dxv = d*xv;
      const float4* bp = (const float4*)&bcs[li*32];
      float4 b0=bp[0], b1=bp[1], b2=bp[2], b3=bp[3];
      float4 c0=bp[4], c1=bp[5], c2=bp[6], c3=bp[7];
      float B[16] = {b0.x,b0.y,b0.z,b0.w, b1.x,b1.y,b1.z,b1.w,
                     b2.x,b2.y,b2.z,b2.w, b3.x,b3.y,b3.z,b3.w};
      float Cv[16] = {c0.x,c0.y,c0.z,c0.w, c1.x,c1.y,c1.z,c1.w,
                      c2.x,c2.y,c2.z,c2.w, c3.x,c3.y,c3.z,c3.w};
      float r = __expf(d*A0);
      float dA[16]; powers16(r, dA);
      float p[4] = {0.f,0.f,0.f,0.f};
#pragma unroll
      for(int n=0;n<16;n++){
        carry[n] = fmaf(carry[n], dA[n], dxv*B[n]);
        p[n&3] = fmaf(carry[n], Cv[n], p[n&3]);
      }
      float ps = (p[0]+p[1]) + (p[2]+p[3]);
      float z = bf2f(*(const unsigned short*)&xz[l*1024 + 512 + e]);
      y[l*DI+e] = __float2bfloat16(fmaf(xv, Dv, ps) * silu_f(z));
    }
  } else {
#pragma unroll 2
    for(int li=0; li<CHL; li++){
      int l = l0 + li;
      float d  = bf2f(*(const unsigned short*)&delta[l*DI+e]);
      float xv = bf2f(*(const unsigned short*)&xs[l*DI+e]);
      float dxv = d*xv;
      const float4* bp = (const float4*)&bcs[li*32];
      float4 b0=bp[0], b1=bp[1], b2=bp[2], b3=bp[3];
      float4 c0=bp[4], c1=bp[5], c2=bp[6], c3=bp[7];
      float B[16] = {b0.x,b0.y,b0.z,b0.w, b1.x,b1.y,b1.z,b1.w,
                     b2.x,b2.y,b2.z,b2.w, b3.x,b3.y,b3.z,b3.w};
      float Cv[16] = {c0.x,c0.y,c0.z,c0.w, c1.x,c1.y,c1.z,c1.w,
                      c2.x,c2.y,c2.z,c2.w, c3.x,c3.y,c3.z,c3.w};
      float p[4] = {0.f,0.f,0.f,0.f};
#pragma unroll
      for(int n=0;n<16;n++){
        float dA = __expf(d*A[n]);
        carry[n] = fmaf(carry[n], dA, dxv*B[n]);
        p[n&3] = fmaf(carry[n], Cv[n], p[n&3]);
      }
      float ps = (p[0]+p[1]) + (p[2]+p[3]);
      float z = bf2f(*(const unsigned short*)&xz[l*1024 + 512 + e]);
      y[l*DI+e] = __float2bfloat16(fmaf(xv, Dv, ps) * silu_f(z));
    }
  }
}

// ---- final: LN(128) -> @W2(128,1)+b2 -> tanh, one wave per row ----
__global__ void k_final(const float* __restrict__ h2, const float* __restrict__ g,
                        const float* __restrict__ b, const float* __restrict__ W2,
                        const float* __restrict__ b2, float* __restrict__ out){
  int lane = threadIdx.x&63;
  int wv = threadIdx.x>>6;
  int r = blockIdx.x*4 + wv;
  float v0 = h2[r*128+lane], v1 = h2[r*128+64+lane];
  float s = v0+v1, sq = v0*v0+v1*v1;
#pragma unroll
  for(int o=32;o;o>>=1){ s += __shfl_xor(s,o); sq += __shfl_xor(sq,o); }
  float mean = s*(1.0f/128), var = sq*(1.0f/128) - mean*mean;
  float rs = rsqrtf(var+1e-5f);
  float n0 = (v0-mean)*rs*g[lane]+b[lane];
  float n1 = (v1-mean)*rs*g[lane+64]+b[lane+64];
  float d = n0*W2[lane] + n1*W2[lane+64];
#pragma unroll
  for(int o=32;o;o>>=1) d += __shfl_xor(d,o);
  if(lane==0) out[r] = tanhf(d + b2[0]);
}

extern "C" void kernel_launch(void* const* d_in, const int* in_sizes, int n_in,
                              void* d_out, int out_size, void* d_ws, size_t ws_size,
                              hipStream_t stream){
  const float* x    = (const float*)d_in[0];
  const float* Win  = (const float*)d_in[1];
  const float* bin  = (const float*)d_in[2];
  const float* ln1g = (const float*)d_in[3];
  const float* ln1b = (const float*)d_in[4];
  const float* rmsw = (const float*)d_in[5];
  const float* inW  = (const float*)d_in[6];
  const float* convW= (const float*)d_in[7];
  const float* convB= (const float*)d_in[8];
  const float* xpW  = (const float*)d_in[9];
  const float* dtW  = (const float*)d_in[10];
  const float* dtB  = (const float*)d_in[11];
  const float* A_log= (const float*)d_in[12];
  const float* Dp   = (const float*)d_in[13];
  const float* outW = (const float*)d_in[14];
  const float* ln2g = (const float*)d_in[15];
  const float* ln2b = (const float*)d_in[16];
  const float* W1   = (const float*)d_in[17];
  const float* b1   = (const float*)d_in[18];
  const float* ln3g = (const float*)d_in[19];
  const float* ln3b = (const float*)d_in[20];
  const float* W2   = (const float*)d_in[21];
  const float* b2   = (const float*)d_in[22];
  float* out = (float*)d_out;
  float* ws = (float*)d_ws;
  __hip_bfloat16* u_bf = (__hip_bfloat16*)ws;                 // 16384*256 bf16 (8MB)
  __hip_bfloat16* hn_bf = (__hip_bfloat16*)(ws + 4194304);    // 16384*256 bf16
  __hip_bfloat16* xz_bf = (__hip_bfloat16*)(ws + 8388608);    // 16384*1024 bf16
  float* dbc32 = ws + 16777216;                               // 16384*32 f32
  __hip_bfloat16* delta_bf = (__hip_bfloat16*)(ws + 17301504);// 16384*512 bf16
  __hip_bfloat16* y_bf  = (__hip_bfloat16*)(ws + 25690112);   // 16384*512 bf16
  __hip_bfloat16* xs_bf = (__hip_bfloat16*)(ws + 29884416);   // 16384*512 bf16
  float* Atot  = ws + 34078720;                               // NCH*8192 f32
  float* Btot  = ws + 38273024;                               // NCH*8192 f32
  float* h0    = Btot;                  // aliased (scan2 loads before store)
  float* h2    = ws;                    // aliased (u dead after k_ln; 8MB fits)
  __hip_bfloat16* inWt   = (__hip_bfloat16*)(ws + 42467328);  // 2*1024*256 bf16
  __hip_bfloat16* outWt  = (__hip_bfloat16*)(ws + 42729472);  // 2*256*512 bf16
  __hip_bfloat16* W1t    = (__hip_bfloat16*)(ws + 42860544);  // 128*256 bf16
  __hip_bfloat16* Wd_t   = (__hip_bfloat16*)(ws + 42876928);  // 2*512*512 bf16
  __hip_bfloat16* Wbc_t  = (__hip_bfloat16*)(ws + 43139072);  // 2*128*512 bf16

  k_cvtw<<<3200,256,0,stream>>>(inW, outW, W1, inWt, outWt, W1t);
  k_wd<<<2560,256,0,stream>>>(xpW, dtW, Wd_t, Wbc_t);
  k_input<<<L_SEQ/4,256,0,stream>>>(x,Win,bin,ln1g,ln1b,u_bf);
  for(int i=0;i<2;i++){
    k_rms<<<L_SEQ/4,256,0,stream>>>(u_bf, rmsw+i*DM, hn_bf);
    k_mgemm<0,__hip_bfloat16><<<dim3(8, L_SEQ/128),512,0,stream>>>(hn_bf, inWt+i*262144, nullptr, nullptr, xz_bf, L_SEQ, DM, 1024, 1024);
    k_conv<<<(L_SEQ/CLB)*128/256,256,0,stream>>>(xz_bf, convW+i*DI*4, convB+i*DI, xs_bf);
    k_mgemm<3,__hip_bfloat16><<<dim3(4, L_SEQ/128),512,0,stream>>>(xs_bf, Wd_t+i*262144, dtB+i*DI, nullptr, delta_bf, L_SEQ, DI, 512, 512);
    k_mgemm<0,float><<<dim3(1, L_SEQ/128),512,0,stream>>>(xs_bf, Wbc_t+i*65536, nullptr, nullptr, dbc32, L_SEQ, DI, 32, 32);
    k_scan1<<<NCH*2,256,0,stream>>>(delta_bf, xs_bf, dbc32, A_log+i*DI*DS, Atot, Btot);
    k_scan2<<<32,256,0,stream>>>(Atot, Btot, h0);
    k_scan3<<<NCH*2,256,0,stream>>>(delta_bf, xs_bf, dbc32, A_log+i*DI*DS, Dp+i*DI, h0, xz_bf, y_bf);
    k_mgemm<1,__hip_bfloat16><<<dim3(2, L_SEQ/128),512,0,stream>>>(y_bf, outWt+i*131072, nullptr, u_bf, u_bf, L_SEQ, DI, 256, 256);
  }
  k_ln<<<L_SEQ/4,256,0,stream>>>(u_bf, ln2g, ln2b, hn_bf);
  k_mgemm<2,float><<<dim3(1, L_SEQ/128),512,0,stream>>>(hn_bf, W1t, b1, nullptr, h2, L_SEQ, DM, 128, 128);
  k_final<<<L_SEQ/4,256,0,stream>>>(h2, ln3g, ln3b, W2, b2, out);
}

// Round 13
// 412.958 us; speedup vs baseline: 1.3594x; 1.0781x over previous
//
#include <hip/hip_runtime.h>
#include <hip/hip_bf16.h>
#include <math.h>

#define L_SEQ 16384
#define DM 256
#define DI 512
#define DS 16
#define NCH 512   // number of scan chunks
#define CHL 32    // chunk length (NCH*CHL == L_SEQ)
#define CLB 16    // conv: timesteps per thread

typedef __attribute__((ext_vector_type(8))) short short8v;
typedef __attribute__((ext_vector_type(4))) float f32x4;

__device__ __forceinline__ float tanh_fast(float x){
  float xc = fminf(x, 15.f);
  float t = __expf(2.f*xc);
  return (t-1.f)/(t+1.f);
}
__device__ __forceinline__ float gelu_f(float x){
  float x3 = x*x*x;
  return 0.5f*x*(1.0f + tanh_fast(0.7978845608028654f*(x + 0.044715f*x3)));
}
__device__ __forceinline__ float silu_f(float x){
  return x / (1.0f + __expf(-x));
}
__device__ __forceinline__ float softplus_f(float x){
  return fmaxf(x,0.0f) + __logf(1.0f + __expf(-fabsf(x)));
}
__device__ __forceinline__ float bf2f(unsigned short u){
  return __uint_as_float(((unsigned int)u)<<16);
}
__device__ __forceinline__ void gload16(const void* g, void* l){
  __builtin_amdgcn_global_load_lds((const __attribute__((address_space(1))) void*)g,
                                   (__attribute__((address_space(3))) void*)l, 16, 0, 0);
}

// r^(n+1) for n=0..15, ~16 muls, depth ~4 (replaces 16 quarter-rate exps)
__device__ __forceinline__ void powers16(float r, float* dA){
  float r2 = r*r;
  float r4 = r2*r2;
  float r8 = r4*r4;
  dA[0]=r;        dA[1]=r2;       dA[2]=r2*r;     dA[3]=r4;
  dA[4]=r4*r;     dA[5]=r4*r2;    dA[6]=r4*dA[2]; dA[7]=r8;
  dA[8]=r8*r;     dA[9]=r8*r2;    dA[10]=r8*dA[2];dA[11]=r8*r4;
  dA[12]=r8*dA[4];dA[13]=r8*dA[5];dA[14]=r8*dA[6];dA[15]=r8*r8;
}

// ---- merged weight prep:
//  inWt[layer][n][k]  = bf16(inW[k][n] * rmsw[layer][k])   (rms weight folded)
//  outWt[layer][n][k] = bf16(outW[k][n])
//  W1t[n][k]          = bf16(W1[k][n])
//  Wdbc_t[layer][640][512]: rows<512 = (xpW[:,:16]@dtW)^T; 512..543 = BC^T; pad 0
__global__ void k_prep(const float* __restrict__ inW, const float* __restrict__ rmsw,
                       const float* __restrict__ outW, const float* __restrict__ W1,
                       const float* __restrict__ xpW, const float* __restrict__ dtW,
                       __hip_bfloat16* __restrict__ inWt, __hip_bfloat16* __restrict__ outWt,
                       __hip_bfloat16* __restrict__ W1t, __hip_bfloat16* __restrict__ Wdbc_t){
  int idx = blockIdx.x*256 + threadIdx.x;
  if(idx < 524288){                      // inW: 2x[256][1024] -> [1024][256], rmsw fold
    int layer = idx >> 18;
    int r = idx & 262143;
    int n = r >> 8, k = r & 255;
    inWt[idx] = __float2bfloat16(inW[layer*262144 + k*1024 + n] * rmsw[layer*256+k]);
  } else if(idx < 786432){               // outW: 2x[512][256] -> [256][512]
    int j = idx - 524288;
    int layer = j >> 17;
    int r = j & 131071;
    int n = r >> 9, k = r & 511;
    outWt[j] = __float2bfloat16(outW[layer*131072 + k*256 + n]);
  } else if(idx < 819200){               // W1: [256][128] -> [128][256]
    int j = idx - 786432;
    int n = j >> 8, k = j & 255;
    W1t[j] = __float2bfloat16(W1[k*128 + n]);
  } else if(idx < 1474560){              // Wdbc: 2x[640][512]
    int j = idx - 819200;
    int layer = j / 327680;
    int r = j % 327680;
    int n = r >> 9, k = r & 511;
    const float* xp = xpW + layer*512*48;
    float v;
    if(n < 512){
      const float* dt = dtW + layer*16*512;
      float s = 0.f;
#pragma unroll
      for(int q=0;q<16;q++) s = fmaf(xp[k*48+q], dt[q*512+n], s);
      v = s;
    } else if(n < 544){
      v = xp[k*48 + 16 + (n-512)];
    } else v = 0.f;
    Wdbc_t[j] = __float2bfloat16(v);
  }
}

// ---- zero rowsq1 ----
__global__ void k_zero(float* __restrict__ p){
  ((float4*)p)[blockIdx.x*256 + threadIdx.x] = make_float4(0.f,0.f,0.f,0.f);
}

// ---- input projection + LN + gelu -> bf16 u; also rowsq0[r] = sum(u_r^2) ----
__global__ __launch_bounds__(256) void k_input(const float* __restrict__ x,
                        const float* __restrict__ Win, const float* __restrict__ bin,
                        const float* __restrict__ g, const float* __restrict__ b,
                        __hip_bfloat16* __restrict__ u, float* __restrict__ rowsq){
  int wv = threadIdx.x>>6, lane = threadIdx.x&63;
  int r = blockIdx.x*4 + wv;
  int c0 = lane*4;
  float acc[4];
  { float4 bv = *(const float4*)&bin[c0];
    acc[0]=bv.x; acc[1]=bv.y; acc[2]=bv.z; acc[3]=bv.w; }
#pragma unroll
  for(int k=0;k<32;k++){
    float xk = x[r*32+k];
    float4 wv4 = *(const float4*)&Win[k*DM+c0];
    acc[0]=fmaf(xk,wv4.x,acc[0]); acc[1]=fmaf(xk,wv4.y,acc[1]);
    acc[2]=fmaf(xk,wv4.z,acc[2]); acc[3]=fmaf(xk,wv4.w,acc[3]);
  }
  float s = (acc[0]+acc[1])+(acc[2]+acc[3]);
  float sq = acc[0]*acc[0]+acc[1]*acc[1]+acc[2]*acc[2]+acc[3]*acc[3];
#pragma unroll
  for(int o=32;o;o>>=1){ s += __shfl_xor(s,o); sq += __shfl_xor(sq,o); }
  float mean = s*(1.0f/DM);
  float var = sq*(1.0f/DM) - mean*mean;
  float rs = rsqrtf(var+1e-5f);
  float4 gv = *(const float4*)&g[c0];
  float4 bv = *(const float4*)&b[c0];
  float go[4];
  go[0] = gelu_f((acc[0]-mean)*rs*gv.x+bv.x);
  go[1] = gelu_f((acc[1]-mean)*rs*gv.y+bv.y);
  go[2] = gelu_f((acc[2]-mean)*rs*gv.z+bv.z);
  go[3] = gelu_f((acc[3]-mean)*rs*gv.w+bv.w);
  float ssq = go[0]*go[0]+go[1]*go[1]+go[2]*go[2]+go[3]*go[3];
#pragma unroll
  for(int o=32;o;o>>=1) ssq += __shfl_xor(ssq,o);
  if(lane==0) rowsq[r] = ssq;
  __hip_bfloat16 ob[4] = {__float2bfloat16(go[0]),__float2bfloat16(go[1]),
                          __float2bfloat16(go[2]),__float2bfloat16(go[3])};
  *(uint2*)&u[r*DM+c0] = *(uint2*)ob;
}

// ---- layernorm over 256 (bf16 in -> bf16 out), wave per row ----
__global__ __launch_bounds__(256) void k_ln(const __hip_bfloat16* __restrict__ u,
                     const float* __restrict__ g, const float* __restrict__ b,
                     __hip_bfloat16* __restrict__ o){
  int wv = threadIdx.x>>6, lane = threadIdx.x&63;
  int r = blockIdx.x*4 + wv;
  int c0 = lane*4;
  ushort4 uv = *(const ushort4*)&u[r*DM+c0];
  float v[4] = {bf2f(uv.x), bf2f(uv.y), bf2f(uv.z), bf2f(uv.w)};
  float s = (v[0]+v[1])+(v[2]+v[3]);
  float sq = v[0]*v[0]+v[1]*v[1]+v[2]*v[2]+v[3]*v[3];
#pragma unroll
  for(int o2=32;o2;o2>>=1){ s += __shfl_xor(s,o2); sq += __shfl_xor(sq,o2); }
  float mean = s*(1.0f/DM);
  float var = sq*(1.0f/DM) - mean*mean;
  float rs = rsqrtf(var+1e-5f);
  float4 gv = *(const float4*)&g[c0];
  float4 bv = *(const float4*)&b[c0];
  __hip_bfloat16 ob[4] = {
    __float2bfloat16((v[0]-mean)*rs*gv.x+bv.x),
    __float2bfloat16((v[1]-mean)*rs*gv.y+bv.y),
    __float2bfloat16((v[2]-mean)*rs*gv.z+bv.z),
    __float2bfloat16((v[3]-mean)*rs*gv.w+bv.w)};
  *(uint2*)&o[r*DM+c0] = *(uint2*)ob;
}

// ---- bf16 MFMA GEMM, 8 waves, BK=128 + XCD remap + LDS-staged epilogue.
//      EPI: 0=store, 1=+R, 2=gelu(+bias), 4=delta|BC split (softplus->C, C2),
//      5=+R + rowsq atomic (out-proj feeding next rms), 6=row-scale by
//      rsqrt(rowsq/256+eps) (rms-folded in-proj). ----
template<int EPI, typename OT>
__global__ __launch_bounds__(512) void k_mgemm(const __hip_bfloat16* __restrict__ A,
    const __hip_bfloat16* __restrict__ Wt, const float* __restrict__ bias,
    const OT* __restrict__ R, OT* __restrict__ C, float* __restrict__ C2,
    float* __restrict__ rowsq, int M, int K, int ldc, int Nout){
  __shared__ char lds[69632];          // stage: As 32K | Bs 32K ; epi: Obuf 128x132 f32
  short* As = (short*)lds;             // [128 rows][128 k], 16-slot XOR swizzle
  short* Bs = (short*)(lds + 32768);
  float* Ob = (float*)lds;             // [128][132]
  int t = threadIdx.x, lane = t&63, wave = t>>6;   // 8 waves
  // XCD-aware tile remap (block f -> XCD f%8; XCD owns contiguous y-panels)
  int gx = gridDim.x;
  int f = blockIdx.y*gx + blockIdx.x;
  int s = f >> 3;
  int sy = s/gx;
  int yb = (f&7)*(gridDim.y>>3) + sy;
  int xb = s - sy*gx;
  int m0 = yb*128, n0 = xb*128;
  int wm = (wave>>1)*32, wn = (wave&1)*64;   // wave owns 32 rows x 64 cols
  f32x4 acc[2][4] = {};
  int nk = K >> 7;
  for(int ki=0; ki<nk; ki++){
    int kt = ki<<7;
    __syncthreads();
#pragma unroll
    for(int c=0;c<4;c++){
      int off = c*8192 + t*16;         // byte offset in 32KB half
      int row = off>>8;                // 256B rows
      int sl  = ((off>>4)&15) ^ (row&15);
      gload16(&A [(m0+row)*K + kt + sl*8], (char*)As + off);
      gload16(&Wt[(n0+row)*K + kt + sl*8], (char*)Bs + off);
    }
    asm volatile("s_waitcnt vmcnt(0)" ::: "memory");
    __syncthreads();
#pragma unroll
    for(int ks=0; ks<4; ks++){
      short8v a[2], b[4];
      int k8 = ks*4 + (lane>>4);
#pragma unroll
      for(int i=0;i<2;i++){
        int lr = wm + i*16 + (lane&15);
        a[i] = *(const short8v*)&As[lr*128 + (k8 ^ (lr&15))*8];
      }
#pragma unroll
      for(int j=0;j<4;j++){
        int lr = wn + j*16 + (lane&15);
        b[j] = *(const short8v*)&Bs[lr*128 + (k8 ^ (lr&15))*8];
      }
#pragma unroll
      for(int i=0;i<2;i++)
#pragma unroll
        for(int j=0;j<4;j++)
          acc[i][j] = __builtin_amdgcn_mfma_f32_16x16x32_bf16(a[i], b[j], acc[i][j], 0,0,0);
    }
  }
  __syncthreads();   // all LDS reads done before Obuf overwrites stage buffers
#pragma unroll
  for(int i=0;i<2;i++){
    int r0 = wm + i*16 + (lane>>4)*4;
#pragma unroll
    for(int j=0;j<4;j++){
      int cl = wn + j*16 + (lane&15);
#pragma unroll
      for(int r=0;r<4;r++) Ob[(r0+r)*132 + cl] = acc[i][j][r];
    }
  }
  __syncthreads();
  // coalesced copy + epilogue: 512 threads x 8 float4 = 128x128.
  // thread t covers 32 consecutive elements = quarter of ONE row (row = t/4).
  float ssq_acc = 0.f;
  int rowq = t>>2;
  int growq = m0 + rowq;
#pragma unroll
  for(int v=0; v<8; v++){
    int fidx = (t*8+v)*4;
    int row = fidx>>7, col = fidx&127;
    if(col < Nout){
      float4 o = *(const float4*)&Ob[row*132 + col];
      int grow = m0 + row, gcol = n0 + col;
      if(EPI==1 || EPI==5){
        if constexpr(sizeof(OT)==2){
          ushort4 rv = *(const ushort4*)&R[grow*ldc+gcol];
          o.x+=bf2f(rv.x); o.y+=bf2f(rv.y); o.z+=bf2f(rv.z); o.w+=bf2f(rv.w);
        } else {
          float4 rv = *(const float4*)&R[grow*ldc+gcol];
          o.x+=rv.x; o.y+=rv.y; o.z+=rv.z; o.w+=rv.w;
        }
        if(EPI==5) ssq_acc += o.x*o.x + o.y*o.y + o.z*o.z + o.w*o.w;
      }
      if(EPI==2){
        float4 bv = *(const float4*)&bias[gcol];
        o.x=gelu_f(o.x+bv.x); o.y=gelu_f(o.y+bv.y);
        o.z=gelu_f(o.z+bv.z); o.w=gelu_f(o.w+bv.w);
      }
      if(EPI==6){
        float rs = rsqrtf(rowsq[grow]*(1.0f/DM) + 1e-5f);
        o.x*=rs; o.y*=rs; o.z*=rs; o.w*=rs;
      }
      if(EPI==4){
        if(gcol < 512){
          float4 bv = *(const float4*)&bias[gcol];
          float4 so = {softplus_f(o.x+bv.x), softplus_f(o.y+bv.y),
                       softplus_f(o.z+bv.z), softplus_f(o.w+bv.w)};
          __hip_bfloat16 ob[4] = {__float2bfloat16(so.x),__float2bfloat16(so.y),
                                  __float2bfloat16(so.z),__float2bfloat16(so.w)};
          *(uint2*)&C[grow*ldc+gcol] = *(uint2*)ob;
        } else {
          *(float4*)&C2[grow*32 + (gcol-512)] = o;
        }
      } else {
        if constexpr(sizeof(OT)==2){
          __hip_bfloat16 ob[4] = {__float2bfloat16(o.x),__float2bfloat16(o.y),
                                  __float2bfloat16(o.z),__float2bfloat16(o.w)};
          *(uint2*)&C[grow*ldc+gcol] = *(uint2*)ob;
        } else {
          *(float4*)&C[grow*ldc+gcol] = o;
        }
      }
    }
  }
  if(EPI==5){
    ssq_acc += __shfl_xor(ssq_acc,1);
    ssq_acc += __shfl_xor(ssq_acc,2);
    if((lane&3)==0) atomicAdd(&rowsq[growq], ssq_acc);
  }
}

// ---- causal depthwise conv (k=4) + bias + silu, sliding window. ----
__global__ __launch_bounds__(256) void k_conv(const __hip_bfloat16* __restrict__ xz,
                       const float* __restrict__ cw, const float* __restrict__ cb,
                       __hip_bfloat16* __restrict__ xs_bf){
  int idx = blockIdx.x*256 + threadIdx.x;   // (L_SEQ/CLB)*128 threads
  int cg = idx & 127, lb = idx >> 7;
  int c4 = cg*4;
  int l0 = lb*CLB;
  float w[4][4], bias[4];
#pragma unroll
  for(int j=0;j<4;j++){
    float4 wv = *(const float4*)&cw[(c4+j)*4];
    w[j][0]=wv.x; w[j][1]=wv.y; w[j][2]=wv.z; w[j][3]=wv.w;
  }
  { float4 bv = *(const float4*)&cb[c4];
    bias[0]=bv.x; bias[1]=bv.y; bias[2]=bv.z; bias[3]=bv.w; }
  float xm0[4], xm1[4], xm2[4];   // x[l-3], x[l-2], x[l-1]
#pragma unroll
  for(int j=0;j<4;j++){ xm0[j]=0.f; xm1[j]=0.f; xm2[j]=0.f; }
  if(l0 >= 3){
    ushort4 r0 = *(const ushort4*)&xz[(l0-3)*1024 + c4];
    ushort4 r1 = *(const ushort4*)&xz[(l0-2)*1024 + c4];
    ushort4 r2 = *(const ushort4*)&xz[(l0-1)*1024 + c4];
    xm0[0]=bf2f(r0.x); xm0[1]=bf2f(r0.y); xm0[2]=bf2f(r0.z); xm0[3]=bf2f(r0.w);
    xm1[0]=bf2f(r1.x); xm1[1]=bf2f(r1.y); xm1[2]=bf2f(r1.z); xm1[3]=bf2f(r1.w);
    xm2[0]=bf2f(r2.x); xm2[1]=bf2f(r2.y); xm2[2]=bf2f(r2.z); xm2[3]=bf2f(r2.w);
  }
#pragma unroll 4
  for(int l=l0; l<l0+CLB; l++){
    ushort4 rc = *(const ushort4*)&xz[l*1024 + c4];
    float xc[4] = {bf2f(rc.x), bf2f(rc.y), bf2f(rc.z), bf2f(rc.w)};
    __hip_bfloat16 ob[4];
#pragma unroll
    for(int j=0;j<4;j++){
      float acc = bias[j];
      acc = fmaf(xm0[j], w[j][0], acc);
      acc = fmaf(xm1[j], w[j][1], acc);
      acc = fmaf(xm2[j], w[j][2], acc);
      acc = fmaf(xc[j],  w[j][3], acc);
      ob[j] = __float2bfloat16(silu_f(acc));
    }
    *(uint2*)&xs_bf[l*DI + c4] = *(uint2*)ob;
#pragma unroll
    for(int j=0;j<4;j++){ xm0[j]=xm1[j]; xm1[j]=xm2[j]; xm2[j]=xc[j]; }
  }
}

// ---- scan phase 1: per-chunk (prod dA, local carry) per state.
//      Fast path: A[n] == (n+1)*A[0] -> dA[n] = r^(n+1), r = exp(d*A[0]). ----
__global__ __launch_bounds__(256) void k_scan1(const __hip_bfloat16* __restrict__ delta,
                        const __hip_bfloat16* __restrict__ xs,
                        const float* __restrict__ dbc32, const float* __restrict__ A_log,
                        float* __restrict__ Atot, float* __restrict__ Btot){
  __shared__ float bcs[CHL*32];
  int t = threadIdx.x;
  int chunk = blockIdx.x >> 1;
  int e = ((blockIdx.x & 1) << 8) + t;
  int l0 = chunk*CHL;
  ((float4*)bcs)[t] = ((const float4*)&dbc32[l0*32])[t];
  float A[16];
  {
    const float4* al = (const float4*)&A_log[e*DS];
#pragma unroll
    for(int q=0;q<4;q++){
      float4 a = al[q];
      A[q*4+0] = -__expf(a.x); A[q*4+1] = -__expf(a.y);
      A[q*4+2] = -__expf(a.z); A[q*4+3] = -__expf(a.w);
    }
  }
  bool pf = true;
#pragma unroll
  for(int n=1;n<16;n++) pf = pf && (fabsf(A[n] - (n+1)*A[0]) <= 1e-4f*fabsf(A[n]));
  float carry[16], aprod[16];
#pragma unroll
  for(int n=0;n<16;n++){ carry[n]=0.f; aprod[n]=1.f; }
  __syncthreads();
  if(pf){
    float A0 = A[0];
#pragma unroll 2
    for(int li=0; li<CHL; li++){
      int l = l0 + li;
      float d  = bf2f(*(const unsigned short*)&delta[l*DI+e]);
      float xv = bf2f(*(const unsigned short*)&xs[l*DI+e]);
      float dxv = d*xv;
      const float4* bp = (const float4*)&bcs[li*32];
      float4 b0=bp[0], b1=bp[1], b2=bp[2], b3=bp[3];
      float B[16] = {b0.x,b0.y,b0.z,b0.w, b1.x,b1.y,b1.z,b1.w,
                     b2.x,b2.y,b2.z,b2.w, b3.x,b3.y,b3.z,b3.w};
      float r = __expf(d*A0);
      float dA[16]; powers16(r, dA);
#pragma unroll
      for(int n=0;n<16;n++){
        carry[n] = fmaf(carry[n], dA[n], dxv*B[n]);
        aprod[n] *= dA[n];
      }
    }
  } else {
#pragma unroll 2
    for(int li=0; li<CHL; li++){
      int l = l0 + li;
      float d  = bf2f(*(const unsigned short*)&delta[l*DI+e]);
      float xv = bf2f(*(const unsigned short*)&xs[l*DI+e]);
      float dxv = d*xv;
      const float4* bp = (const float4*)&bcs[li*32];
      float4 b0=bp[0], b1=bp[1], b2=bp[2], b3=bp[3];
      float B[16] = {b0.x,b0.y,b0.z,b0.w, b1.x,b1.y,b1.z,b1.w,
                     b2.x,b2.y,b2.z,b2.w, b3.x,b3.y,b3.z,b3.w};
#pragma unroll
      for(int n=0;n<16;n++){
        float dA = __expf(d*A[n]);
        carry[n] = fmaf(carry[n], dA, dxv*B[n]);
        aprod[n] *= dA;
      }
    }
  }
  float4* ap = (float4*)&Atot[chunk*8192 + e*DS];
  float4* bp = (float4*)&Btot[chunk*8192 + e*DS];
#pragma unroll
  for(int q=0;q<4;q++){
    ap[q] = make_float4(aprod[q*4],aprod[q*4+1],aprod[q*4+2],aprod[q*4+3]);
    bp[q] = make_float4(carry[q*4],carry[q*4+1],carry[q*4+2],carry[q*4+3]);
  }
}

// ---- scan phase 2: carry-in per chunk, unroll-8 batched loads
//      (h0 aliases Btot: all batch loads precede batch stores) ----
__global__ void k_scan2(const float* __restrict__ Atot, const float* __restrict__ Btot,
                        float* __restrict__ h0){
  int tg = blockIdx.x*256 + threadIdx.x;
  float carry = 0.f;
  for(int c0=0;c0<NCH;c0+=8){
    float a[8], b[8];
#pragma unroll
    for(int j=0;j<8;j++){
      a[j] = Atot[(c0+j)*8192+tg];
      b[j] = Btot[(c0+j)*8192+tg];
    }
#pragma unroll
    for(int j=0;j<8;j++){
      h0[(c0+j)*8192+tg] = carry;
      carry = fmaf(carry, a[j], b[j]);
    }
  }
}

// ---- scan phase 3: replay with carry-in, y = (sum h*C + xs*D)*silu(z) -> bf16 ----
__global__ __launch_bounds__(256) void k_scan3(const __hip_bfloat16* __restrict__ delta,
                        const __hip_bfloat16* __restrict__ xs,
                        const float* __restrict__ dbc32, const float* __restrict__ A_log,
                        const float* __restrict__ Dp, const float* __restrict__ h0,
                        const __hip_bfloat16* __restrict__ xz, __hip_bfloat16* __restrict__ y){
  __shared__ float bcs[CHL*32];
  int t = threadIdx.x;
  int chunk = blockIdx.x >> 1;
  int e = ((blockIdx.x & 1) << 8) + t;
  int l0 = chunk*CHL;
  ((float4*)bcs)[t] = ((const float4*)&dbc32[l0*32])[t];
  float A[16];
  {
    const float4* al = (const float4*)&A_log[e*DS];
#pragma unroll
    for(int q=0;q<4;q++){
      float4 a = al[q];
      A[q*4+0] = -__expf(a.x); A[q*4+1] = -__expf(a.y);
      A[q*4+2] = -__expf(a.z); A[q*4+3] = -__expf(a.w);
    }
  }
  bool pf = true;
#pragma unroll
  for(int n=1;n<16;n++) pf = pf && (fabsf(A[n] - (n+1)*A[0]) <= 1e-4f*fabsf(A[n]));
  float carry[16];
  {
    const float4* hp = (const float4*)&h0[chunk*8192 + e*DS];
#pragma unroll
    for(int q=0;q<4;q++){
      float4 h = hp[q];
      carry[q*4+0]=h.x; carry[q*4+1]=h.y; carry[q*4+2]=h.z; carry[q*4+3]=h.w;
    }
  }
  float Dv = Dp[e];
  __syncthreads();
  if(pf){
    float A0 = A[0];
#pragma unroll 2
    for(int li=0; li<CHL; li++){
      int l = l0 + li;
      float d  = bf2f(*(const unsigned short*)&delta[l*DI+e]);
      float xv = bf2f(*(const unsigned short*)&xs[l*DI+e]);
      float dxv = d*xv;
      const float4* bp = (const float4*)&bcs[li*32];
      float4 b0=bp[0], b1=bp[1], b2=bp[2], b3=bp[3];
      float4 c0=bp[4], c1=bp[5], c2=bp[6], c3=bp[7];
      float B[16] = {b0.x,b0.y,b0.z,b0.w, b1.x,b1.y,b1.z,b1.w,
                     b2.x,b2.y,b2.z,b2.w, b3.x,b3.y,b3.z,b3.w};
      float Cv[16] = {c0.x,c0.y,c0.z,c0.w, c1.x,c1.y,c1.z,c1.w,
                      c2.x,c2.y,c2.z,c2.w, c3.x,c3.y,c3.z,c3.w};
      float r = __expf(d*A0);
      float dA[16]; powers16(r, dA);
      float p[4] = {0.f,0.f,0.f,0.f};
#pragma unroll
      for(int n=0;n<16;n++){
        carry[n] = fmaf(carry[n], dA[n], dxv*B[n]);
        p[n&3] = fmaf(carry[n], Cv[n], p[n&3]);
      }
      float ps = (p[0]+p[1]) + (p[2]+p[3]);
      float z = bf2f(*(const unsigned short*)&xz[l*1024 + 512 + e]);
      y[l*DI+e] = __float2bfloat16(fmaf(xv, Dv, ps) * silu_f(z));
    }
  } else {
#pragma unroll 2
    for(int li=0; li<CHL; li++){
      int l = l0 + li;
      float d  = bf2f(*(const unsigned short*)&delta[l*DI+e]);
      float xv = bf2f(*(const unsigned short*)&xs[l*DI+e]);
      float dxv = d*xv;
      const float4* bp = (const float4*)&bcs[li*32];
      float4 b0=bp[0], b1=bp[1], b2=bp[2], b3=bp[3];
      float4 c0=bp[4], c1=bp[5], c2=bp[6], c3=bp[7];
      float B[16] = {b0.x,b0.y,b0.z,b0.w, b1.x,b1.y,b1.z,b1.w,
                     b2.x,b2.y,b2.z,b2.w, b3.x,b3.y,b3.z,b3.w};
      float Cv[16] = {c0.x,c0.y,c0.z,c0.w, c1.x,c1.y,c1.z,c1.w,
                      c2.x,c2.y,c2.z,c2.w, c3.x,c3.y,c3.z,c3.w};
      float p[4] = {0.f,0.f,0.f,0.f};
#pragma unroll
      for(int n=0;n<16;n++){
        float dA = __expf(d*A[n]);
        carry[n] = fmaf(carry[n], dA, dxv*B[n]);
        p[n&3] = fmaf(carry[n], Cv[n], p[n&3]);
      }
      float ps = (p[0]+p[1]) + (p[2]+p[3]);
      float z = bf2f(*(const unsigned short*)&xz[l*1024 + 512 + e]);
      y[l*DI+e] = __float2bfloat16(fmaf(xv, Dv, ps) * silu_f(z));
    }
  }
}

// ---- final: LN(128) -> @W2(128,1)+b2 -> tanh, one wave per row ----
__global__ void k_final(const float* __restrict__ h2, const float* __restrict__ g,
                        const float* __restrict__ b, const float* __restrict__ W2,
                        const float* __restrict__ b2, float* __restrict__ out){
  int lane = threadIdx.x&63;
  int wv = threadIdx.x>>6;
  int r = blockIdx.x*4 + wv;
  float v0 = h2[r*128+lane], v1 = h2[r*128+64+lane];
  float s = v0+v1, sq = v0*v0+v1*v1;
#pragma unroll
  for(int o=32;o;o>>=1){ s += __shfl_xor(s,o); sq += __shfl_xor(sq,o); }
  float mean = s*(1.0f/128), var = sq*(1.0f/128) - mean*mean;
  float rs = rsqrtf(var+1e-5f);
  float n0 = (v0-mean)*rs*g[lane]+b[lane];
  float n1 = (v1-mean)*rs*g[lane+64]+b[lane+64];
  float d = n0*W2[lane] + n1*W2[lane+64];
#pragma unroll
  for(int o=32;o;o>>=1) d += __shfl_xor(d,o);
  if(lane==0) out[r] = tanhf(d + b2[0]);
}

extern "C" void kernel_launch(void* const* d_in, const int* in_sizes, int n_in,
                              void* d_out, int out_size, void* d_ws, size_t ws_size,
                              hipStream_t stream){
  const float* x    = (const float*)d_in[0];
  const float* Win  = (const float*)d_in[1];
  const float* bin  = (const float*)d_in[2];
  const float* ln1g = (const float*)d_in[3];
  const float* ln1b = (const float*)d_in[4];
  const float* rmsw = (const float*)d_in[5];
  const float* inW  = (const float*)d_in[6];
  const float* convW= (const float*)d_in[7];
  const float* convB= (const float*)d_in[8];
  const float* xpW  = (const float*)d_in[9];
  const float* dtW  = (const float*)d_in[10];
  const float* dtB  = (const float*)d_in[11];
  const float* A_log= (const float*)d_in[12];
  const float* Dp   = (const float*)d_in[13];
  const float* outW = (const float*)d_in[14];
  const float* ln2g = (const float*)d_in[15];
  const float* ln2b = (const float*)d_in[16];
  const float* W1   = (const float*)d_in[17];
  const float* b1   = (const float*)d_in[18];
  const float* ln3g = (const float*)d_in[19];
  const float* ln3b = (const float*)d_in[20];
  const float* W2   = (const float*)d_in[21];
  const float* b2   = (const float*)d_in[22];
  float* out = (float*)d_out;
  float* ws = (float*)d_ws;
  __hip_bfloat16* u_bf = (__hip_bfloat16*)ws;                 // 16384*256 bf16 (8MB)
  float* rowsq0 = ws + 4194304;                               // 16384 f32
  float* rowsq1 = ws + 4194304 + 16384;                       // 16384 f32
  __hip_bfloat16* hn_bf = (__hip_bfloat16*)(ws + 4259840);    // 16384*256 bf16 (ln out)
  __hip_bfloat16* xz_bf = (__hip_bfloat16*)(ws + 8388608);    // 16384*1024 bf16
  float* dbc32 = ws + 16777216;                               // 16384*32 f32
  __hip_bfloat16* delta_bf = (__hip_bfloat16*)(ws + 17301504);// 16384*512 bf16
  __hip_bfloat16* y_bf  = (__hip_bfloat16*)(ws + 25690112);   // 16384*512 bf16
  __hip_bfloat16* xs_bf = (__hip_bfloat16*)(ws + 29884416);   // 16384*512 bf16
  float* Atot  = ws + 34078720;                               // NCH*8192 f32
  float* Btot  = ws + 38273024;                               // NCH*8192 f32
  float* h0    = Btot;                  // aliased (scan2 loads before store)
  float* h2    = ws;                    // aliased (u dead after k_ln; 8MB fits)
  __hip_bfloat16* inWt   = (__hip_bfloat16*)(ws + 42467328);  // 2*1024*256 bf16
  __hip_bfloat16* outWt  = (__hip_bfloat16*)(ws + 42729472);  // 2*256*512 bf16
  __hip_bfloat16* W1t    = (__hip_bfloat16*)(ws + 42860544);  // 128*256 bf16
  __hip_bfloat16* Wdbc_t = (__hip_bfloat16*)(ws + 42876928);  // 2*640*512 bf16

  k_prep<<<5760,256,0,stream>>>(inW, rmsw, outW, W1, xpW, dtW, inWt, outWt, W1t, Wdbc_t);
  k_zero<<<16,256,0,stream>>>(rowsq1);
  k_input<<<L_SEQ/4,256,0,stream>>>(x,Win,bin,ln1g,ln1b,u_bf,rowsq0);
  for(int i=0;i<2;i++){
    float* rsq_in = (i==0) ? rowsq0 : rowsq1;
    // in-proj with folded rms: xz = (u @ inWt') * rsqrt(rowsq/256+eps)
    k_mgemm<6,__hip_bfloat16><<<dim3(8, L_SEQ/128),512,0,stream>>>(
        u_bf, inWt+i*262144, nullptr, nullptr, xz_bf, nullptr, rsq_in, L_SEQ, DM, 1024, 1024);
    k_conv<<<(L_SEQ/CLB)*128/256,256,0,stream>>>(xz_bf, convW+i*DI*4, convB+i*DI, xs_bf);
    // merged delta|BC GEMM
    k_mgemm<4,__hip_bfloat16><<<dim3(5, L_SEQ/128),512,0,stream>>>(
        xs_bf, Wdbc_t+i*327680, dtB+i*DI, nullptr, delta_bf, dbc32, nullptr, L_SEQ, DI, 512, 544);
    k_scan1<<<NCH*2,256,0,stream>>>(delta_bf, xs_bf, dbc32, A_log+i*DI*DS, Atot, Btot);
    k_scan2<<<32,256,0,stream>>>(Atot, Btot, h0);
    k_scan3<<<NCH*2,256,0,stream>>>(delta_bf, xs_bf, dbc32, A_log+i*DI*DS, Dp+i*DI, h0, xz_bf, y_bf);
    if(i==0){
      k_mgemm<5,__hip_bfloat16><<<dim3(2, L_SEQ/128),512,0,stream>>>(
          y_bf, outWt, nullptr, u_bf, u_bf, nullptr, rowsq1, L_SEQ, DI, 256, 256);
    } else {
      k_mgemm<1,__hip_bfloat16><<<dim3(2, L_SEQ/128),512,0,stream>>>(
          y_bf, outWt+131072, nullptr, u_bf, u_bf, nullptr, nullptr, L_SEQ, DI, 256, 256);
    }
  }
  k_ln<<<L_SEQ/4,256,0,stream>>>(u_bf, ln2g, ln2b, hn_bf);
  k_mgemm<2,float><<<dim3(1, L_SEQ/128),512,0,stream>>>(
      hn_bf, W1t, b1, nullptr, h2, nullptr, nullptr, L_SEQ, DM, 128, 128);
  k_final<<<L_SEQ/4,256,0,stream>>>(h2, ln3g, ln3b, W2, b2, out);
}